// Round 3
// baseline (1804.337 us; speedup 1.0000x reference)
//
#include <hip/hip_runtime.h>
#include <hip/hip_bf16.h>

typedef __hip_bfloat16 bf16;

#define BB 4
#define CC 64
#define NN 4096           // 64*64
#define MH 512
#define MW 512

// ---- workspace layout (BYTE offsets; total ~4.5 MiB) ----
#define WB_AFC  ((size_t)0)         // f32[4*4096*64] att_fore (compacted q), pixel-major
#define WB_DEN  ((size_t)4194304)   // f32[4*4096] softmax denominators
#define WB_VIS  ((size_t)4259840)   // f32[4*4096] visatt
#define WB_QIX  ((size_t)4325376)   // int[4*4096]
#define WB_KIX  ((size_t)4390912)   // int[4*4096]
#define WB_MFL  ((size_t)4456448)   // uchar[4*4096]
#define WB_CNT  ((size_t)4472832)   // int nq[4]; int nk[4]; uint vmaxbits

__device__ __forceinline__ float b2f(bf16 v) { return __bfloat162float(v); }

// ---------------- 1. maxpool 8x8 on mask + init vis/vmax -------------------
__global__ __launch_bounds__(256) void k_maxpool(const float* __restrict__ mask,
                                                 unsigned char* __restrict__ mfl,
                                                 float* __restrict__ vis,
                                                 unsigned int* __restrict__ vmaxb) {
  int i = blockIdx.x * 256 + threadIdx.x;          // < 4*4096
  int b = i >> 12, p = i & 4095;
  int py = p >> 6, px = p & 63;
  const float* mb = mask + (size_t)b * MH * MW + (py * 8) * MW + px * 8;
  float mx = 0.f;
  #pragma unroll
  for (int dy = 0; dy < 8; ++dy) {
    const float4* r4 = (const float4*)(mb + dy * MW);
    float4 a = r4[0], c = r4[1];
    mx = fmaxf(mx, fmaxf(fmaxf(a.x, a.y), fmaxf(a.z, a.w)));
    mx = fmaxf(mx, fmaxf(fmaxf(c.x, c.y), fmaxf(c.z, c.w)));
  }
  mfl[i] = (mx > 0.f) ? 1 : 0;
  vis[i] = 0.f;
  if (i == 0) vmaxb[0] = 0u;
}

// ---------------- 2. fg/bg index compaction (1 wave per batch) -------------
__global__ __launch_bounds__(64) void k_compact(const unsigned char* __restrict__ mfl,
                                                int* __restrict__ qidx, int* __restrict__ kidx,
                                                int* __restrict__ nq, int* __restrict__ nk) {
  int b = blockIdx.x, lane = threadIdx.x;
  int qb = 0, kb = 0;
  for (int it = 0; it < 64; ++it) {
    int p = it * 64 + lane;
    bool f = mfl[b * NN + p] != 0;
    unsigned long long bal = __ballot(f);
    int before = __popcll(bal & ((1ULL << lane) - 1ULL));
    if (f)  qidx[b * NN + qb + before] = p;
    if (!f) kidx[b * NN + kb + (lane - before)] = p;
    int cnt = __popcll(bal);
    qb += cnt; kb += 64 - cnt;
  }
  if (lane == 0) { nq[b] = qb; nk[b] = kb; }
}

// -------- 3. conv3x3(pad1) + instance-norm (+ optional residual) + relu ----
// one block per (b, c_out); each thread owns a 4x4 output patch.
__global__ __launch_bounds__(256) void k_conv(const float* __restrict__ in,
                                              const float* __restrict__ wts,
                                              const float* __restrict__ addsrc,
                                              float* __restrict__ outp) {
  int b = blockIdx.x >> 6, co = blockIdx.x & 63;
  __shared__ float tile[66 * 68];
  __shared__ float rsum[4], rsq[4];
  int t = threadIdx.x;
  int tx = (t & 15) * 4, ty = (t >> 4) * 4;
  float acc[16];
  #pragma unroll
  for (int i = 0; i < 16; ++i) acc[i] = 0.f;
  const float* inb = in + (size_t)b * CC * NN;
  const float* wb = wts + (size_t)(co * CC) * 9;
  for (int ci = 0; ci < CC; ++ci) {
    __syncthreads();
    for (int idx = t; idx < 66 * 66; idx += 256) {
      int r = idx / 66, cc2 = idx - r * 66;
      int iy = r - 1, ix = cc2 - 1;
      float v = 0.f;
      if ((unsigned)iy < 64u && (unsigned)ix < 64u) v = inb[ci * NN + iy * 64 + ix];
      tile[r * 68 + cc2] = v;
    }
    __syncthreads();
    float w9[9];
    #pragma unroll
    for (int k = 0; k < 9; ++k) w9[k] = wb[ci * 9 + k];
    float patch[6][6];
    #pragma unroll
    for (int r = 0; r < 6; ++r)
      #pragma unroll
      for (int c = 0; c < 6; ++c) patch[r][c] = tile[(ty + r) * 68 + tx + c];
    #pragma unroll
    for (int iy = 0; iy < 4; ++iy)
      #pragma unroll
      for (int ix = 0; ix < 4; ++ix) {
        float a = acc[iy * 4 + ix];
        #pragma unroll
        for (int dy = 0; dy < 3; ++dy)
          #pragma unroll
          for (int dx = 0; dx < 3; ++dx) a += w9[dy * 3 + dx] * patch[iy + dy][ix + dx];
        acc[iy * 4 + ix] = a;
      }
  }
  float s1 = 0.f, s2 = 0.f;
  #pragma unroll
  for (int i = 0; i < 16; ++i) { s1 += acc[i]; s2 += acc[i] * acc[i]; }
  #pragma unroll
  for (int off = 32; off > 0; off >>= 1) { s1 += __shfl_down(s1, off); s2 += __shfl_down(s2, off); }
  if ((t & 63) == 0) { rsum[t >> 6] = s1; rsq[t >> 6] = s2; }
  __syncthreads();
  s1 = rsum[0] + rsum[1] + rsum[2] + rsum[3];
  s2 = rsq[0] + rsq[1] + rsq[2] + rsq[3];
  float mean = s1 * (1.f / NN);
  float var = fmaxf(s2 * (1.f / NN) - mean * mean, 0.f);
  float inv = rsqrtf(var + 1e-5f);
  float* ob = outp + ((size_t)b * CC + co) * NN;
  const float* ab = addsrc ? addsrc + ((size_t)b * CC + co) * NN : nullptr;
  #pragma unroll
  for (int iy = 0; iy < 4; ++iy)
    #pragma unroll
    for (int ix = 0; ix < 4; ++ix) {
      int p = (ty + iy) * 64 + tx + ix;
      float v = (acc[iy * 4 + ix] - mean) * inv;
      if (ab) v += ab[p];
      ob[p] = fmaxf(v, 0.f);
    }
}

// -------- 4. per-pixel channel L2-normalize + transpose to pixel-major -----
// khat[(b*N+p)*64+c] = kx[b,c,p] / (||kx[b,:,p]|| + 1e-8)
__global__ __launch_bounds__(256) void k_normT(const float* __restrict__ kx,
                                               float* __restrict__ khat) {
  int b = blockIdx.x >> 6, p0 = (blockIdx.x & 63) * 64;
  __shared__ float lk[64][65];
  __shared__ float inv[64];
  int t = threadIdx.x;
  const float* kb = kx + (size_t)b * CC * NN + p0;
  for (int idx = t; idx < 4096; idx += 256) {
    int c = idx >> 6, j = idx & 63;
    lk[j][c] = kb[c * NN + j];
  }
  __syncthreads();
  if (t < 64) {
    float s = 0.f;
    for (int c = 0; c < 64; ++c) { float v = lk[t][c]; s += v * v; }
    inv[t] = 1.f / (sqrtf(s) + 1e-8f);
  }
  __syncthreads();
  float* kh = khat + ((size_t)b * NN + p0) * 64;
  for (int idx = t; idx < 4096; idx += 256) {
    int j = idx >> 6, c = idx & 63;
    kh[j * 64 + c] = lk[j][c] * inv[j];
  }
}

// -------- 5. attention pass 1: denom + att_fore ----------------------------
#define QT 32
#define KT 64
__global__ __launch_bounds__(256) void k_att1(const float* __restrict__ khat, const float* __restrict__ x,
                                              const int* __restrict__ qidx, const int* __restrict__ kidx,
                                              const int* __restrict__ nqv, const int* __restrict__ nkv,
                                              float* __restrict__ afc, float* __restrict__ denomg) {
  int b = blockIdx.y;
  int nqb = nqv[b], nkb = nkv[b];
  int q0 = blockIdx.x * QT;
  if (q0 >= nqb) return;
  __shared__ float lq[QT][65];
  __shared__ float lk[KT][65];
  __shared__ float lv[KT][65];
  __shared__ float le[QT][KT + 1];
  int t = threadIdx.x;
  const int* qix = qidx + b * NN;
  const int* kix = kidx + b * NN;
  const float* khb = khat + (size_t)b * NN * 64;
  const float* xb = x + (size_t)b * CC * NN;
  for (int idx = t; idx < QT * 64; idx += 256) {
    int q = idx >> 6, c = idx & 63;
    float v = 0.f;
    if (q0 + q < nqb) v = khb[(size_t)qix[q0 + q] * 64 + c];
    lq[q][c] = v;
  }
  int q = t >> 3, g = t & 7;
  float o[8];
  #pragma unroll
  for (int u = 0; u < 8; ++u) o[u] = 0.f;
  float dn = 0.f;
  for (int j0 = 0; j0 < nkb; j0 += KT) {
    __syncthreads();
    for (int idx = t; idx < KT * 64; idx += 256) {
      int j = idx >> 6, c = idx & 63;
      float kv = 0.f, vv = 0.f;
      int kk = j0 + j;
      if (kk < nkb) {
        int kp = kix[kk];
        kv = khb[(size_t)kp * 64 + c];
        vv = xb[(size_t)c * NN + kp];        // V = x at bg keys (channel-major gather)
      }
      lk[j][c] = kv; lv[j][c] = vv;
    }
    __syncthreads();
    float s[8];
    #pragma unroll
    for (int u = 0; u < 8; ++u) s[u] = 0.f;
    for (int c = 0; c < 64; ++c) {
      float qv = lq[q][c];
      #pragma unroll
      for (int u = 0; u < 8; ++u) s[u] += qv * lk[g * 8 + u][c];
    }
    #pragma unroll
    for (int u = 0; u < 8; ++u) {
      int kk = j0 + g * 8 + u;
      le[q][g * 8 + u] = (kk < nkb) ? __expf(20.f * s[u]) : 0.f;
    }
    __syncthreads();
    for (int j = 0; j < KT; ++j) {
      float e = le[q][j];
      dn += e;
      #pragma unroll
      for (int u = 0; u < 8; ++u) o[u] += e * lv[j][g * 8 + u];
    }
  }
  int qq = q0 + q;
  if (qq < nqb) {
    float invd = (dn > 0.f) ? 1.f / dn : 0.f;
    float* dst = afc + ((size_t)b * NN + qq) * 64 + g * 8;
    #pragma unroll
    for (int u = 0; u < 8; ++u) dst[u] = o[u] * invd;
    if (g == 0) denomg[b * NN + qq] = dn;
  }
}

// -------- 6. attention pass 2: per-key visatt column sums ------------------
#define KT2 32
__global__ __launch_bounds__(256) void k_att2(const float* __restrict__ khat,
                                              const int* __restrict__ qidx, const int* __restrict__ kidx,
                                              const int* __restrict__ nqv, const int* __restrict__ nkv,
                                              const float* __restrict__ denomg, float* __restrict__ vis) {
  int b = blockIdx.y;
  int nqb = nqv[b], nkb = nkv[b];
  int k0 = blockIdx.x * KT2;
  if (k0 >= nkb) return;
  __shared__ float lk2[KT2][65];
  __shared__ float lq2[64][65];
  __shared__ float ldi[64];
  int t = threadIdx.x;
  const int* qix = qidx + b * NN;
  const int* kix = kidx + b * NN;
  const float* khb = khat + (size_t)b * NN * 64;
  for (int idx = t; idx < KT2 * 64; idx += 256) {
    int k = idx >> 6, c = idx & 63;
    float v = 0.f;
    if (k0 + k < nkb) v = khb[(size_t)kix[k0 + k] * 64 + c];
    lk2[k][c] = v;
  }
  int k = t >> 3, g = t & 7;
  float vacc = 0.f;
  for (int i0 = 0; i0 < nqb; i0 += 64) {
    __syncthreads();
    for (int idx = t; idx < 64 * 64; idx += 256) {
      int i = idx >> 6, c = idx & 63;
      float v = 0.f;
      if (i0 + i < nqb) v = khb[(size_t)qix[i0 + i] * 64 + c];
      lq2[i][c] = v;
    }
    if (t < 64) {
      int qq = i0 + t;
      float d = (qq < nqb) ? denomg[b * NN + qq] : 0.f;
      ldi[t] = (d > 0.f) ? 1.f / d : 0.f;
    }
    __syncthreads();
    float s[8];
    #pragma unroll
    for (int u = 0; u < 8; ++u) s[u] = 0.f;
    for (int c = 0; c < 64; ++c) {
      float kv = lk2[k][c];
      #pragma unroll
      for (int u = 0; u < 8; ++u) s[u] += kv * lq2[g * 8 + u][c];
    }
    #pragma unroll
    for (int u = 0; u < 8; ++u) vacc += __expf(20.f * s[u]) * ldi[g * 8 + u];
  }
  vacc += __shfl_down(vacc, 4);
  vacc += __shfl_down(vacc, 2);
  vacc += __shfl_down(vacc, 1);
  if (g == 0 && k0 + k < nkb) vis[b * NN + kix[k0 + k]] = vacc;
}

// -------- 7a. default out = x (fp32 bit copy, 4 MB) ------------------------
__global__ __launch_bounds__(256) void k_copy(const uint4* __restrict__ src, uint4* __restrict__ dst, int n) {
  int i = blockIdx.x * 256 + threadIdx.x;
  if (i < n) dst[i] = src[i];
}

// -------- 7b. fusion epilogue over fg pixels (LDS ~43.5KB) -----------------
__global__ __launch_bounds__(256) void k_fusion(const float* __restrict__ x, const float* __restrict__ afc,
                                                const int* __restrict__ qidx, const int* __restrict__ nqv,
                                                const float* __restrict__ w1, const float* __restrict__ w2,
                                                const float* __restrict__ b2, const float* __restrict__ wf,
                                                float* __restrict__ outp) {
  int b = blockIdx.y;
  int nqb = nqv[b];
  int q0 = blockIdx.x * 16;
  if (q0 >= nqb) return;
  __shared__ bf16 w1s[128 * 64];   // w1s[j*64+c] = w1[c,j]  (bf16-rounded)
  __shared__ bf16 w2s[64 * 64];
  __shared__ bf16 wfs[128 * 64];
  __shared__ float b2s[64];
  __shared__ float px[4][64];
  __shared__ float pa[4][64];
  __shared__ float pf[4][64];
  int t = threadIdx.x;
  for (int idx = t; idx < 8192; idx += 256) {
    int j = idx >> 6, c = idx & 63;
    w1s[j * 64 + c] = __float2bfloat16(w1[c * 128 + j]);
    wfs[j * 64 + c] = __float2bfloat16(wf[c * 128 + j]);
  }
  for (int idx = t; idx < 4096; idx += 256) {
    int j = idx >> 6, c = idx & 63;
    w2s[j * 64 + c] = __float2bfloat16(w2[c * 64 + j]);
  }
  if (t < 64) b2s[t] = b2[t];
  int c = t & 63, pp = t >> 6;
  const int* qix = qidx + b * NN;
  const float* xb = x + (size_t)b * CC * NN;
  for (int it = 0; it < 4; ++it) {
    int qq = q0 + it * 4 + pp;
    bool valid = qq < nqb;
    int qp = valid ? qix[qq] : 0;
    __syncthreads();
    px[pp][c] = valid ? xb[(size_t)c * NN + qp] : 0.f;
    pa[pp][c] = valid ? afc[((size_t)b * NN + qq) * 64 + c] : 0.f;
    __syncthreads();
    float f1 = 0.f;
    for (int j = 0; j < 64; ++j) f1 += b2f(w1s[j * 64 + c]) * px[pp][j];
    for (int j = 0; j < 64; ++j) f1 += b2f(w1s[(64 + j) * 64 + c]) * pa[pp][j];
    pf[pp][c] = f1;
    __syncthreads();
    float z = b2s[c];
    for (int j = 0; j < 64; ++j) z += b2f(w2s[j * 64 + c]) * pf[pp][j];
    float sg = 1.f / (1.f + __expf(-z));
    pa[pp][c] = pa[pp][c] * (1.f - sg);
    __syncthreads();
    float fu = 0.f;
    for (int j = 0; j < 64; ++j) fu += b2f(wfs[j * 64 + c]) * px[pp][j];
    for (int j = 0; j < 64; ++j) fu += b2f(wfs[(64 + j) * 64 + c]) * pa[pp][j];
    if (valid) outp[((size_t)b * CC + c) * NN + qp] = fu;
  }
}

// -------- 8a. global max of visatt (non-negative -> uint atomicMax) --------
__global__ __launch_bounds__(256) void k_vmax(const float* __restrict__ vis, unsigned int* __restrict__ vmaxb) {
  int i = blockIdx.x * 256 + threadIdx.x;   // grid exactly 4*4096
  float v = vis[i];
  #pragma unroll
  for (int off = 32; off > 0; off >>= 1) v = fmaxf(v, __shfl_down(v, off));
  if ((threadIdx.x & 63) == 0) atomicMax(vmaxb, __float_as_uint(v));
}

// -------- 8b. x8 nearest upsample + normalize ------------------------------
__global__ __launch_bounds__(256) void k_upsample(const float* __restrict__ vis,
                                                  const unsigned int* __restrict__ vmaxb,
                                                  float* __restrict__ out2) {
  int i = blockIdx.x * 256 + threadIdx.x;   // < 4*512*512
  int b = i >> 18;
  int rem = i & 262143;
  int y = rem >> 9, x = rem & 511;
  float vm = __uint_as_float(vmaxb[0]);
  if (!(vm > 0.f)) vm = 1.f;
  out2[i] = vis[b * NN + (y >> 3) * 64 + (x >> 3)] / vm;
}

extern "C" void kernel_launch(void* const* d_in, const int* in_sizes, int n_in,
                              void* d_out, int out_size, void* d_ws, size_t ws_size,
                              hipStream_t stream) {
  const float* x    = (const float*)d_in[0];
  const float* mask = (const float*)d_in[1];
  const float* w1   = (const float*)d_in[2];
  const float* w2c  = (const float*)d_in[3];
  const float* fsw1 = (const float*)d_in[4];
  const float* fsw2 = (const float*)d_in[5];
  const float* fsb2 = (const float*)d_in[6];
  const float* fswf = (const float*)d_in[7];
  float* out = (float*)d_out;
  char* wsb = (char*)d_ws;

  float* afc = (float*)(wsb + WB_AFC);
  float* den = (float*)(wsb + WB_DEN);
  float* vis = (float*)(wsb + WB_VIS);
  int* qidx  = (int*)(wsb + WB_QIX);
  int* kidx  = (int*)(wsb + WB_KIX);
  unsigned char* mfl = (unsigned char*)(wsb + WB_MFL);
  int* nq = (int*)(wsb + WB_CNT);
  int* nk = nq + 4;
  unsigned int* vmaxb = (unsigned int*)(nq + 8);

  // scratch staged inside d_out (regions dead before their final writes):
  float* y1   = out;              // [0 .. 1M floats): conv1 out, then khat, then final out
  float* kx   = out + 1048576;    // [1M .. 2M): conv2 out, then attmask
  float* khat = out;

  k_maxpool<<<64, 256, 0, stream>>>(mask, mfl, vis, vmaxb);
  k_compact<<<4, 64, 0, stream>>>(mfl, qidx, kidx, nq, nk);
  k_conv<<<256, 256, 0, stream>>>(x, w1, nullptr, y1);
  k_conv<<<256, 256, 0, stream>>>(y1, w2c, x, kx);
  k_normT<<<256, 256, 0, stream>>>(kx, khat);
  k_att1<<<dim3(128, BB), 256, 0, stream>>>(khat, x, qidx, kidx, nq, nk, afc, den);
  k_att2<<<dim3(128, BB), 256, 0, stream>>>(khat, qidx, kidx, nq, nk, den, vis);
  k_copy<<<1024, 256, 0, stream>>>((const uint4*)x, (uint4*)out, 262144);
  k_fusion<<<dim3(256, BB), 256, 0, stream>>>(x, afc, qidx, nq, fsw1, fsw2, fsb2, fswf, out);
  k_vmax<<<64, 256, 0, stream>>>(vis, vmaxb);
  k_upsample<<<4096, 256, 0, stream>>>(vis, vmaxb, out + 1048576);
}

// Round 4
// 1288.557 us; speedup vs baseline: 1.4003x; 1.4003x over previous
//
#include <hip/hip_runtime.h>
#include <hip/hip_bf16.h>

typedef __hip_bfloat16 bf16;

#define BB 4
#define CC 64
#define NN 4096           // 64*64
#define MH 512
#define MW 512
#define KSPLIT 4

// ---- workspace layout (BYTE offsets; total ~4.5 MiB) ----
#define WB_AFC  ((size_t)0)         // f32[4*4096*64] att_fore UNNORMALIZED sums, pixel-major
#define WB_DEN  ((size_t)4194304)   // f32[4*4096] softmax denominators
#define WB_VIS  ((size_t)4259840)   // f32[4*4096] visatt
#define WB_QIX  ((size_t)4325376)   // int[4*4096]
#define WB_KIX  ((size_t)4390912)   // int[4*4096]
#define WB_MFL  ((size_t)4456448)   // uchar[4*4096]
#define WB_CNT  ((size_t)4472832)   // int nq[4]; int nk[4]; uint vmaxbits

__device__ __forceinline__ float b2f(bf16 v) { return __bfloat162float(v); }

// ------- 1. maxpool 8x8 on mask + zero-init vis/den/afc/vmax ---------------
__global__ __launch_bounds__(256) void k_maxpool(const float* __restrict__ mask,
                                                 unsigned char* __restrict__ mfl,
                                                 float* __restrict__ vis,
                                                 float* __restrict__ den,
                                                 float* __restrict__ afc,
                                                 unsigned int* __restrict__ vmaxb) {
  int i = blockIdx.x * 256 + threadIdx.x;          // < 4*4096
  int b = i >> 12, p = i & 4095;
  int py = p >> 6, px = p & 63;
  const float* mb = mask + (size_t)b * MH * MW + (py * 8) * MW + px * 8;
  float mx = 0.f;
  #pragma unroll
  for (int dy = 0; dy < 8; ++dy) {
    const float4* r4 = (const float4*)(mb + dy * MW);
    float4 a = r4[0], c = r4[1];
    mx = fmaxf(mx, fmaxf(fmaxf(a.x, a.y), fmaxf(a.z, a.w)));
    mx = fmaxf(mx, fmaxf(fmaxf(c.x, c.y), fmaxf(c.z, c.w)));
  }
  mfl[i] = (mx > 0.f) ? 1 : 0;
  vis[i] = 0.f;
  den[i] = 0.f;
  float4* az = (float4*)(afc + (size_t)i * 64);
  float4 z = make_float4(0.f, 0.f, 0.f, 0.f);
  #pragma unroll
  for (int j = 0; j < 16; ++j) az[j] = z;
  if (i == 0) vmaxb[0] = 0u;
}

// ---------------- 2. fg/bg index compaction (1 wave per batch) -------------
__global__ __launch_bounds__(64) void k_compact(const unsigned char* __restrict__ mfl,
                                                int* __restrict__ qidx, int* __restrict__ kidx,
                                                int* __restrict__ nq, int* __restrict__ nk) {
  int b = blockIdx.x, lane = threadIdx.x;
  int qb = 0, kb = 0;
  for (int it = 0; it < 64; ++it) {
    int p = it * 64 + lane;
    bool f = mfl[b * NN + p] != 0;
    unsigned long long bal = __ballot(f);
    int before = __popcll(bal & ((1ULL << lane) - 1ULL));
    if (f)  qidx[b * NN + qb + before] = p;
    if (!f) kidx[b * NN + kb + (lane - before)] = p;
    int cnt = __popcll(bal);
    qb += cnt; kb += 64 - cnt;
  }
  if (lane == 0) { nq[b] = qb; nk[b] = kb; }
}

// -------- 3. conv3x3(pad1) + instance-norm (+ optional residual) + relu ----
__global__ __launch_bounds__(256) void k_conv(const float* __restrict__ in,
                                              const float* __restrict__ wts,
                                              const float* __restrict__ addsrc,
                                              float* __restrict__ outp) {
  int b = blockIdx.x >> 6, co = blockIdx.x & 63;
  __shared__ float tile[66 * 68];
  __shared__ float rsum[4], rsq[4];
  int t = threadIdx.x;
  int tx = (t & 15) * 4, ty = (t >> 4) * 4;
  float acc[16];
  #pragma unroll
  for (int i = 0; i < 16; ++i) acc[i] = 0.f;
  const float* inb = in + (size_t)b * CC * NN;
  const float* wb = wts + (size_t)(co * CC) * 9;
  for (int ci = 0; ci < CC; ++ci) {
    __syncthreads();
    for (int idx = t; idx < 66 * 66; idx += 256) {
      int r = idx / 66, cc2 = idx - r * 66;
      int iy = r - 1, ix = cc2 - 1;
      float v = 0.f;
      if ((unsigned)iy < 64u && (unsigned)ix < 64u) v = inb[ci * NN + iy * 64 + ix];
      tile[r * 68 + cc2] = v;
    }
    __syncthreads();
    float w9[9];
    #pragma unroll
    for (int k = 0; k < 9; ++k) w9[k] = wb[ci * 9 + k];
    float patch[6][6];
    #pragma unroll
    for (int r = 0; r < 6; ++r)
      #pragma unroll
      for (int c = 0; c < 6; ++c) patch[r][c] = tile[(ty + r) * 68 + tx + c];
    #pragma unroll
    for (int iy = 0; iy < 4; ++iy)
      #pragma unroll
      for (int ix = 0; ix < 4; ++ix) {
        float a = acc[iy * 4 + ix];
        #pragma unroll
        for (int dy = 0; dy < 3; ++dy)
          #pragma unroll
          for (int dx = 0; dx < 3; ++dx) a += w9[dy * 3 + dx] * patch[iy + dy][ix + dx];
        acc[iy * 4 + ix] = a;
      }
  }
  float s1 = 0.f, s2 = 0.f;
  #pragma unroll
  for (int i = 0; i < 16; ++i) { s1 += acc[i]; s2 += acc[i] * acc[i]; }
  #pragma unroll
  for (int off = 32; off > 0; off >>= 1) { s1 += __shfl_down(s1, off); s2 += __shfl_down(s2, off); }
  if ((t & 63) == 0) { rsum[t >> 6] = s1; rsq[t >> 6] = s2; }
  __syncthreads();
  s1 = rsum[0] + rsum[1] + rsum[2] + rsum[3];
  s2 = rsq[0] + rsq[1] + rsq[2] + rsq[3];
  float mean = s1 * (1.f / NN);
  float var = fmaxf(s2 * (1.f / NN) - mean * mean, 0.f);
  float inv = rsqrtf(var + 1e-5f);
  float* ob = outp + ((size_t)b * CC + co) * NN;
  const float* ab = addsrc ? addsrc + ((size_t)b * CC + co) * NN : nullptr;
  #pragma unroll
  for (int iy = 0; iy < 4; ++iy)
    #pragma unroll
    for (int ix = 0; ix < 4; ++ix) {
      int p = (ty + iy) * 64 + tx + ix;
      float v = (acc[iy * 4 + ix] - mean) * inv;
      if (ab) v += ab[p];
      ob[p] = fmaxf(v, 0.f);
    }
}

// -------- 4. per-pixel channel L2-normalize + transpose to pixel-major -----
__global__ __launch_bounds__(256) void k_normT(const float* __restrict__ kx,
                                               float* __restrict__ khat) {
  int b = blockIdx.x >> 6, p0 = (blockIdx.x & 63) * 64;
  __shared__ float lk[64][65];
  __shared__ float inv[64];
  int t = threadIdx.x;
  const float* kb = kx + (size_t)b * CC * NN + p0;
  for (int idx = t; idx < 4096; idx += 256) {
    int c = idx >> 6, j = idx & 63;
    lk[j][c] = kb[c * NN + j];
  }
  __syncthreads();
  if (t < 64) {
    float s = 0.f;
    for (int c = 0; c < 64; ++c) { float v = lk[t][c]; s += v * v; }
    inv[t] = 1.f / (sqrtf(s) + 1e-8f);
  }
  __syncthreads();
  float* kh = khat + ((size_t)b * NN + p0) * 64;
  for (int idx = t; idx < 4096; idx += 256) {
    int j = idx >> 6, c = idx & 63;
    kh[j * 64 + c] = lk[j][c] * inv[j];
  }
}

// -------- 5. attention pass 1: register-tiled, K-split, atomic combine -----
// block: 64 q x (nk/KSPLIT) keys in 64-wide tiles; thread: 4q x 4k.
__global__ __launch_bounds__(256) void k_att1(const float* __restrict__ khat, const float* __restrict__ x,
                                              const int* __restrict__ qidx, const int* __restrict__ kidx,
                                              const int* __restrict__ nqv, const int* __restrict__ nkv,
                                              float* __restrict__ afc, float* __restrict__ den) {
  int b = blockIdx.y;
  int nqb = nqv[b], nkb = nkv[b];
  int q0 = (blockIdx.x >> 2) * 64;
  int part = blockIdx.x & 3;
  if (q0 >= nqb) return;
  int kbeg = (part * nkb) >> 2;
  int kend = ((part + 1) * nkb) >> 2;
  __shared__ float lqT[64][68];   // [c][q]
  __shared__ float lkT[64][68];   // [c][k]
  __shared__ float lv [64][68];   // [k][c]
  __shared__ float eT [32][68];   // [k-half][q]
  int t = threadIdx.x;
  int tq = t >> 4, tk = t & 15;
  const int* qix = qidx + b * NN;
  const int* kix = kidx + b * NN;
  const float* khb = khat + (size_t)b * (NN * 64);
  const float* xb  = x + (size_t)b * (CC * NN);
  for (int idx = t; idx < 4096; idx += 256) {
    int q = idx >> 6, c = idx & 63;                 // lanes: consecutive c (coalesced)
    float v = 0.f;
    if (q0 + q < nqb) v = khb[(size_t)qix[q0 + q] * 64 + c];
    lqT[c][q] = v;
  }
  float o[4][4] = {};
  float dnq[4] = {};
  for (int j0 = kbeg; j0 < kend; j0 += 64) {
    __syncthreads();
    for (int idx = t; idx < 4096; idx += 256) {     // K^T stage: coalesced khat rows
      int k = idx >> 6, c = idx & 63;
      int kk = j0 + k;
      lkT[c][k] = (kk < kend) ? khb[(size_t)kix[kk] * 64 + c] : 0.f;
    }
    for (int idx = t; idx < 4096; idx += 256) {     // V stage: windowed gather on x
      int c = idx >> 6, k = idx & 63;
      int kk = j0 + k;
      lv[k][c] = (kk < kend) ? xb[(size_t)c * NN + kix[kk]] : 0.f;
    }
    __syncthreads();
    float s[4][4] = {};
    for (int c = 0; c < 64; ++c) {
      float4 q4 = *(const float4*)&lqT[c][tq * 4];
      float4 k4 = *(const float4*)&lkT[c][tk * 4];
      float qa[4] = {q4.x, q4.y, q4.z, q4.w};
      float ka[4] = {k4.x, k4.y, k4.z, k4.w};
      #pragma unroll
      for (int i = 0; i < 4; ++i)
        #pragma unroll
        for (int j = 0; j < 4; ++j) s[i][j] += qa[i] * ka[j];
    }
    float e[4][4];
    #pragma unroll
    for (int j = 0; j < 4; ++j) {
      bool kval = (j0 + tk * 4 + j) < kend;
      #pragma unroll
      for (int i = 0; i < 4; ++i) {
        float ev = kval ? __expf(20.f * s[i][j]) : 0.f;
        e[i][j] = ev;
        dnq[i] += ev;
      }
    }
    #pragma unroll
    for (int h = 0; h < 2; ++h) {                   // PV in two 32-key halves (LDS budget)
      __syncthreads();
      if ((tk >> 3) == h) {
        #pragma unroll
        for (int j = 0; j < 4; ++j)
          *(float4*)&eT[(tk & 7) * 4 + j][tq * 4] = make_float4(e[0][j], e[1][j], e[2][j], e[3][j]);
      }
      __syncthreads();
      for (int k2 = 0; k2 < 32; ++k2) {
        int k = h * 32 + k2;
        float4 e4 = *(const float4*)&eT[k2][tq * 4];
        float4 v4 = *(const float4*)&lv[k][tk * 4];
        float ea[4] = {e4.x, e4.y, e4.z, e4.w};
        float va[4] = {v4.x, v4.y, v4.z, v4.w};
        #pragma unroll
        for (int i = 0; i < 4; ++i)
          #pragma unroll
          for (int j = 0; j < 4; ++j) o[i][j] += ea[i] * va[j];
      }
    }
  }
  #pragma unroll
  for (int i = 0; i < 4; ++i) {
    float v = dnq[i];
    v += __shfl_down(v, 8); v += __shfl_down(v, 4); v += __shfl_down(v, 2); v += __shfl_down(v, 1);
    dnq[i] = v;
  }
  if (tk == 0) {
    #pragma unroll
    for (int i = 0; i < 4; ++i) {
      int qq = q0 + tq * 4 + i;
      if (qq < nqb) atomicAdd(&den[b * NN + qq], dnq[i]);
    }
  }
  #pragma unroll
  for (int i = 0; i < 4; ++i) {
    int qq = q0 + tq * 4 + i;
    if (qq < nqb) {
      float* dst = afc + ((size_t)b * NN + qq) * 64 + tk * 4;
      #pragma unroll
      for (int j = 0; j < 4; ++j) atomicAdd(&dst[j], o[i][j]);
    }
  }
}

// -------- 6. attention pass 2: per-key visatt sums, register-tiled ---------
// block: 64 keys x (nq/KSPLIT) queries; thread: 4k x 4q.
__global__ __launch_bounds__(256) void k_att2(const float* __restrict__ khat,
                                              const int* __restrict__ qidx, const int* __restrict__ kidx,
                                              const int* __restrict__ nqv, const int* __restrict__ nkv,
                                              const float* __restrict__ den, float* __restrict__ vis) {
  int b = blockIdx.y;
  int nqb = nqv[b], nkb = nkv[b];
  int k0 = (blockIdx.x >> 2) * 64;
  int part = blockIdx.x & 3;
  if (k0 >= nkb) return;
  int qbeg = (part * nqb) >> 2;
  int qend = ((part + 1) * nqb) >> 2;
  __shared__ float lkT[64][68];   // [c][k]
  __shared__ float lqT[64][68];   // [c][q]
  __shared__ float w[64];
  int t = threadIdx.x;
  int tk = t >> 4, tq = t & 15;
  const int* qix = qidx + b * NN;
  const int* kix = kidx + b * NN;
  const float* khb = khat + (size_t)b * (NN * 64);
  for (int idx = t; idx < 4096; idx += 256) {
    int k = idx >> 6, c = idx & 63;
    lkT[c][k] = (k0 + k < nkb) ? khb[(size_t)kix[k0 + k] * 64 + c] : 0.f;
  }
  float vacc[4] = {};
  for (int i0 = qbeg; i0 < qend; i0 += 64) {
    __syncthreads();
    for (int idx = t; idx < 4096; idx += 256) {
      int q = idx >> 6, c = idx & 63;
      lqT[c][q] = (i0 + q < qend) ? khb[(size_t)qix[i0 + q] * 64 + c] : 0.f;
    }
    if (t < 64) {
      int qq = i0 + t;
      float d = (qq < qend) ? den[b * NN + qq] : 0.f;
      w[t] = (d > 0.f) ? 1.f / d : 0.f;
    }
    __syncthreads();
    float s[4][4] = {};
    for (int c = 0; c < 64; ++c) {
      float4 k4 = *(const float4*)&lkT[c][tk * 4];
      float4 q4 = *(const float4*)&lqT[c][tq * 4];
      float ka[4] = {k4.x, k4.y, k4.z, k4.w};
      float qa[4] = {q4.x, q4.y, q4.z, q4.w};
      #pragma unroll
      for (int i = 0; i < 4; ++i)
        #pragma unroll
        for (int j = 0; j < 4; ++j) s[i][j] += ka[i] * qa[j];
    }
    #pragma unroll
    for (int i = 0; i < 4; ++i) {
      bool kval = (k0 + tk * 4 + i) < nkb;
      #pragma unroll
      for (int j = 0; j < 4; ++j) {
        float ev = kval ? __expf(20.f * s[i][j]) : 0.f;
        vacc[i] += ev * w[tq * 4 + j];
      }
    }
  }
  #pragma unroll
  for (int i = 0; i < 4; ++i) {
    float v = vacc[i];
    v += __shfl_down(v, 8); v += __shfl_down(v, 4); v += __shfl_down(v, 2); v += __shfl_down(v, 1);
    vacc[i] = v;
  }
  if (tq == 0) {
    #pragma unroll
    for (int i = 0; i < 4; ++i) {
      int kk = k0 + tk * 4 + i;
      if (kk < nkb) atomicAdd(&vis[b * NN + kix[kk]], vacc[i]);
    }
  }
}

// -------- 7a. default out = x (fp32 bit copy, 4 MB) ------------------------
__global__ __launch_bounds__(256) void k_copy(const uint4* __restrict__ src, uint4* __restrict__ dst, int n) {
  int i = blockIdx.x * 256 + threadIdx.x;
  if (i < n) dst[i] = src[i];
}

// -------- 7b. fusion epilogue over fg pixels (LDS ~43.5KB) -----------------
__global__ __launch_bounds__(256) void k_fusion(const float* __restrict__ x, const float* __restrict__ afc,
                                                const float* __restrict__ den,
                                                const int* __restrict__ qidx, const int* __restrict__ nqv,
                                                const float* __restrict__ w1, const float* __restrict__ w2,
                                                const float* __restrict__ b2, const float* __restrict__ wf,
                                                float* __restrict__ outp) {
  int b = blockIdx.y;
  int nqb = nqv[b];
  int q0 = blockIdx.x * 16;
  if (q0 >= nqb) return;
  __shared__ bf16 w1s[128 * 64];
  __shared__ bf16 w2s[64 * 64];
  __shared__ bf16 wfs[128 * 64];
  __shared__ float b2s[64];
  __shared__ float px[4][64];
  __shared__ float pa[4][64];
  __shared__ float pf[4][64];
  int t = threadIdx.x;
  for (int idx = t; idx < 8192; idx += 256) {
    int j = idx >> 6, c = idx & 63;
    w1s[j * 64 + c] = __float2bfloat16(w1[c * 128 + j]);
    wfs[j * 64 + c] = __float2bfloat16(wf[c * 128 + j]);
  }
  for (int idx = t; idx < 4096; idx += 256) {
    int j = idx >> 6, c = idx & 63;
    w2s[j * 64 + c] = __float2bfloat16(w2[c * 64 + j]);
  }
  if (t < 64) b2s[t] = b2[t];
  int c = t & 63, pp = t >> 6;
  const int* qix = qidx + b * NN;
  const float* xb = x + (size_t)b * CC * NN;
  for (int it = 0; it < 4; ++it) {
    int qq = q0 + it * 4 + pp;
    bool valid = qq < nqb;
    int qp = valid ? qix[qq] : 0;
    float dq = valid ? den[b * NN + qq] : 1.f;
    float invd = (dq > 0.f) ? 1.f / dq : 0.f;
    __syncthreads();
    px[pp][c] = valid ? xb[(size_t)c * NN + qp] : 0.f;
    pa[pp][c] = valid ? afc[((size_t)b * NN + qq) * 64 + c] * invd : 0.f;
    __syncthreads();
    float f1 = 0.f;
    for (int j = 0; j < 64; ++j) f1 += b2f(w1s[j * 64 + c]) * px[pp][j];
    for (int j = 0; j < 64; ++j) f1 += b2f(w1s[(64 + j) * 64 + c]) * pa[pp][j];
    pf[pp][c] = f1;
    __syncthreads();
    float z = b2s[c];
    for (int j = 0; j < 64; ++j) z += b2f(w2s[j * 64 + c]) * pf[pp][j];
    float sg = 1.f / (1.f + __expf(-z));
    pa[pp][c] = pa[pp][c] * (1.f - sg);
    __syncthreads();
    float fu = 0.f;
    for (int j = 0; j < 64; ++j) fu += b2f(wfs[j * 64 + c]) * px[pp][j];
    for (int j = 0; j < 64; ++j) fu += b2f(wfs[(64 + j) * 64 + c]) * pa[pp][j];
    if (valid) outp[((size_t)b * CC + c) * NN + qp] = fu;
  }
}

// -------- 8a. global max of visatt -----------------------------------------
__global__ __launch_bounds__(256) void k_vmax(const float* __restrict__ vis, unsigned int* __restrict__ vmaxb) {
  int i = blockIdx.x * 256 + threadIdx.x;
  float v = vis[i];
  #pragma unroll
  for (int off = 32; off > 0; off >>= 1) v = fmaxf(v, __shfl_down(v, off));
  if ((threadIdx.x & 63) == 0) atomicMax(vmaxb, __float_as_uint(v));
}

// -------- 8b. x8 nearest upsample + normalize ------------------------------
__global__ __launch_bounds__(256) void k_upsample(const float* __restrict__ vis,
                                                  const unsigned int* __restrict__ vmaxb,
                                                  float* __restrict__ out2) {
  int i = blockIdx.x * 256 + threadIdx.x;
  int b = i >> 18;
  int rem = i & 262143;
  int y = rem >> 9, x = rem & 511;
  float vm = __uint_as_float(vmaxb[0]);
  if (!(vm > 0.f)) vm = 1.f;
  out2[i] = vis[b * NN + (y >> 3) * 64 + (x >> 3)] / vm;
}

extern "C" void kernel_launch(void* const* d_in, const int* in_sizes, int n_in,
                              void* d_out, int out_size, void* d_ws, size_t ws_size,
                              hipStream_t stream) {
  const float* x    = (const float*)d_in[0];
  const float* mask = (const float*)d_in[1];
  const float* w1   = (const float*)d_in[2];
  const float* w2c  = (const float*)d_in[3];
  const float* fsw1 = (const float*)d_in[4];
  const float* fsw2 = (const float*)d_in[5];
  const float* fsb2 = (const float*)d_in[6];
  const float* fswf = (const float*)d_in[7];
  float* out = (float*)d_out;
  char* wsb = (char*)d_ws;

  float* afc = (float*)(wsb + WB_AFC);
  float* den = (float*)(wsb + WB_DEN);
  float* vis = (float*)(wsb + WB_VIS);
  int* qidx  = (int*)(wsb + WB_QIX);
  int* kidx  = (int*)(wsb + WB_KIX);
  unsigned char* mfl = (unsigned char*)(wsb + WB_MFL);
  int* nq = (int*)(wsb + WB_CNT);
  int* nk = nq + 4;
  unsigned int* vmaxb = (unsigned int*)(nq + 8);

  // scratch staged inside d_out (regions dead before their final writes):
  float* y1   = out;              // conv1 out, then khat, then final out
  float* kx   = out + 1048576;    // conv2 out, then attmask
  float* khat = out;

  k_maxpool<<<64, 256, 0, stream>>>(mask, mfl, vis, den, afc, vmaxb);
  k_compact<<<4, 64, 0, stream>>>(mfl, qidx, kidx, nq, nk);
  k_conv<<<256, 256, 0, stream>>>(x, w1, nullptr, y1);
  k_conv<<<256, 256, 0, stream>>>(y1, w2c, x, kx);
  k_normT<<<256, 256, 0, stream>>>(kx, khat);
  k_att1<<<dim3(64 * KSPLIT, BB), 256, 0, stream>>>(khat, x, qidx, kidx, nq, nk, afc, den);
  k_att2<<<dim3(64 * KSPLIT, BB), 256, 0, stream>>>(khat, qidx, kidx, nq, nk, den, vis);
  k_copy<<<1024, 256, 0, stream>>>((const uint4*)x, (uint4*)out, 262144);
  k_fusion<<<dim3(256, BB), 256, 0, stream>>>(x, afc, den, qidx, nq, fsw1, fsw2, fsb2, fswf, out);
  k_vmax<<<64, 256, 0, stream>>>(vis, vmaxb);
  k_upsample<<<4096, 256, 0, stream>>>(vis, vmaxb, out + 1048576);
}

// Round 5
// 736.121 us; speedup vs baseline: 2.4511x; 1.7505x over previous
//
#include <hip/hip_runtime.h>
#include <hip/hip_bf16.h>

typedef __hip_bfloat16 bf16;

#define BB 4
#define CC 64
#define NN 4096           // 64*64
#define MH 512
#define MW 512
#define KSPLIT 4

// ---- workspace layout (BYTE offsets; total ~4.5 MiB) ----
#define WB_AFC  ((size_t)0)         // f32[4*4096*64] att_fore UNNORMALIZED sums, pixel-major
#define WB_DEN  ((size_t)4194304)   // f32[4*4096] softmax denominators
#define WB_VIS  ((size_t)4259840)   // f32[4*4096] visatt
#define WB_QIX  ((size_t)4325376)   // int[4*4096]
#define WB_KIX  ((size_t)4390912)   // int[4*4096]
#define WB_MFL  ((size_t)4456448)   // uchar[4*4096]
#define WB_CNT  ((size_t)4472832)   // int nq[4]; int nk[4]; uint vmaxbits (12 ints)
#define WB_STAT ((size_t)4472896)   // f32 gsum1[256]; gsq1[256]; gsum2[256]; gsq2[256]

__device__ __forceinline__ float b2f(bf16 v) { return __bfloat162float(v); }

// ------- 1. maxpool 8x8 on mask + zero-init vis/den/afc/stats/vmax ---------
__global__ __launch_bounds__(256) void k_maxpool(const float* __restrict__ mask,
                                                 unsigned char* __restrict__ mfl,
                                                 float* __restrict__ vis,
                                                 float* __restrict__ den,
                                                 float* __restrict__ afc,
                                                 float* __restrict__ gstat,
                                                 unsigned int* __restrict__ vmaxb) {
  int i = blockIdx.x * 256 + threadIdx.x;          // < 4*4096
  int b = i >> 12, p = i & 4095;
  int py = p >> 6, px = p & 63;
  const float* mb = mask + (size_t)b * MH * MW + (py * 8) * MW + px * 8;
  float mx = 0.f;
  #pragma unroll
  for (int dy = 0; dy < 8; ++dy) {
    const float4* r4 = (const float4*)(mb + dy * MW);
    float4 a = r4[0], c = r4[1];
    mx = fmaxf(mx, fmaxf(fmaxf(a.x, a.y), fmaxf(a.z, a.w)));
    mx = fmaxf(mx, fmaxf(fmaxf(c.x, c.y), fmaxf(c.z, c.w)));
  }
  mfl[i] = (mx > 0.f) ? 1 : 0;
  vis[i] = 0.f;
  den[i] = 0.f;
  if (i < 1024) gstat[i] = 0.f;
  float4* az = (float4*)(afc + (size_t)i * 64);
  float4 z = make_float4(0.f, 0.f, 0.f, 0.f);
  #pragma unroll
  for (int j = 0; j < 16; ++j) az[j] = z;
  if (i == 0) vmaxb[0] = 0u;
}

// ---------------- 2. fg/bg index compaction (1 wave per batch) -------------
__global__ __launch_bounds__(64) void k_compact(const unsigned char* __restrict__ mfl,
                                                int* __restrict__ qidx, int* __restrict__ kidx,
                                                int* __restrict__ nq, int* __restrict__ nk) {
  int b = blockIdx.x, lane = threadIdx.x;
  int qb = 0, kb = 0;
  for (int it = 0; it < 64; ++it) {
    int p = it * 64 + lane;
    bool f = mfl[b * NN + p] != 0;
    unsigned long long bal = __ballot(f);
    int before = __popcll(bal & ((1ULL << lane) - 1ULL));
    if (f)  qidx[b * NN + qb + before] = p;
    if (!f) kidx[b * NN + kb + (lane - before)] = p;
    int cnt = __popcll(bal);
    qb += cnt; kb += 64 - cnt;
  }
  if (lane == 0) { nq[b] = qb; nk[b] = kb; }
}

// -------- 3a. conv3x3(pad1), raw output + per-(b,co) partial stats ---------
// block = (b, co-group of 4, row-band of 8 rows). 512 blocks, 256 threads.
__global__ __launch_bounds__(256) void k_conv_raw(const float* __restrict__ in,
                                                  const float* __restrict__ wts,
                                                  float* __restrict__ yraw,
                                                  float* __restrict__ gsum,
                                                  float* __restrict__ gsq) {
  int b = blockIdx.y;
  int band = blockIdx.x & 7;
  int cg = blockIdx.x >> 3;        // 0..15
  int r0 = band * 8;
  __shared__ float wl[4 * 768];    // [co][ci*12 + tap] (tap-padded for aligned b128)
  __shared__ float tile[10 * 68];
  int t = threadIdx.x;
  for (int idx = t; idx < 4 * 576; idx += 256) {
    int co = idx / 576, rem = idx - co * 576;
    int ci = rem / 9, tap = rem - ci * 9;
    wl[co * 768 + ci * 12 + tap] = wts[(size_t)((cg * 4 + co) * 64) * 9 + rem];
  }
  int co = t >> 6, g = t & 63;     // wave-uniform co
  int gr = g >> 3;                 // row within band (0..7)
  int c0 = (g & 7) * 8;            // col start
  const float* inb = in + (size_t)b * CC * NN;
  float acc[8] = {};
  for (int ci = 0; ci < 64; ++ci) {
    __syncthreads();
    for (int idx = t; idx < 680; idx += 256) {
      int row = idx / 68, col = idx - row * 68;
      int gy = r0 - 1 + row, gx = col - 1;
      float v = 0.f;
      if (col < 66 && (unsigned)gy < 64u && (unsigned)gx < 64u)
        v = inb[ci * NN + gy * 64 + gx];
      tile[idx] = v;
    }
    __syncthreads();
    const float* wr = &wl[co * 768 + ci * 12];
    float4 wa = *(const float4*)wr;
    float4 wb4 = *(const float4*)(wr + 4);
    float w9[9] = {wa.x, wa.y, wa.z, wa.w, wb4.x, wb4.y, wb4.z, wb4.w, wr[8]};
    float patch[3][10];
    #pragma unroll
    for (int dy = 0; dy < 3; ++dy) {
      const float* rp = &tile[(gr + dy) * 68 + c0];
      float4 a = *(const float4*)rp;
      float4 b4 = *(const float4*)(rp + 4);
      float2 c2 = *(const float2*)(rp + 8);
      patch[dy][0] = a.x;  patch[dy][1] = a.y;  patch[dy][2] = a.z;  patch[dy][3] = a.w;
      patch[dy][4] = b4.x; patch[dy][5] = b4.y; patch[dy][6] = b4.z; patch[dy][7] = b4.w;
      patch[dy][8] = c2.x; patch[dy][9] = c2.y;
    }
    #pragma unroll
    for (int dy = 0; dy < 3; ++dy)
      #pragma unroll
      for (int dx = 0; dx < 3; ++dx) {
        float w = w9[dy * 3 + dx];
        #pragma unroll
        for (int j = 0; j < 8; ++j) acc[j] += w * patch[dy][j + dx];
      }
  }
  int bc = b * CC + cg * 4 + co;
  float* yo = yraw + (size_t)bc * NN + (r0 + gr) * 64 + c0;
  *(float4*)yo       = make_float4(acc[0], acc[1], acc[2], acc[3]);
  *(float4*)(yo + 4) = make_float4(acc[4], acc[5], acc[6], acc[7]);
  float s1 = 0.f, s2 = 0.f;
  #pragma unroll
  for (int j = 0; j < 8; ++j) { s1 += acc[j]; s2 += acc[j] * acc[j]; }
  #pragma unroll
  for (int off = 32; off > 0; off >>= 1) { s1 += __shfl_down(s1, off); s2 += __shfl_down(s2, off); }
  if (g == 0) { atomicAdd(&gsum[bc], s1); atomicAdd(&gsq[bc], s2); }
}

// -------- 3b. instance-norm finalize (+ optional residual) + relu, in place
__global__ __launch_bounds__(256) void k_inorm(float* __restrict__ y,
                                               const float* __restrict__ gsum,
                                               const float* __restrict__ gsq,
                                               const float* __restrict__ addsrc) {
  int bc = blockIdx.x;             // b*64+co
  int t = threadIdx.x;
  float mean = gsum[bc] * (1.f / NN);
  float var = fmaxf(gsq[bc] * (1.f / NN) - mean * mean, 0.f);
  float inv = rsqrtf(var + 1e-5f);
  float* yp = y + (size_t)bc * NN;
  const float* ap = addsrc ? addsrc + (size_t)bc * NN : nullptr;
  #pragma unroll
  for (int ch = 0; ch < 4; ++ch) {
    int p = ch * 1024 + t * 4;
    float4 v = *(const float4*)(yp + p);
    v.x = (v.x - mean) * inv; v.y = (v.y - mean) * inv;
    v.z = (v.z - mean) * inv; v.w = (v.w - mean) * inv;
    if (ap) {
      float4 a = *(const float4*)(ap + p);
      v.x += a.x; v.y += a.y; v.z += a.z; v.w += a.w;
    }
    v.x = fmaxf(v.x, 0.f); v.y = fmaxf(v.y, 0.f);
    v.z = fmaxf(v.z, 0.f); v.w = fmaxf(v.w, 0.f);
    *(float4*)(yp + p) = v;
  }
}

// -------- 4. per-pixel channel L2-normalize + transpose to pixel-major -----
__global__ __launch_bounds__(256) void k_normT(const float* __restrict__ kx,
                                               float* __restrict__ khat) {
  int b = blockIdx.x >> 6, p0 = (blockIdx.x & 63) * 64;
  __shared__ float lk[64][65];
  __shared__ float inv[64];
  int t = threadIdx.x;
  const float* kb = kx + (size_t)b * CC * NN + p0;
  for (int idx = t; idx < 4096; idx += 256) {
    int c = idx >> 6, j = idx & 63;
    lk[j][c] = kb[c * NN + j];
  }
  __syncthreads();
  if (t < 64) {
    float s = 0.f;
    for (int c = 0; c < 64; ++c) { float v = lk[t][c]; s += v * v; }
    inv[t] = 1.f / (sqrtf(s) + 1e-8f);
  }
  __syncthreads();
  float* kh = khat + ((size_t)b * NN + p0) * 64;
  for (int idx = t; idx < 4096; idx += 256) {
    int j = idx >> 6, c = idx & 63;
    kh[j * 64 + c] = lk[j][c] * inv[j];
  }
}

// -------- 5. attention pass 1: register-tiled, K-split, atomic combine -----
__global__ __launch_bounds__(256) void k_att1(const float* __restrict__ khat, const float* __restrict__ x,
                                              const int* __restrict__ qidx, const int* __restrict__ kidx,
                                              const int* __restrict__ nqv, const int* __restrict__ nkv,
                                              float* __restrict__ afc, float* __restrict__ den) {
  int b = blockIdx.y;
  int nqb = nqv[b], nkb = nkv[b];
  int q0 = (blockIdx.x >> 2) * 64;
  int part = blockIdx.x & 3;
  if (q0 >= nqb) return;
  int kbeg = (part * nkb) >> 2;
  int kend = ((part + 1) * nkb) >> 2;
  __shared__ float lqT[64][68];   // [c][q]
  __shared__ float lkT[64][68];   // [c][k]
  __shared__ float lv [64][68];   // [k][c]
  __shared__ float eT [32][68];   // [k-half][q]
  int t = threadIdx.x;
  int tq = t >> 4, tk = t & 15;
  const int* qix = qidx + b * NN;
  const int* kix = kidx + b * NN;
  const float* khb = khat + (size_t)b * (NN * 64);
  const float* xb  = x + (size_t)b * (CC * NN);
  for (int idx = t; idx < 4096; idx += 256) {
    int q = idx >> 6, c = idx & 63;
    float v = 0.f;
    if (q0 + q < nqb) v = khb[(size_t)qix[q0 + q] * 64 + c];
    lqT[c][q] = v;
  }
  float o[4][4] = {};
  float dnq[4] = {};
  for (int j0 = kbeg; j0 < kend; j0 += 64) {
    __syncthreads();
    for (int idx = t; idx < 4096; idx += 256) {
      int k = idx >> 6, c = idx & 63;
      int kk = j0 + k;
      lkT[c][k] = (kk < kend) ? khb[(size_t)kix[kk] * 64 + c] : 0.f;
    }
    for (int idx = t; idx < 4096; idx += 256) {
      int c = idx >> 6, k = idx & 63;
      int kk = j0 + k;
      lv[k][c] = (kk < kend) ? xb[(size_t)c * NN + kix[kk]] : 0.f;
    }
    __syncthreads();
    float s[4][4] = {};
    for (int c = 0; c < 64; ++c) {
      float4 q4 = *(const float4*)&lqT[c][tq * 4];
      float4 k4 = *(const float4*)&lkT[c][tk * 4];
      float qa[4] = {q4.x, q4.y, q4.z, q4.w};
      float ka[4] = {k4.x, k4.y, k4.z, k4.w};
      #pragma unroll
      for (int i = 0; i < 4; ++i)
        #pragma unroll
        for (int j = 0; j < 4; ++j) s[i][j] += qa[i] * ka[j];
    }
    float e[4][4];
    #pragma unroll
    for (int j = 0; j < 4; ++j) {
      bool kval = (j0 + tk * 4 + j) < kend;
      #pragma unroll
      for (int i = 0; i < 4; ++i) {
        float ev = kval ? __expf(20.f * s[i][j]) : 0.f;
        e[i][j] = ev;
        dnq[i] += ev;
      }
    }
    #pragma unroll
    for (int h = 0; h < 2; ++h) {
      __syncthreads();
      if ((tk >> 3) == h) {
        #pragma unroll
        for (int j = 0; j < 4; ++j)
          *(float4*)&eT[(tk & 7) * 4 + j][tq * 4] = make_float4(e[0][j], e[1][j], e[2][j], e[3][j]);
      }
      __syncthreads();
      for (int k2 = 0; k2 < 32; ++k2) {
        int k = h * 32 + k2;
        float4 e4 = *(const float4*)&eT[k2][tq * 4];
        float4 v4 = *(const float4*)&lv[k][tk * 4];
        float ea[4] = {e4.x, e4.y, e4.z, e4.w};
        float va[4] = {v4.x, v4.y, v4.z, v4.w};
        #pragma unroll
        for (int i = 0; i < 4; ++i)
          #pragma unroll
          for (int j = 0; j < 4; ++j) o[i][j] += ea[i] * va[j];
      }
    }
  }
  #pragma unroll
  for (int i = 0; i < 4; ++i) {
    float v = dnq[i];
    v += __shfl_down(v, 8); v += __shfl_down(v, 4); v += __shfl_down(v, 2); v += __shfl_down(v, 1);
    dnq[i] = v;
  }
  if (tk == 0) {
    #pragma unroll
    for (int i = 0; i < 4; ++i) {
      int qq = q0 + tq * 4 + i;
      if (qq < nqb) atomicAdd(&den[b * NN + qq], dnq[i]);
    }
  }
  #pragma unroll
  for (int i = 0; i < 4; ++i) {
    int qq = q0 + tq * 4 + i;
    if (qq < nqb) {
      float* dst = afc + ((size_t)b * NN + qq) * 64 + tk * 4;
      #pragma unroll
      for (int j = 0; j < 4; ++j) atomicAdd(&dst[j], o[i][j]);
    }
  }
}

// -------- 6. attention pass 2: per-key visatt sums, register-tiled ---------
__global__ __launch_bounds__(256) void k_att2(const float* __restrict__ khat,
                                              const int* __restrict__ qidx, const int* __restrict__ kidx,
                                              const int* __restrict__ nqv, const int* __restrict__ nkv,
                                              const float* __restrict__ den, float* __restrict__ vis) {
  int b = blockIdx.y;
  int nqb = nqv[b], nkb = nkv[b];
  int k0 = (blockIdx.x >> 2) * 64;
  int part = blockIdx.x & 3;
  if (k0 >= nkb) return;
  int qbeg = (part * nqb) >> 2;
  int qend = ((part + 1) * nqb) >> 2;
  __shared__ float lkT[64][68];
  __shared__ float lqT[64][68];
  __shared__ float w[64];
  int t = threadIdx.x;
  int tk = t >> 4, tq = t & 15;
  const int* qix = qidx + b * NN;
  const int* kix = kidx + b * NN;
  const float* khb = khat + (size_t)b * (NN * 64);
  for (int idx = t; idx < 4096; idx += 256) {
    int k = idx >> 6, c = idx & 63;
    lkT[c][k] = (k0 + k < nkb) ? khb[(size_t)kix[k0 + k] * 64 + c] : 0.f;
  }
  float vacc[4] = {};
  for (int i0 = qbeg; i0 < qend; i0 += 64) {
    __syncthreads();
    for (int idx = t; idx < 4096; idx += 256) {
      int q = idx >> 6, c = idx & 63;
      lqT[c][q] = (i0 + q < qend) ? khb[(size_t)qix[i0 + q] * 64 + c] : 0.f;
    }
    if (t < 64) {
      int qq = i0 + t;
      float d = (qq < qend) ? den[b * NN + qq] : 0.f;
      w[t] = (d > 0.f) ? 1.f / d : 0.f;
    }
    __syncthreads();
    float s[4][4] = {};
    for (int c = 0; c < 64; ++c) {
      float4 k4 = *(const float4*)&lkT[c][tk * 4];
      float4 q4 = *(const float4*)&lqT[c][tq * 4];
      float ka[4] = {k4.x, k4.y, k4.z, k4.w};
      float qa[4] = {q4.x, q4.y, q4.z, q4.w};
      #pragma unroll
      for (int i = 0; i < 4; ++i)
        #pragma unroll
        for (int j = 0; j < 4; ++j) s[i][j] += ka[i] * qa[j];
    }
    #pragma unroll
    for (int i = 0; i < 4; ++i) {
      bool kval = (k0 + tk * 4 + i) < nkb;
      #pragma unroll
      for (int j = 0; j < 4; ++j) {
        float ev = kval ? __expf(20.f * s[i][j]) : 0.f;
        vacc[i] += ev * w[tq * 4 + j];
      }
    }
  }
  #pragma unroll
  for (int i = 0; i < 4; ++i) {
    float v = vacc[i];
    v += __shfl_down(v, 8); v += __shfl_down(v, 4); v += __shfl_down(v, 2); v += __shfl_down(v, 1);
    vacc[i] = v;
  }
  if (tq == 0) {
    #pragma unroll
    for (int i = 0; i < 4; ++i) {
      int kk = k0 + tk * 4 + i;
      if (kk < nkb) atomicAdd(&vis[b * NN + kix[kk]], vacc[i]);
    }
  }
}

// -------- 7a. default out = x (fp32 bit copy, 4 MB) ------------------------
__global__ __launch_bounds__(256) void k_copy(const uint4* __restrict__ src, uint4* __restrict__ dst, int n) {
  int i = blockIdx.x * 256 + threadIdx.x;
  if (i < n) dst[i] = src[i];
}

// -------- 7b. fusion epilogue over fg pixels (LDS ~43.5KB) -----------------
__global__ __launch_bounds__(256) void k_fusion(const float* __restrict__ x, const float* __restrict__ afc,
                                                const float* __restrict__ den,
                                                const int* __restrict__ qidx, const int* __restrict__ nqv,
                                                const float* __restrict__ w1, const float* __restrict__ w2,
                                                const float* __restrict__ b2, const float* __restrict__ wf,
                                                float* __restrict__ outp) {
  int b = blockIdx.y;
  int nqb = nqv[b];
  int q0 = blockIdx.x * 16;
  if (q0 >= nqb) return;
  __shared__ bf16 w1s[128 * 64];
  __shared__ bf16 w2s[64 * 64];
  __shared__ bf16 wfs[128 * 64];
  __shared__ float b2s[64];
  __shared__ float px[4][64];
  __shared__ float pa[4][64];
  __shared__ float pf[4][64];
  int t = threadIdx.x;
  for (int idx = t; idx < 8192; idx += 256) {
    int j = idx >> 6, c = idx & 63;
    w1s[j * 64 + c] = __float2bfloat16(w1[c * 128 + j]);
    wfs[j * 64 + c] = __float2bfloat16(wf[c * 128 + j]);
  }
  for (int idx = t; idx < 4096; idx += 256) {
    int j = idx >> 6, c = idx & 63;
    w2s[j * 64 + c] = __float2bfloat16(w2[c * 64 + j]);
  }
  if (t < 64) b2s[t] = b2[t];
  int c = t & 63, pp = t >> 6;
  const int* qix = qidx + b * NN;
  const float* xb = x + (size_t)b * CC * NN;
  for (int it = 0; it < 4; ++it) {
    int qq = q0 + it * 4 + pp;
    bool valid = qq < nqb;
    int qp = valid ? qix[qq] : 0;
    float dq = valid ? den[b * NN + qq] : 1.f;
    float invd = (dq > 0.f) ? 1.f / dq : 0.f;
    __syncthreads();
    px[pp][c] = valid ? xb[(size_t)c * NN + qp] : 0.f;
    pa[pp][c] = valid ? afc[((size_t)b * NN + qq) * 64 + c] * invd : 0.f;
    __syncthreads();
    float f1 = 0.f;
    for (int j = 0; j < 64; ++j) f1 += b2f(w1s[j * 64 + c]) * px[pp][j];
    for (int j = 0; j < 64; ++j) f1 += b2f(w1s[(64 + j) * 64 + c]) * pa[pp][j];
    pf[pp][c] = f1;
    __syncthreads();
    float z = b2s[c];
    for (int j = 0; j < 64; ++j) z += b2f(w2s[j * 64 + c]) * pf[pp][j];
    float sg = 1.f / (1.f + __expf(-z));
    pa[pp][c] = pa[pp][c] * (1.f - sg);
    __syncthreads();
    float fu = 0.f;
    for (int j = 0; j < 64; ++j) fu += b2f(wfs[j * 64 + c]) * px[pp][j];
    for (int j = 0; j < 64; ++j) fu += b2f(wfs[(64 + j) * 64 + c]) * pa[pp][j];
    if (valid) outp[((size_t)b * CC + c) * NN + qp] = fu;
  }
}

// -------- 8a. global max of visatt -----------------------------------------
__global__ __launch_bounds__(256) void k_vmax(const float* __restrict__ vis, unsigned int* __restrict__ vmaxb) {
  int i = blockIdx.x * 256 + threadIdx.x;
  float v = vis[i];
  #pragma unroll
  for (int off = 32; off > 0; off >>= 1) v = fmaxf(v, __shfl_down(v, off));
  if ((threadIdx.x & 63) == 0) atomicMax(vmaxb, __float_as_uint(v));
}

// -------- 8b. x8 nearest upsample + normalize ------------------------------
__global__ __launch_bounds__(256) void k_upsample(const float* __restrict__ vis,
                                                  const unsigned int* __restrict__ vmaxb,
                                                  float* __restrict__ out2) {
  int i = blockIdx.x * 256 + threadIdx.x;
  int b = i >> 18;
  int rem = i & 262143;
  int y = rem >> 9, x = rem & 511;
  float vm = __uint_as_float(vmaxb[0]);
  if (!(vm > 0.f)) vm = 1.f;
  out2[i] = vis[b * NN + (y >> 3) * 64 + (x >> 3)] / vm;
}

extern "C" void kernel_launch(void* const* d_in, const int* in_sizes, int n_in,
                              void* d_out, int out_size, void* d_ws, size_t ws_size,
                              hipStream_t stream) {
  const float* x    = (const float*)d_in[0];
  const float* mask = (const float*)d_in[1];
  const float* w1   = (const float*)d_in[2];
  const float* w2c  = (const float*)d_in[3];
  const float* fsw1 = (const float*)d_in[4];
  const float* fsw2 = (const float*)d_in[5];
  const float* fsb2 = (const float*)d_in[6];
  const float* fswf = (const float*)d_in[7];
  float* out = (float*)d_out;
  char* wsb = (char*)d_ws;

  float* afc = (float*)(wsb + WB_AFC);
  float* den = (float*)(wsb + WB_DEN);
  float* vis = (float*)(wsb + WB_VIS);
  int* qidx  = (int*)(wsb + WB_QIX);
  int* kidx  = (int*)(wsb + WB_KIX);
  unsigned char* mfl = (unsigned char*)(wsb + WB_MFL);
  int* nq = (int*)(wsb + WB_CNT);
  int* nk = nq + 4;
  unsigned int* vmaxb = (unsigned int*)(nq + 8);
  float* gstat = (float*)(wsb + WB_STAT);   // 1024 floats, zeroed by k_maxpool
  float* gsum1 = gstat;
  float* gsq1  = gstat + 256;
  float* gsum2 = gstat + 512;
  float* gsq2  = gstat + 768;

  // scratch staged inside d_out (regions dead before their final writes):
  float* y1   = out;              // conv1 raw/normed, then khat, then final out
  float* kx   = out + 1048576;    // conv2 raw/normed, then attmask
  float* khat = out;

  k_maxpool<<<64, 256, 0, stream>>>(mask, mfl, vis, den, afc, gstat, vmaxb);
  k_compact<<<4, 64, 0, stream>>>(mfl, qidx, kidx, nq, nk);
  k_conv_raw<<<dim3(128, BB), 256, 0, stream>>>(x, w1, y1, gsum1, gsq1);
  k_inorm<<<256, 256, 0, stream>>>(y1, gsum1, gsq1, nullptr);
  k_conv_raw<<<dim3(128, BB), 256, 0, stream>>>(y1, w2c, kx, gsum2, gsq2);
  k_inorm<<<256, 256, 0, stream>>>(kx, gsum2, gsq2, x);
  k_normT<<<256, 256, 0, stream>>>(kx, khat);
  k_att1<<<dim3(64 * KSPLIT, BB), 256, 0, stream>>>(khat, x, qidx, kidx, nq, nk, afc, den);
  k_att2<<<dim3(64 * KSPLIT, BB), 256, 0, stream>>>(khat, qidx, kidx, nq, nk, den, vis);
  k_copy<<<1024, 256, 0, stream>>>((const uint4*)x, (uint4*)out, 262144);
  k_fusion<<<dim3(256, BB), 256, 0, stream>>>(x, afc, den, qidx, nq, fsw1, fsw2, fsb2, fswf, out);
  k_vmax<<<64, 256, 0, stream>>>(vis, vmaxb);
  k_upsample<<<4096, 256, 0, stream>>>(vis, vmaxb, out + 1048576);
}

// Round 6
// 709.788 us; speedup vs baseline: 2.5421x; 1.0371x over previous
//
#include <hip/hip_runtime.h>
#include <hip/hip_bf16.h>

typedef __hip_bfloat16 bf16;
typedef __attribute__((ext_vector_type(8))) short short8;
typedef __attribute__((ext_vector_type(4))) float f32x4;

#define BB 4
#define CC 64
#define NN 4096           // 64*64
#define MH 512
#define MW 512
#define LS 72             // LDS row stride in bf16 elements (144 B, 16B-mult, 2-way alias)

// ---- workspace layout (BYTE offsets; total ~4.5 MiB) ----
#define WB_AFC  ((size_t)0)         // f32[4*4096*64] att_fore NORMALIZED, pixel-major (fg rows only)
#define WB_DEN  ((size_t)4194304)   // f32[4*4096] softmax denominators (fg rows only)
#define WB_VIS  ((size_t)4259840)   // f32[4*4096] visatt
#define WB_QIX  ((size_t)4325376)   // int[4*4096]
#define WB_KIX  ((size_t)4390912)   // int[4*4096]
#define WB_MFL  ((size_t)4456448)   // uchar[4*4096]
#define WB_CNT  ((size_t)4472832)   // int nq[4]; int nk[4]; uint vmaxbits (12 ints)
#define WB_STAT ((size_t)4472896)   // f32 gsum1[256]; gsq1[256]; gsum2[256]; gsq2[256]

__device__ __forceinline__ float b2f(bf16 v) { return __bfloat162float(v); }
__device__ __forceinline__ unsigned short f2bu(float f) {
  bf16 h = __float2bfloat16(f);
  return *(unsigned short*)&h;
}

// ------- 1. maxpool 8x8 on mask + zero-init vis/stats/vmax -----------------
__global__ __launch_bounds__(256) void k_maxpool(const float* __restrict__ mask,
                                                 unsigned char* __restrict__ mfl,
                                                 float* __restrict__ vis,
                                                 float* __restrict__ gstat,
                                                 unsigned int* __restrict__ vmaxb) {
  int i = blockIdx.x * 256 + threadIdx.x;          // < 4*4096
  int b = i >> 12, p = i & 4095;
  int py = p >> 6, px = p & 63;
  const float* mb = mask + (size_t)b * MH * MW + (py * 8) * MW + px * 8;
  float mx = 0.f;
  #pragma unroll
  for (int dy = 0; dy < 8; ++dy) {
    const float4* r4 = (const float4*)(mb + dy * MW);
    float4 a = r4[0], c = r4[1];
    mx = fmaxf(mx, fmaxf(fmaxf(a.x, a.y), fmaxf(a.z, a.w)));
    mx = fmaxf(mx, fmaxf(fmaxf(c.x, c.y), fmaxf(c.z, c.w)));
  }
  mfl[i] = (mx > 0.f) ? 1 : 0;
  vis[i] = 0.f;
  if (i < 1024) gstat[i] = 0.f;
  if (i == 0) vmaxb[0] = 0u;
}

// ---------------- 2. fg/bg index compaction (1 wave per batch) -------------
__global__ __launch_bounds__(64) void k_compact(const unsigned char* __restrict__ mfl,
                                                int* __restrict__ qidx, int* __restrict__ kidx,
                                                int* __restrict__ nq, int* __restrict__ nk) {
  int b = blockIdx.x, lane = threadIdx.x;
  int qb = 0, kb = 0;
  for (int it = 0; it < 64; ++it) {
    int p = it * 64 + lane;
    bool f = mfl[b * NN + p] != 0;
    unsigned long long bal = __ballot(f);
    int before = __popcll(bal & ((1ULL << lane) - 1ULL));
    if (f)  qidx[b * NN + qb + before] = p;
    if (!f) kidx[b * NN + kb + (lane - before)] = p;
    int cnt = __popcll(bal);
    qb += cnt; kb += 64 - cnt;
  }
  if (lane == 0) { nq[b] = qb; nk[b] = kb; }
}

// -------- 3a. conv3x3(pad1), raw output + per-(b,co) partial stats ---------
__global__ __launch_bounds__(256) void k_conv_raw(const float* __restrict__ in,
                                                  const float* __restrict__ wts,
                                                  float* __restrict__ yraw,
                                                  float* __restrict__ gsum,
                                                  float* __restrict__ gsq) {
  int b = blockIdx.y;
  int band = blockIdx.x & 7;
  int cg = blockIdx.x >> 3;        // 0..15
  int r0 = band * 8;
  __shared__ float wl[4 * 768];
  __shared__ float tile[10 * 68];
  int t = threadIdx.x;
  for (int idx = t; idx < 4 * 576; idx += 256) {
    int co = idx / 576, rem = idx - co * 576;
    int ci = rem / 9, tap = rem - ci * 9;
    wl[co * 768 + ci * 12 + tap] = wts[(size_t)((cg * 4 + co) * 64) * 9 + rem];
  }
  int co = t >> 6, g = t & 63;
  int gr = g >> 3;
  int c0 = (g & 7) * 8;
  const float* inb = in + (size_t)b * CC * NN;
  float acc[8] = {};
  for (int ci = 0; ci < 64; ++ci) {
    __syncthreads();
    for (int idx = t; idx < 680; idx += 256) {
      int row = idx / 68, col = idx - row * 68;
      int gy = r0 - 1 + row, gx = col - 1;
      float v = 0.f;
      if (col < 66 && (unsigned)gy < 64u && (unsigned)gx < 64u)
        v = inb[ci * NN + gy * 64 + gx];
      tile[idx] = v;
    }
    __syncthreads();
    const float* wr = &wl[co * 768 + ci * 12];
    float4 wa = *(const float4*)wr;
    float4 wb4 = *(const float4*)(wr + 4);
    float w9[9] = {wa.x, wa.y, wa.z, wa.w, wb4.x, wb4.y, wb4.z, wb4.w, wr[8]};
    float patch[3][10];
    #pragma unroll
    for (int dy = 0; dy < 3; ++dy) {
      const float* rp = &tile[(gr + dy) * 68 + c0];
      float4 a = *(const float4*)rp;
      float4 b4 = *(const float4*)(rp + 4);
      float2 c2 = *(const float2*)(rp + 8);
      patch[dy][0] = a.x;  patch[dy][1] = a.y;  patch[dy][2] = a.z;  patch[dy][3] = a.w;
      patch[dy][4] = b4.x; patch[dy][5] = b4.y; patch[dy][6] = b4.z; patch[dy][7] = b4.w;
      patch[dy][8] = c2.x; patch[dy][9] = c2.y;
    }
    #pragma unroll
    for (int dy = 0; dy < 3; ++dy)
      #pragma unroll
      for (int dx = 0; dx < 3; ++dx) {
        float w = w9[dy * 3 + dx];
        #pragma unroll
        for (int j = 0; j < 8; ++j) acc[j] += w * patch[dy][j + dx];
      }
  }
  int bc = b * CC + cg * 4 + co;
  float* yo = yraw + (size_t)bc * NN + (r0 + gr) * 64 + c0;
  *(float4*)yo       = make_float4(acc[0], acc[1], acc[2], acc[3]);
  *(float4*)(yo + 4) = make_float4(acc[4], acc[5], acc[6], acc[7]);
  float s1 = 0.f, s2 = 0.f;
  #pragma unroll
  for (int j = 0; j < 8; ++j) { s1 += acc[j]; s2 += acc[j] * acc[j]; }
  #pragma unroll
  for (int off = 32; off > 0; off >>= 1) { s1 += __shfl_down(s1, off); s2 += __shfl_down(s2, off); }
  if (g == 0) { atomicAdd(&gsum[bc], s1); atomicAdd(&gsq[bc], s2); }
}

// -------- 3b. instance-norm finalize (+ optional residual) + relu, in place
__global__ __launch_bounds__(256) void k_inorm(float* __restrict__ y,
                                               const float* __restrict__ gsum,
                                               const float* __restrict__ gsq,
                                               const float* __restrict__ addsrc) {
  int bc = blockIdx.x;
  int t = threadIdx.x;
  float mean = gsum[bc] * (1.f / NN);
  float var = fmaxf(gsq[bc] * (1.f / NN) - mean * mean, 0.f);
  float inv = rsqrtf(var + 1e-5f);
  float* yp = y + (size_t)bc * NN;
  const float* ap = addsrc ? addsrc + (size_t)bc * NN : nullptr;
  #pragma unroll
  for (int ch = 0; ch < 4; ++ch) {
    int p = ch * 1024 + t * 4;
    float4 v = *(const float4*)(yp + p);
    v.x = (v.x - mean) * inv; v.y = (v.y - mean) * inv;
    v.z = (v.z - mean) * inv; v.w = (v.w - mean) * inv;
    if (ap) {
      float4 a = *(const float4*)(ap + p);
      v.x += a.x; v.y += a.y; v.z += a.z; v.w += a.w;
    }
    v.x = fmaxf(v.x, 0.f); v.y = fmaxf(v.y, 0.f);
    v.z = fmaxf(v.z, 0.f); v.w = fmaxf(v.w, 0.f);
    *(float4*)(yp + p) = v;
  }
}

// -------- 4. per-pixel channel L2-normalize + transpose -> bf16 pixel-major
__global__ __launch_bounds__(256) void k_normT(const float* __restrict__ kx,
                                               unsigned short* __restrict__ khat) {
  int b = blockIdx.x >> 6, p0 = (blockIdx.x & 63) * 64;
  __shared__ float lk[64][65];
  __shared__ float inv[64];
  int t = threadIdx.x;
  const float* kb = kx + (size_t)b * CC * NN + p0;
  for (int idx = t; idx < 4096; idx += 256) {
    int c = idx >> 6, j = idx & 63;
    lk[j][c] = kb[c * NN + j];
  }
  __syncthreads();
  if (t < 64) {
    float s = 0.f;
    for (int c = 0; c < 64; ++c) { float v = lk[t][c]; s += v * v; }
    inv[t] = 1.f / (sqrtf(s) + 1e-8f);
  }
  __syncthreads();
  unsigned short* kh = khat + ((size_t)b * NN + p0) * 64;
  for (int idx = t; idx < 2048; idx += 256) {
    int j = idx >> 5, c2 = (idx & 31) * 2;
    ushort2 w2;
    w2.x = f2bu(lk[j][c2] * inv[j]);
    w2.y = f2bu(lk[j][c2 + 1] * inv[j]);
    *(ushort2*)&kh[j * 64 + c2] = w2;
  }
}

// -------- 5. attention pass 1: MFMA flash-style, block owns 64 queries -----
// 4 waves x 16-q strips; loops all bg keys in 64-wide tiles; direct stores.
__global__ __launch_bounds__(256) void k_att1(const unsigned short* __restrict__ khat,
                                              const float* __restrict__ x,
                                              const int* __restrict__ qidx, const int* __restrict__ kidx,
                                              const int* __restrict__ nqv, const int* __restrict__ nkv,
                                              float* __restrict__ afc, float* __restrict__ den) {
  int b = blockIdx.y;
  int nqb = nqv[b], nkb = nkv[b];
  int q0 = blockIdx.x * 64;
  if (q0 >= nqb) return;
  __shared__ unsigned short lq [64 * LS];   // Q   [q][c]
  __shared__ unsigned short lk [64 * LS];   // K   [k][c]
  __shared__ unsigned short lvT[64 * LS];   // V^T [c][k]
  __shared__ unsigned short le [64 * LS];   // E   [q][k]
  int t = threadIdx.x;
  int wave = t >> 6, lane = t & 63;
  int quad = lane >> 4, col = lane & 15;
  int qw = wave * 16;
  const int* qix = qidx + b * NN;
  const int* kix = kidx + b * NN;
  const unsigned short* khb = khat + (size_t)b * NN * 64;
  const float* xb = x + (size_t)b * CC * NN;
  // stage Q once (zero-fill invalid rows)
  for (int idx = t; idx < 512; idx += 256) {
    int q = idx >> 3, c8 = (idx & 7) * 8;
    uint4 v = make_uint4(0u, 0u, 0u, 0u);
    if (q0 + q < nqb) v = *(const uint4*)(khb + (size_t)qix[q0 + q] * 64 + c8);
    *(uint4*)&lq[q * LS + c8] = v;
  }
  f32x4 pv[4] = {{0.f,0.f,0.f,0.f},{0.f,0.f,0.f,0.f},{0.f,0.f,0.f,0.f},{0.f,0.f,0.f,0.f}};
  float dsum[4] = {0.f, 0.f, 0.f, 0.f};
  for (int j0 = 0; j0 < nkb; j0 += 64) {
    __syncthreads();   // prior PV reads of lvT/le done; also orders Q staging (1st iter)
    for (int idx = t; idx < 512; idx += 256) {
      int k = idx >> 3, c8 = (idx & 7) * 8;
      uint4 v = make_uint4(0u, 0u, 0u, 0u);
      if (j0 + k < nkb) v = *(const uint4*)(khb + (size_t)kix[j0 + k] * 64 + c8);
      *(uint4*)&lk[k * LS + c8] = v;
    }
    for (int idx = t; idx < 4096; idx += 256) {
      int c = idx >> 6, k = idx & 63;
      float v = (j0 + k < nkb) ? xb[(size_t)c * NN + kix[j0 + k]] : 0.f;
      lvT[c * LS + k] = f2bu(v);
    }
    __syncthreads();
    // S = Q K^T for this wave's q-strip, 4 k-tiles of 16
    #pragma unroll
    for (int kt = 0; kt < 4; ++kt) {
      f32x4 s = {0.f, 0.f, 0.f, 0.f};
      #pragma unroll
      for (int h = 0; h < 2; ++h) {
        short8 a  = *(const short8*)&lq[(qw + col) * LS + h * 32 + quad * 8];
        short8 bk = *(const short8*)&lk[(kt * 16 + col) * LS + h * 32 + quad * 8];
        s = __builtin_amdgcn_mfma_f32_16x16x32_bf16(a, bk, s, 0, 0, 0);
      }
      bool kval = (j0 + kt * 16 + col) < nkb;
      #pragma unroll
      for (int r = 0; r < 4; ++r) {
        float e = kval ? __expf(20.f * s[r]) : 0.f;
        dsum[r] += e;
        le[(qw + quad * 4 + r) * LS + kt * 16 + col] = f2bu(e);
      }
    }
    __syncthreads();
    // PV: O += E * V  (A=E[q][kk], B=V[kk][c] via lvT rows)
    #pragma unroll
    for (int ct = 0; ct < 4; ++ct) {
      #pragma unroll
      for (int h = 0; h < 2; ++h) {
        short8 a  = *(const short8*)&le[(qw + col) * LS + h * 32 + quad * 8];
        short8 bv = *(const short8*)&lvT[(ct * 16 + col) * LS + h * 32 + quad * 8];
        pv[ct] = __builtin_amdgcn_mfma_f32_16x16x32_bf16(a, bv, pv[ct], 0, 0, 0);
      }
    }
  }
  // reduce row sums across the 16 cols (xor within 16-lane groups)
  #pragma unroll
  for (int r = 0; r < 4; ++r) {
    float v = dsum[r];
    v += __shfl_xor(v, 1); v += __shfl_xor(v, 2);
    v += __shfl_xor(v, 4); v += __shfl_xor(v, 8);
    dsum[r] = v;
  }
  #pragma unroll
  for (int r = 0; r < 4; ++r) {
    int qq = q0 + qw + quad * 4 + r;
    if (qq < nqb) {
      float dn = dsum[r];
      float invd = (dn > 0.f) ? 1.f / dn : 0.f;
      if (col == 0) den[b * NN + qq] = dn;
      float* dst = afc + ((size_t)b * NN + qq) * 64;
      #pragma unroll
      for (int ct = 0; ct < 4; ++ct) dst[ct * 16 + col] = pv[ct][r] * invd;
    }
  }
}

// -------- 6. attention pass 2: MFMA per-key visatt sums --------------------
// block owns 64 keys; loops all queries; direct stores.
__global__ __launch_bounds__(256) void k_att2(const unsigned short* __restrict__ khat,
                                              const int* __restrict__ qidx, const int* __restrict__ kidx,
                                              const int* __restrict__ nqv, const int* __restrict__ nkv,
                                              const float* __restrict__ den, float* __restrict__ vis) {
  int b = blockIdx.y;
  int nqb = nqv[b], nkb = nkv[b];
  int k0 = blockIdx.x * 64;
  if (k0 >= nkb) return;
  __shared__ unsigned short lk[64 * LS];
  __shared__ unsigned short lq[64 * LS];
  __shared__ float w[64];
  int t = threadIdx.x;
  int wave = t >> 6, lane = t & 63;
  int quad = lane >> 4, col = lane & 15;
  int kw = wave * 16;
  const int* qix = qidx + b * NN;
  const int* kix = kidx + b * NN;
  const unsigned short* khb = khat + (size_t)b * NN * 64;
  for (int idx = t; idx < 512; idx += 256) {
    int k = idx >> 3, c8 = (idx & 7) * 8;
    uint4 v = make_uint4(0u, 0u, 0u, 0u);
    if (k0 + k < nkb) v = *(const uint4*)(khb + (size_t)kix[k0 + k] * 64 + c8);
    *(uint4*)&lk[k * LS + c8] = v;
  }
  float vacc[4] = {0.f, 0.f, 0.f, 0.f};
  for (int i0 = 0; i0 < nqb; i0 += 64) {
    __syncthreads();
    for (int idx = t; idx < 512; idx += 256) {
      int q = idx >> 3, c8 = (idx & 7) * 8;
      uint4 v = make_uint4(0u, 0u, 0u, 0u);
      if (i0 + q < nqb) v = *(const uint4*)(khb + (size_t)qix[i0 + q] * 64 + c8);
      *(uint4*)&lq[q * LS + c8] = v;
    }
    if (t < 64) {
      int qq = i0 + t;
      float d = (qq < nqb) ? den[b * NN + qq] : 0.f;
      w[t] = (d > 0.f) ? 1.f / d : 0.f;
    }
    __syncthreads();
    #pragma unroll
    for (int qt = 0; qt < 4; ++qt) {
      f32x4 s = {0.f, 0.f, 0.f, 0.f};
      #pragma unroll
      for (int h = 0; h < 2; ++h) {
        short8 a  = *(const short8*)&lk[(kw + col) * LS + h * 32 + quad * 8];
        short8 bq = *(const short8*)&lq[(qt * 16 + col) * LS + h * 32 + quad * 8];
        s = __builtin_amdgcn_mfma_f32_16x16x32_bf16(a, bq, s, 0, 0, 0);
      }
      float wq = w[qt * 16 + col];
      #pragma unroll
      for (int r = 0; r < 4; ++r) vacc[r] += __expf(20.f * s[r]) * wq;
    }
  }
  #pragma unroll
  for (int r = 0; r < 4; ++r) {
    float v = vacc[r];
    v += __shfl_xor(v, 1); v += __shfl_xor(v, 2);
    v += __shfl_xor(v, 4); v += __shfl_xor(v, 8);
    int kk = k0 + kw + quad * 4 + r;
    if (col == 0 && kk < nkb) vis[b * NN + kix[kk]] = v;
  }
}

// -------- 7a. default out = x (fp32 bit copy, 4 MB) ------------------------
__global__ __launch_bounds__(256) void k_copy(const uint4* __restrict__ src, uint4* __restrict__ dst, int n) {
  int i = blockIdx.x * 256 + threadIdx.x;
  if (i < n) dst[i] = src[i];
}

// -------- 7b. fusion epilogue over fg pixels (LDS ~43.5KB) -----------------
__global__ __launch_bounds__(256) void k_fusion(const float* __restrict__ x, const float* __restrict__ afc,
                                                const int* __restrict__ qidx, const int* __restrict__ nqv,
                                                const float* __restrict__ w1, const float* __restrict__ w2,
                                                const float* __restrict__ b2, const float* __restrict__ wf,
                                                float* __restrict__ outp) {
  int b = blockIdx.y;
  int nqb = nqv[b];
  int q0 = blockIdx.x * 16;
  if (q0 >= nqb) return;
  __shared__ bf16 w1s[128 * 64];
  __shared__ bf16 w2s[64 * 64];
  __shared__ bf16 wfs[128 * 64];
  __shared__ float b2s[64];
  __shared__ float px[4][64];
  __shared__ float pa[4][64];
  __shared__ float pf[4][64];
  int t = threadIdx.x;
  for (int idx = t; idx < 8192; idx += 256) {
    int j = idx >> 6, c = idx & 63;
    w1s[j * 64 + c] = __float2bfloat16(w1[c * 128 + j]);
    wfs[j * 64 + c] = __float2bfloat16(wf[c * 128 + j]);
  }
  for (int idx = t; idx < 4096; idx += 256) {
    int j = idx >> 6, c = idx & 63;
    w2s[j * 64 + c] = __float2bfloat16(w2[c * 64 + j]);
  }
  if (t < 64) b2s[t] = b2[t];
  int c = t & 63, pp = t >> 6;
  const int* qix = qidx + b * NN;
  const float* xb = x + (size_t)b * CC * NN;
  for (int it = 0; it < 4; ++it) {
    int qq = q0 + it * 4 + pp;
    bool valid = qq < nqb;
    int qp = valid ? qix[qq] : 0;
    __syncthreads();
    px[pp][c] = valid ? xb[(size_t)c * NN + qp] : 0.f;
    pa[pp][c] = valid ? afc[((size_t)b * NN + qq) * 64 + c] : 0.f;
    __syncthreads();
    float f1 = 0.f;
    for (int j = 0; j < 64; ++j) f1 += b2f(w1s[j * 64 + c]) * px[pp][j];
    for (int j = 0; j < 64; ++j) f1 += b2f(w1s[(64 + j) * 64 + c]) * pa[pp][j];
    pf[pp][c] = f1;
    __syncthreads();
    float z = b2s[c];
    for (int j = 0; j < 64; ++j) z += b2f(w2s[j * 64 + c]) * pf[pp][j];
    float sg = 1.f / (1.f + __expf(-z));
    pa[pp][c] = pa[pp][c] * (1.f - sg);
    __syncthreads();
    float fu = 0.f;
    for (int j = 0; j < 64; ++j) fu += b2f(wfs[j * 64 + c]) * px[pp][j];
    for (int j = 0; j < 64; ++j) fu += b2f(wfs[(64 + j) * 64 + c]) * pa[pp][j];
    if (valid) outp[((size_t)b * CC + c) * NN + qp] = fu;
  }
}

// -------- 8a. global max of visatt -----------------------------------------
__global__ __launch_bounds__(256) void k_vmax(const float* __restrict__ vis, unsigned int* __restrict__ vmaxb) {
  int i = blockIdx.x * 256 + threadIdx.x;
  float v = vis[i];
  #pragma unroll
  for (int off = 32; off > 0; off >>= 1) v = fmaxf(v, __shfl_down(v, off));
  if ((threadIdx.x & 63) == 0) atomicMax(vmaxb, __float_as_uint(v));
}

// -------- 8b. x8 nearest upsample + normalize ------------------------------
__global__ __launch_bounds__(256) void k_upsample(const float* __restrict__ vis,
                                                  const unsigned int* __restrict__ vmaxb,
                                                  float* __restrict__ out2) {
  int i = blockIdx.x * 256 + threadIdx.x;
  int b = i >> 18;
  int rem = i & 262143;
  int y = rem >> 9, x = rem & 511;
  float vm = __uint_as_float(vmaxb[0]);
  if (!(vm > 0.f)) vm = 1.f;
  out2[i] = vis[b * NN + (y >> 3) * 64 + (x >> 3)] / vm;
}

extern "C" void kernel_launch(void* const* d_in, const int* in_sizes, int n_in,
                              void* d_out, int out_size, void* d_ws, size_t ws_size,
                              hipStream_t stream) {
  const float* x    = (const float*)d_in[0];
  const float* mask = (const float*)d_in[1];
  const float* w1   = (const float*)d_in[2];
  const float* w2c  = (const float*)d_in[3];
  const float* fsw1 = (const float*)d_in[4];
  const float* fsw2 = (const float*)d_in[5];
  const float* fsb2 = (const float*)d_in[6];
  const float* fswf = (const float*)d_in[7];
  float* out = (float*)d_out;
  char* wsb = (char*)d_ws;

  float* afc = (float*)(wsb + WB_AFC);
  float* den = (float*)(wsb + WB_DEN);
  float* vis = (float*)(wsb + WB_VIS);
  int* qidx  = (int*)(wsb + WB_QIX);
  int* kidx  = (int*)(wsb + WB_KIX);
  unsigned char* mfl = (unsigned char*)(wsb + WB_MFL);
  int* nq = (int*)(wsb + WB_CNT);
  int* nk = nq + 4;
  unsigned int* vmaxb = (unsigned int*)(nq + 8);
  float* gstat = (float*)(wsb + WB_STAT);
  float* gsum1 = gstat;
  float* gsq1  = gstat + 256;
  float* gsum2 = gstat + 512;
  float* gsq2  = gstat + 768;

  // scratch staged inside d_out (regions dead before their final writes):
  float* y1   = out;                       // conv1 raw/normed; later khat(bf16); later final out
  float* kx   = out + 1048576;             // conv2 raw/normed; later attmask
  unsigned short* khat = (unsigned short*)out;   // bf16[4*4096*64] = 2 MB, in [0..1M floats)

  k_maxpool<<<64, 256, 0, stream>>>(mask, mfl, vis, gstat, vmaxb);
  k_compact<<<4, 64, 0, stream>>>(mfl, qidx, kidx, nq, nk);
  k_conv_raw<<<dim3(128, BB), 256, 0, stream>>>(x, w1, y1, gsum1, gsq1);
  k_inorm<<<256, 256, 0, stream>>>(y1, gsum1, gsq1, nullptr);
  k_conv_raw<<<dim3(128, BB), 256, 0, stream>>>(y1, w2c, kx, gsum2, gsq2);
  k_inorm<<<256, 256, 0, stream>>>(kx, gsum2, gsq2, x);
  k_normT<<<256, 256, 0, stream>>>(kx, khat);            // overwrites y1 region (dead)
  k_att1<<<dim3(64, BB), 256, 0, stream>>>(khat, x, qidx, kidx, nq, nk, afc, den);
  k_att2<<<dim3(64, BB), 256, 0, stream>>>(khat, qidx, kidx, nq, nk, den, vis);
  k_copy<<<1024, 256, 0, stream>>>((const uint4*)x, (uint4*)out, 262144);
  k_fusion<<<dim3(256, BB), 256, 0, stream>>>(x, afc, qidx, nq, fsw1, fsw2, fsb2, fswf, out);
  k_vmax<<<64, 256, 0, stream>>>(vis, vmaxb);
  k_upsample<<<4096, 256, 0, stream>>>(vis, vmaxb, out + 1048576);
}

// Round 7
// 509.855 us; speedup vs baseline: 3.5389x; 1.3921x over previous
//
#include <hip/hip_runtime.h>
#include <hip/hip_bf16.h>

typedef __hip_bfloat16 bf16;
typedef __attribute__((ext_vector_type(8))) short short8;
typedef __attribute__((ext_vector_type(4))) float f32x4;

#define BB 4
#define CC 64
#define NN 4096           // 64*64
#define MH 512
#define MW 512
#define LS 72             // LDS row stride in bf16 elements (144 B, 16B-mult, 2-way alias)

// ---- workspace layout (BYTE offsets; total ~4.5 MiB) ----
#define WB_AFC  ((size_t)0)         // f32[4*4096*64] att_fore NORMALIZED, pixel-major (fg rows only)
#define WB_DEN  ((size_t)4194304)   // f32[4*4096] softmax denominators (fg rows only)
#define WB_VIS  ((size_t)4259840)   // f32[4*4096] visatt
#define WB_QIX  ((size_t)4325376)   // int[4*4096]
#define WB_KIX  ((size_t)4390912)   // int[4*4096]
#define WB_MFL  ((size_t)4456448)   // uchar[4*4096]
#define WB_CNT  ((size_t)4472832)   // int nq[4]; int nk[4]; uint vmaxbits (12 ints)
#define WB_STAT ((size_t)4472896)   // f32 gsum1[256]; gsq1[256]; gsum2[256]; gsq2[256]

__device__ __forceinline__ float b2f(bf16 v) { return __bfloat162float(v); }
__device__ __forceinline__ float us2f(unsigned short u) { return __uint_as_float(((unsigned)u) << 16); }
__device__ __forceinline__ unsigned short f2bu(float f) {
  bf16 h = __float2bfloat16(f);
  return *(unsigned short*)&h;
}

// ------- 1. maxpool 8x8 on mask + zero-init vis/stats/vmax -----------------
__global__ __launch_bounds__(256) void k_maxpool(const float* __restrict__ mask,
                                                 unsigned char* __restrict__ mfl,
                                                 float* __restrict__ vis,
                                                 float* __restrict__ gstat,
                                                 unsigned int* __restrict__ vmaxb) {
  int i = blockIdx.x * 256 + threadIdx.x;          // < 4*4096
  int b = i >> 12, p = i & 4095;
  int py = p >> 6, px = p & 63;
  const float* mb = mask + (size_t)b * MH * MW + (py * 8) * MW + px * 8;
  float mx = 0.f;
  #pragma unroll
  for (int dy = 0; dy < 8; ++dy) {
    const float4* r4 = (const float4*)(mb + dy * MW);
    float4 a = r4[0], c = r4[1];
    mx = fmaxf(mx, fmaxf(fmaxf(a.x, a.y), fmaxf(a.z, a.w)));
    mx = fmaxf(mx, fmaxf(fmaxf(c.x, c.y), fmaxf(c.z, c.w)));
  }
  mfl[i] = (mx > 0.f) ? 1 : 0;
  vis[i] = 0.f;
  if (i < 1024) gstat[i] = 0.f;
  if (i == 0) vmaxb[0] = 0u;
}

// ---------------- 2. fg/bg index compaction (1 wave per batch) -------------
__global__ __launch_bounds__(64) void k_compact(const unsigned char* __restrict__ mfl,
                                                int* __restrict__ qidx, int* __restrict__ kidx,
                                                int* __restrict__ nq, int* __restrict__ nk) {
  int b = blockIdx.x, lane = threadIdx.x;
  int qb = 0, kb = 0;
  for (int it = 0; it < 64; ++it) {
    int p = it * 64 + lane;
    bool f = mfl[b * NN + p] != 0;
    unsigned long long bal = __ballot(f);
    int before = __popcll(bal & ((1ULL << lane) - 1ULL));
    if (f)  qidx[b * NN + qb + before] = p;
    if (!f) kidx[b * NN + kb + (lane - before)] = p;
    int cnt = __popcll(bal);
    qb += cnt; kb += 64 - cnt;
  }
  if (lane == 0) { nq[b] = qb; nk[b] = kb; }
}

// -------- 3a. conv3x3(pad1), raw output + per-(b,co) partial stats ---------
__global__ __launch_bounds__(256) void k_conv_raw(const float* __restrict__ in,
                                                  const float* __restrict__ wts,
                                                  float* __restrict__ yraw,
                                                  float* __restrict__ gsum,
                                                  float* __restrict__ gsq) {
  int b = blockIdx.y;
  int band = blockIdx.x & 7;
  int cg = blockIdx.x >> 3;        // 0..15
  int r0 = band * 8;
  __shared__ float wl[4 * 768];
  __shared__ float tile[10 * 68];
  int t = threadIdx.x;
  for (int idx = t; idx < 4 * 576; idx += 256) {
    int co = idx / 576, rem = idx - co * 576;
    int ci = rem / 9, tap = rem - ci * 9;
    wl[co * 768 + ci * 12 + tap] = wts[(size_t)((cg * 4 + co) * 64) * 9 + rem];
  }
  int co = t >> 6, g = t & 63;
  int gr = g >> 3;
  int c0 = (g & 7) * 8;
  const float* inb = in + (size_t)b * CC * NN;
  float acc[8] = {};
  for (int ci = 0; ci < 64; ++ci) {
    __syncthreads();
    for (int idx = t; idx < 680; idx += 256) {
      int row = idx / 68, col = idx - row * 68;
      int gy = r0 - 1 + row, gx = col - 1;
      float v = 0.f;
      if (col < 66 && (unsigned)gy < 64u && (unsigned)gx < 64u)
        v = inb[ci * NN + gy * 64 + gx];
      tile[idx] = v;
    }
    __syncthreads();
    const float* wr = &wl[co * 768 + ci * 12];
    float4 wa = *(const float4*)wr;
    float4 wb4 = *(const float4*)(wr + 4);
    float w9[9] = {wa.x, wa.y, wa.z, wa.w, wb4.x, wb4.y, wb4.z, wb4.w, wr[8]};
    float patch[3][10];
    #pragma unroll
    for (int dy = 0; dy < 3; ++dy) {
      const float* rp = &tile[(gr + dy) * 68 + c0];
      float4 a = *(const float4*)rp;
      float4 b4 = *(const float4*)(rp + 4);
      float2 c2 = *(const float2*)(rp + 8);
      patch[dy][0] = a.x;  patch[dy][1] = a.y;  patch[dy][2] = a.z;  patch[dy][3] = a.w;
      patch[dy][4] = b4.x; patch[dy][5] = b4.y; patch[dy][6] = b4.z; patch[dy][7] = b4.w;
      patch[dy][8] = c2.x; patch[dy][9] = c2.y;
    }
    #pragma unroll
    for (int dy = 0; dy < 3; ++dy)
      #pragma unroll
      for (int dx = 0; dx < 3; ++dx) {
        float w = w9[dy * 3 + dx];
        #pragma unroll
        for (int j = 0; j < 8; ++j) acc[j] += w * patch[dy][j + dx];
      }
  }
  int bc = b * CC + cg * 4 + co;
  float* yo = yraw + (size_t)bc * NN + (r0 + gr) * 64 + c0;
  *(float4*)yo       = make_float4(acc[0], acc[1], acc[2], acc[3]);
  *(float4*)(yo + 4) = make_float4(acc[4], acc[5], acc[6], acc[7]);
  float s1 = 0.f, s2 = 0.f;
  #pragma unroll
  for (int j = 0; j < 8; ++j) { s1 += acc[j]; s2 += acc[j] * acc[j]; }
  #pragma unroll
  for (int off = 32; off > 0; off >>= 1) { s1 += __shfl_down(s1, off); s2 += __shfl_down(s2, off); }
  if (g == 0) { atomicAdd(&gsum[bc], s1); atomicAdd(&gsq[bc], s2); }
}

// -------- 3b. instance-norm finalize (+ optional residual) + relu, in place
__global__ __launch_bounds__(256) void k_inorm(float* __restrict__ y,
                                               const float* __restrict__ gsum,
                                               const float* __restrict__ gsq,
                                               const float* __restrict__ addsrc) {
  int bc = blockIdx.x;
  int t = threadIdx.x;
  float mean = gsum[bc] * (1.f / NN);
  float var = fmaxf(gsq[bc] * (1.f / NN) - mean * mean, 0.f);
  float inv = rsqrtf(var + 1e-5f);
  float* yp = y + (size_t)bc * NN;
  const float* ap = addsrc ? addsrc + (size_t)bc * NN : nullptr;
  #pragma unroll
  for (int ch = 0; ch < 4; ++ch) {
    int p = ch * 1024 + t * 4;
    float4 v = *(const float4*)(yp + p);
    v.x = (v.x - mean) * inv; v.y = (v.y - mean) * inv;
    v.z = (v.z - mean) * inv; v.w = (v.w - mean) * inv;
    if (ap) {
      float4 a = *(const float4*)(ap + p);
      v.x += a.x; v.y += a.y; v.z += a.z; v.w += a.w;
    }
    v.x = fmaxf(v.x, 0.f); v.y = fmaxf(v.y, 0.f);
    v.z = fmaxf(v.z, 0.f); v.w = fmaxf(v.w, 0.f);
    *(float4*)(yp + p) = v;
  }
}

// -------- 4a. per-pixel channel L2-normalize + transpose -> bf16 pixel-major
__global__ __launch_bounds__(256) void k_normT(const float* __restrict__ kx,
                                               unsigned short* __restrict__ khat) {
  int b = blockIdx.x >> 6, p0 = (blockIdx.x & 63) * 64;
  __shared__ float lk[64][65];
  __shared__ float inv[64];
  int t = threadIdx.x;
  const float* kb = kx + (size_t)b * CC * NN + p0;
  for (int idx = t; idx < 4096; idx += 256) {
    int c = idx >> 6, j = idx & 63;
    lk[j][c] = kb[c * NN + j];
  }
  __syncthreads();
  if (t < 64) {
    float s = 0.f;
    for (int c = 0; c < 64; ++c) { float v = lk[t][c]; s += v * v; }
    inv[t] = 1.f / (sqrtf(s) + 1e-8f);
  }
  __syncthreads();
  unsigned short* kh = khat + ((size_t)b * NN + p0) * 64;
  for (int idx = t; idx < 2048; idx += 256) {
    int j = idx >> 5, c2 = (idx & 31) * 2;
    ushort2 w2;
    w2.x = f2bu(lk[j][c2] * inv[j]);
    w2.y = f2bu(lk[j][c2 + 1] * inv[j]);
    *(ushort2*)&kh[j * 64 + c2] = w2;
  }
}

// -------- 4b. transpose x -> bf16 pixel-major (xt) -------------------------
// runs AFTER k_normT (xt overwrites the dead kx region).
__global__ __launch_bounds__(256) void k_xT(const float* __restrict__ x,
                                            unsigned short* __restrict__ xt) {
  int b = blockIdx.x >> 6, p0 = (blockIdx.x & 63) * 64;
  __shared__ float lx[64][65];
  int t = threadIdx.x;
  const float* xb = x + (size_t)b * CC * NN + p0;
  for (int idx = t; idx < 4096; idx += 256) {
    int c = idx >> 6, j = idx & 63;
    lx[j][c] = xb[c * NN + j];
  }
  __syncthreads();
  unsigned short* xo = xt + ((size_t)b * NN + p0) * 64;
  for (int idx = t; idx < 2048; idx += 256) {
    int j = idx >> 5, c2 = (idx & 31) * 2;
    ushort2 w2;
    w2.x = f2bu(lx[j][c2]);
    w2.y = f2bu(lx[j][c2 + 1]);
    *(ushort2*)&xo[j * 64 + c2] = w2;
  }
}

// -------- 5. attention pass 1: MFMA flash-style, block owns 64 queries -----
__global__ __launch_bounds__(256) void k_att1(const unsigned short* __restrict__ khat,
                                              const unsigned short* __restrict__ xt,
                                              const int* __restrict__ qidx, const int* __restrict__ kidx,
                                              const int* __restrict__ nqv, const int* __restrict__ nkv,
                                              float* __restrict__ afc, float* __restrict__ den) {
  int b = blockIdx.y;
  int nqb = nqv[b], nkb = nkv[b];
  int q0 = blockIdx.x * 64;
  if (q0 >= nqb) return;
  __shared__ unsigned short lq [64 * LS];   // Q   [q][c]
  __shared__ unsigned short lk [64 * LS];   // K   [k][c]
  __shared__ unsigned short lvT[64 * LS];   // V^T [c][k]
  __shared__ unsigned short le [64 * LS];   // E   [q][k]
  int t = threadIdx.x;
  int wave = t >> 6, lane = t & 63;
  int quad = lane >> 4, col = lane & 15;
  int qw = wave * 16;
  const int* qix = qidx + b * NN;
  const int* kix = kidx + b * NN;
  const unsigned short* khb = khat + (size_t)b * NN * 64;
  const unsigned short* xtb = xt + (size_t)b * NN * 64;
  // stage Q once (zero-fill invalid rows)
  for (int idx = t; idx < 512; idx += 256) {
    int q = idx >> 3, c8 = (idx & 7) * 8;
    uint4 v = make_uint4(0u, 0u, 0u, 0u);
    if (q0 + q < nqb) v = *(const uint4*)(khb + (size_t)qix[q0 + q] * 64 + c8);
    *(uint4*)&lq[q * LS + c8] = v;
  }
  f32x4 pv[4] = {{0.f,0.f,0.f,0.f},{0.f,0.f,0.f,0.f},{0.f,0.f,0.f,0.f},{0.f,0.f,0.f,0.f}};
  float dsum[4] = {0.f, 0.f, 0.f, 0.f};
  for (int j0 = 0; j0 < nkb; j0 += 64) {
    __syncthreads();   // prior PV reads of lvT/le done; also orders Q staging (1st iter)
    for (int idx = t; idx < 512; idx += 256) {
      int k = idx >> 3, c8 = (idx & 7) * 8;
      uint4 v = make_uint4(0u, 0u, 0u, 0u);
      uint4 vv = make_uint4(0u, 0u, 0u, 0u);
      if (j0 + k < nkb) {
        int kp = kix[j0 + k];
        v  = *(const uint4*)(khb + (size_t)kp * 64 + c8);
        vv = *(const uint4*)(xtb + (size_t)kp * 64 + c8);
      }
      *(uint4*)&lk[k * LS + c8] = v;
      unsigned short* vs = (unsigned short*)&vv;
      #pragma unroll
      for (int jj = 0; jj < 8; ++jj) lvT[(c8 + jj) * LS + k] = vs[jj];
    }
    __syncthreads();
    // S = Q K^T for this wave's q-strip, 4 k-tiles of 16
    #pragma unroll
    for (int kt = 0; kt < 4; ++kt) {
      f32x4 s = {0.f, 0.f, 0.f, 0.f};
      #pragma unroll
      for (int h = 0; h < 2; ++h) {
        short8 a  = *(const short8*)&lq[(qw + col) * LS + h * 32 + quad * 8];
        short8 bk = *(const short8*)&lk[(kt * 16 + col) * LS + h * 32 + quad * 8];
        s = __builtin_amdgcn_mfma_f32_16x16x32_bf16(a, bk, s, 0, 0, 0);
      }
      bool kval = (j0 + kt * 16 + col) < nkb;
      #pragma unroll
      for (int r = 0; r < 4; ++r) {
        float e = kval ? __expf(20.f * s[r]) : 0.f;
        dsum[r] += e;
        le[(qw + quad * 4 + r) * LS + kt * 16 + col] = f2bu(e);
      }
    }
    __syncthreads();
    // PV: O += E * V  (A=E[q][kk], B=V[kk][c] via lvT rows)
    #pragma unroll
    for (int ct = 0; ct < 4; ++ct) {
      #pragma unroll
      for (int h = 0; h < 2; ++h) {
        short8 a  = *(const short8*)&le[(qw + col) * LS + h * 32 + quad * 8];
        short8 bv = *(const short8*)&lvT[(ct * 16 + col) * LS + h * 32 + quad * 8];
        pv[ct] = __builtin_amdgcn_mfma_f32_16x16x32_bf16(a, bv, pv[ct], 0, 0, 0);
      }
    }
  }
  // reduce row sums across the 16 cols (xor within 16-lane groups)
  #pragma unroll
  for (int r = 0; r < 4; ++r) {
    float v = dsum[r];
    v += __shfl_xor(v, 1); v += __shfl_xor(v, 2);
    v += __shfl_xor(v, 4); v += __shfl_xor(v, 8);
    dsum[r] = v;
  }
  #pragma unroll
  for (int r = 0; r < 4; ++r) {
    int qq = q0 + qw + quad * 4 + r;
    if (qq < nqb) {
      float dn = dsum[r];
      float invd = (dn > 0.f) ? 1.f / dn : 0.f;
      if (col == 0) den[b * NN + qq] = dn;
      float* dst = afc + ((size_t)b * NN + qq) * 64;
      #pragma unroll
      for (int ct = 0; ct < 4; ++ct) dst[ct * 16 + col] = pv[ct][r] * invd;
    }
  }
}

// -------- 6. attention pass 2: MFMA per-key visatt sums --------------------
__global__ __launch_bounds__(256) void k_att2(const unsigned short* __restrict__ khat,
                                              const int* __restrict__ qidx, const int* __restrict__ kidx,
                                              const int* __restrict__ nqv, const int* __restrict__ nkv,
                                              const float* __restrict__ den, float* __restrict__ vis) {
  int b = blockIdx.y;
  int nqb = nqv[b], nkb = nkv[b];
  int k0 = blockIdx.x * 64;
  if (k0 >= nkb) return;
  __shared__ unsigned short lk[64 * LS];
  __shared__ unsigned short lq[64 * LS];
  __shared__ float w[64];
  int t = threadIdx.x;
  int wave = t >> 6, lane = t & 63;
  int quad = lane >> 4, col = lane & 15;
  int kw = wave * 16;
  const int* qix = qidx + b * NN;
  const int* kix = kidx + b * NN;
  const unsigned short* khb = khat + (size_t)b * NN * 64;
  for (int idx = t; idx < 512; idx += 256) {
    int k = idx >> 3, c8 = (idx & 7) * 8;
    uint4 v = make_uint4(0u, 0u, 0u, 0u);
    if (k0 + k < nkb) v = *(const uint4*)(khb + (size_t)kix[k0 + k] * 64 + c8);
    *(uint4*)&lk[k * LS + c8] = v;
  }
  float vacc[4] = {0.f, 0.f, 0.f, 0.f};
  for (int i0 = 0; i0 < nqb; i0 += 64) {
    __syncthreads();
    for (int idx = t; idx < 512; idx += 256) {
      int q = idx >> 3, c8 = (idx & 7) * 8;
      uint4 v = make_uint4(0u, 0u, 0u, 0u);
      if (i0 + q < nqb) v = *(const uint4*)(khb + (size_t)qix[i0 + q] * 64 + c8);
      *(uint4*)&lq[q * LS + c8] = v;
    }
    if (t < 64) {
      int qq = i0 + t;
      float d = (qq < nqb) ? den[b * NN + qq] : 0.f;
      w[t] = (d > 0.f) ? 1.f / d : 0.f;
    }
    __syncthreads();
    #pragma unroll
    for (int qt = 0; qt < 4; ++qt) {
      f32x4 s = {0.f, 0.f, 0.f, 0.f};
      #pragma unroll
      for (int h = 0; h < 2; ++h) {
        short8 a  = *(const short8*)&lk[(kw + col) * LS + h * 32 + quad * 8];
        short8 bq = *(const short8*)&lq[(qt * 16 + col) * LS + h * 32 + quad * 8];
        s = __builtin_amdgcn_mfma_f32_16x16x32_bf16(a, bq, s, 0, 0, 0);
      }
      float wq = w[qt * 16 + col];
      #pragma unroll
      for (int r = 0; r < 4; ++r) vacc[r] += __expf(20.f * s[r]) * wq;
    }
  }
  #pragma unroll
  for (int r = 0; r < 4; ++r) {
    float v = vacc[r];
    v += __shfl_xor(v, 1); v += __shfl_xor(v, 2);
    v += __shfl_xor(v, 4); v += __shfl_xor(v, 8);
    int kk = k0 + kw + quad * 4 + r;
    if (col == 0 && kk < nkb) vis[b * NN + kix[kk]] = v;
  }
}

// -------- 7a. default out = x (fp32 bit copy, 4 MB) ------------------------
__global__ __launch_bounds__(256) void k_copy(const uint4* __restrict__ src, uint4* __restrict__ dst, int n) {
  int i = blockIdx.x * 256 + threadIdx.x;
  if (i < n) dst[i] = src[i];
}

// -------- 7b. fusion epilogue over fg pixels (LDS ~43.5KB) -----------------
__global__ __launch_bounds__(256) void k_fusion(const unsigned short* __restrict__ xt,
                                                const float* __restrict__ afc,
                                                const int* __restrict__ qidx, const int* __restrict__ nqv,
                                                const float* __restrict__ w1, const float* __restrict__ w2,
                                                const float* __restrict__ b2, const float* __restrict__ wf,
                                                float* __restrict__ outp) {
  int b = blockIdx.y;
  int nqb = nqv[b];
  int q0 = blockIdx.x * 16;
  if (q0 >= nqb) return;
  __shared__ bf16 w1s[128 * 64];
  __shared__ bf16 w2s[64 * 64];
  __shared__ bf16 wfs[128 * 64];
  __shared__ float b2s[64];
  __shared__ float px[4][64];
  __shared__ float pa[4][64];
  __shared__ float pf[4][64];
  int t = threadIdx.x;
  for (int idx = t; idx < 8192; idx += 256) {
    int j = idx >> 6, c = idx & 63;
    w1s[j * 64 + c] = __float2bfloat16(w1[c * 128 + j]);
    wfs[j * 64 + c] = __float2bfloat16(wf[c * 128 + j]);
  }
  for (int idx = t; idx < 4096; idx += 256) {
    int j = idx >> 6, c = idx & 63;
    w2s[j * 64 + c] = __float2bfloat16(w2[c * 64 + j]);
  }
  if (t < 64) b2s[t] = b2[t];
  int c = t & 63, pp = t >> 6;
  const int* qix = qidx + b * NN;
  const unsigned short* xtb = xt + (size_t)b * NN * 64;
  for (int it = 0; it < 4; ++it) {
    int qq = q0 + it * 4 + pp;
    bool valid = qq < nqb;
    int qp = valid ? qix[qq] : 0;
    __syncthreads();
    px[pp][c] = valid ? us2f(xtb[(size_t)qp * 64 + c]) : 0.f;
    pa[pp][c] = valid ? afc[((size_t)b * NN + qq) * 64 + c] : 0.f;
    __syncthreads();
    float f1 = 0.f;
    for (int j = 0; j < 64; ++j) f1 += b2f(w1s[j * 64 + c]) * px[pp][j];
    for (int j = 0; j < 64; ++j) f1 += b2f(w1s[(64 + j) * 64 + c]) * pa[pp][j];
    pf[pp][c] = f1;
    __syncthreads();
    float z = b2s[c];
    for (int j = 0; j < 64; ++j) z += b2f(w2s[j * 64 + c]) * pf[pp][j];
    float sg = 1.f / (1.f + __expf(-z));
    pa[pp][c] = pa[pp][c] * (1.f - sg);
    __syncthreads();
    float fu = 0.f;
    for (int j = 0; j < 64; ++j) fu += b2f(wfs[j * 64 + c]) * px[pp][j];
    for (int j = 0; j < 64; ++j) fu += b2f(wfs[(64 + j) * 64 + c]) * pa[pp][j];
    if (valid) outp[((size_t)b * CC + c) * NN + qp] = fu;
  }
}

// -------- 8a. global max of visatt -----------------------------------------
__global__ __launch_bounds__(256) void k_vmax(const float* __restrict__ vis, unsigned int* __restrict__ vmaxb) {
  int i = blockIdx.x * 256 + threadIdx.x;
  float v = vis[i];
  #pragma unroll
  for (int off = 32; off > 0; off >>= 1) v = fmaxf(v, __shfl_down(v, off));
  if ((threadIdx.x & 63) == 0) atomicMax(vmaxb, __float_as_uint(v));
}

// -------- 8b. x8 nearest upsample + normalize ------------------------------
__global__ __launch_bounds__(256) void k_upsample(const float* __restrict__ vis,
                                                  const unsigned int* __restrict__ vmaxb,
                                                  float* __restrict__ out2) {
  int i = blockIdx.x * 256 + threadIdx.x;
  int b = i >> 18;
  int rem = i & 262143;
  int y = rem >> 9, x = rem & 511;
  float vm = __uint_as_float(vmaxb[0]);
  if (!(vm > 0.f)) vm = 1.f;
  out2[i] = vis[b * NN + (y >> 3) * 64 + (x >> 3)] / vm;
}

extern "C" void kernel_launch(void* const* d_in, const int* in_sizes, int n_in,
                              void* d_out, int out_size, void* d_ws, size_t ws_size,
                              hipStream_t stream) {
  const float* x    = (const float*)d_in[0];
  const float* mask = (const float*)d_in[1];
  const float* w1   = (const float*)d_in[2];
  const float* w2c  = (const float*)d_in[3];
  const float* fsw1 = (const float*)d_in[4];
  const float* fsw2 = (const float*)d_in[5];
  const float* fsb2 = (const float*)d_in[6];
  const float* fswf = (const float*)d_in[7];
  float* out = (float*)d_out;
  char* wsb = (char*)d_ws;

  float* afc = (float*)(wsb + WB_AFC);
  float* den = (float*)(wsb + WB_DEN);
  float* vis = (float*)(wsb + WB_VIS);
  int* qidx  = (int*)(wsb + WB_QIX);
  int* kidx  = (int*)(wsb + WB_KIX);
  unsigned char* mfl = (unsigned char*)(wsb + WB_MFL);
  int* nq = (int*)(wsb + WB_CNT);
  int* nk = nq + 4;
  unsigned int* vmaxb = (unsigned int*)(nq + 8);
  float* gstat = (float*)(wsb + WB_STAT);
  float* gsum1 = gstat;
  float* gsq1  = gstat + 256;
  float* gsum2 = gstat + 512;
  float* gsq2  = gstat + 768;

  // scratch staged inside d_out (regions dead before their final writes):
  // floats [0 .. 1M):  conv1 raw/normed (y1) -> khat (bf16, 2 MB = [0..0.5M floats)) -> final out
  // floats [1M .. 2M): conv2 raw/normed (kx) -> xt (bf16, 2 MB = [1M..1.5M floats)) -> attmask
  float* y1   = out;
  float* kx   = out + 1048576;
  unsigned short* khat = (unsigned short*)out;
  unsigned short* xt   = (unsigned short*)(out + 1048576);

  k_maxpool<<<64, 256, 0, stream>>>(mask, mfl, vis, gstat, vmaxb);
  k_compact<<<4, 64, 0, stream>>>(mfl, qidx, kidx, nq, nk);
  k_conv_raw<<<dim3(128, BB), 256, 0, stream>>>(x, w1, y1, gsum1, gsq1);
  k_inorm<<<256, 256, 0, stream>>>(y1, gsum1, gsq1, nullptr);
  k_conv_raw<<<dim3(128, BB), 256, 0, stream>>>(y1, w2c, kx, gsum2, gsq2);
  k_inorm<<<256, 256, 0, stream>>>(kx, gsum2, gsq2, x);
  k_normT<<<256, 256, 0, stream>>>(kx, khat);            // reads kx, writes khat over dead y1
  k_xT<<<256, 256, 0, stream>>>(x, xt);                  // overwrites dead kx region
  k_att1<<<dim3(64, BB), 256, 0, stream>>>(khat, xt, qidx, kidx, nq, nk, afc, den);
  k_att2<<<dim3(64, BB), 256, 0, stream>>>(khat, qidx, kidx, nq, nk, den, vis);
  k_copy<<<1024, 256, 0, stream>>>((const uint4*)x, (uint4*)out, 262144);
  k_fusion<<<dim3(256, BB), 256, 0, stream>>>(xt, afc, qidx, nq, fsw1, fsw2, fsb2, fswf, out);
  k_vmax<<<64, 256, 0, stream>>>(vis, vmaxb);
  k_upsample<<<4096, 256, 0, stream>>>(vis, vmaxb, out + 1048576);
}

// Round 8
// 500.445 us; speedup vs baseline: 3.6055x; 1.0188x over previous
//
#include <hip/hip_runtime.h>
#include <hip/hip_bf16.h>

typedef __hip_bfloat16 bf16;
typedef __attribute__((ext_vector_type(8))) short short8;
typedef __attribute__((ext_vector_type(4))) float f32x4;

#define BB 4
#define CC 64
#define NN 4096           // 64*64
#define MH 512
#define MW 512
#define LS 72             // LDS row stride in bf16 elements (144 B, 16B-mult, 2-way alias)

// ---- workspace layout (BYTE offsets; total ~4.5 MiB) ----
#define WB_AFC  ((size_t)0)         // f32[4*4096*64] att_fore NORMALIZED, pixel-major (fg rows only)
#define WB_DEN  ((size_t)4194304)   // f32[4*4096] softmax denominators (fg rows only)
#define WB_VIS  ((size_t)4259840)   // f32[4*4096] visatt
#define WB_QIX  ((size_t)4325376)   // int[4*4096]
#define WB_KIX  ((size_t)4390912)   // int[4*4096]
#define WB_MFL  ((size_t)4456448)   // uchar[4*4096]
#define WB_CNT  ((size_t)4472832)   // int nq[4]; int nk[4]; uint vmaxbits (12 ints)
#define WB_STAT ((size_t)4472896)   // f32 gsum1[256]; gsq1[256]; gsum2[256]; gsq2[256]

__device__ __forceinline__ float b2f(bf16 v) { return __bfloat162float(v); }
__device__ __forceinline__ float us2f(unsigned short u) { return __uint_as_float(((unsigned)u) << 16); }
__device__ __forceinline__ unsigned short f2bu(float f) {
  bf16 h = __float2bfloat16(f);
  return *(unsigned short*)&h;
}

// ------- 1. maxpool 8x8 on mask + zero-init vis/stats/vmax -----------------
__global__ __launch_bounds__(256) void k_maxpool(const float* __restrict__ mask,
                                                 unsigned char* __restrict__ mfl,
                                                 float* __restrict__ vis,
                                                 float* __restrict__ gstat,
                                                 unsigned int* __restrict__ vmaxb) {
  int i = blockIdx.x * 256 + threadIdx.x;          // < 4*4096
  int b = i >> 12, p = i & 4095;
  int py = p >> 6, px = p & 63;
  const float* mb = mask + (size_t)b * MH * MW + (py * 8) * MW + px * 8;
  float mx = 0.f;
  #pragma unroll
  for (int dy = 0; dy < 8; ++dy) {
    const float4* r4 = (const float4*)(mb + dy * MW);
    float4 a = r4[0], c = r4[1];
    mx = fmaxf(mx, fmaxf(fmaxf(a.x, a.y), fmaxf(a.z, a.w)));
    mx = fmaxf(mx, fmaxf(fmaxf(c.x, c.y), fmaxf(c.z, c.w)));
  }
  mfl[i] = (mx > 0.f) ? 1 : 0;
  vis[i] = 0.f;
  if (i < 1024) gstat[i] = 0.f;
  if (i == 0) vmaxb[0] = 0u;
}

// ---------------- 2. fg/bg index compaction (1 wave per batch) -------------
__global__ __launch_bounds__(64) void k_compact(const unsigned char* __restrict__ mfl,
                                                int* __restrict__ qidx, int* __restrict__ kidx,
                                                int* __restrict__ nq, int* __restrict__ nk) {
  int b = blockIdx.x, lane = threadIdx.x;
  int qb = 0, kb = 0;
  for (int it = 0; it < 64; ++it) {
    int p = it * 64 + lane;
    bool f = mfl[b * NN + p] != 0;
    unsigned long long bal = __ballot(f);
    int before = __popcll(bal & ((1ULL << lane) - 1ULL));
    if (f)  qidx[b * NN + qb + before] = p;
    if (!f) kidx[b * NN + kb + (lane - before)] = p;
    int cnt = __popcll(bal);
    qb += cnt; kb += 64 - cnt;
  }
  if (lane == 0) { nq[b] = qb; nk[b] = kb; }
}

// -------- 3a. conv3x3(pad1), ci-chunked staging (16 ci per barrier) --------
// block = (b, co-group of 4, row-band of 8 rows). 512 blocks, 256 threads.
// NORM_IN: normalize+relu the input during staging using layer-1 stats.
template <bool NORM_IN>
__global__ __launch_bounds__(256) void k_conv_raw(const float* __restrict__ in,
                                                  const float* __restrict__ wts,
                                                  const float* __restrict__ insum,
                                                  const float* __restrict__ insq,
                                                  float* __restrict__ yraw,
                                                  float* __restrict__ gsum,
                                                  float* __restrict__ gsq) {
  int b = blockIdx.y;
  int band = blockIdx.x & 7;
  int cg = blockIdx.x >> 3;        // 0..15
  int r0 = band * 8;
  __shared__ float wl[4 * 768];    // [co][ci*12 + tap]   12.3 KB
  __shared__ float tile[16 * 680]; // [ci][row*68 + col]  43.5 KB
  __shared__ float nmean[64], ninv[64];
  int t = threadIdx.x;
  for (int idx = t; idx < 4 * 576; idx += 256) {
    int co = idx / 576, rem = idx - co * 576;
    int ci = rem / 9, tap = rem - ci * 9;
    wl[co * 768 + ci * 12 + tap] = wts[(size_t)((cg * 4 + co) * 64) * 9 + rem];
  }
  if (NORM_IN && t < 64) {
    float m = insum[b * 64 + t] * (1.f / NN);
    float v = fmaxf(insq[b * 64 + t] * (1.f / NN) - m * m, 0.f);
    nmean[t] = m;
    ninv[t] = rsqrtf(v + 1e-5f);
  }
  int co = t >> 6, g = t & 63;     // wave-uniform co
  int gr = g >> 3;                 // row within band (0..7)
  int c0 = (g & 7) * 8;            // col start
  const float* inb = in + (size_t)b * CC * NN;
  float acc[8] = {};
  for (int chunk = 0; chunk < 4; ++chunk) {
    __syncthreads();
    for (int idx = t; idx < 16 * 680; idx += 256) {
      int ci = idx / 680;
      int rem = idx - ci * 680;
      int row = rem / 68, col = rem - row * 68;
      int gy = r0 - 1 + row, gx = col - 1;
      int cig = chunk * 16 + ci;
      float v = 0.f;
      if (col < 66 && (unsigned)gy < 64u && (unsigned)gx < 64u) {
        v = inb[cig * NN + gy * 64 + gx];
        if (NORM_IN) v = fmaxf((v - nmean[cig]) * ninv[cig], 0.f);
      }
      tile[idx] = v;
    }
    __syncthreads();
    for (int ci2 = 0; ci2 < 16; ++ci2) {
      int cig = chunk * 16 + ci2;
      const float* wr = &wl[co * 768 + cig * 12];
      float4 wa = *(const float4*)wr;
      float4 wb4 = *(const float4*)(wr + 4);
      float w9[9] = {wa.x, wa.y, wa.z, wa.w, wb4.x, wb4.y, wb4.z, wb4.w, wr[8]};
      float patch[3][10];
      #pragma unroll
      for (int dy = 0; dy < 3; ++dy) {
        const float* rp = &tile[ci2 * 680 + (gr + dy) * 68 + c0];
        float4 a = *(const float4*)rp;
        float4 b4 = *(const float4*)(rp + 4);
        float2 c2 = *(const float2*)(rp + 8);
        patch[dy][0] = a.x;  patch[dy][1] = a.y;  patch[dy][2] = a.z;  patch[dy][3] = a.w;
        patch[dy][4] = b4.x; patch[dy][5] = b4.y; patch[dy][6] = b4.z; patch[dy][7] = b4.w;
        patch[dy][8] = c2.x; patch[dy][9] = c2.y;
      }
      #pragma unroll
      for (int dy = 0; dy < 3; ++dy)
        #pragma unroll
        for (int dx = 0; dx < 3; ++dx) {
          float w = w9[dy * 3 + dx];
          #pragma unroll
          for (int j = 0; j < 8; ++j) acc[j] += w * patch[dy][j + dx];
        }
    }
  }
  int bc = b * CC + cg * 4 + co;
  float* yo = yraw + (size_t)bc * NN + (r0 + gr) * 64 + c0;
  *(float4*)yo       = make_float4(acc[0], acc[1], acc[2], acc[3]);
  *(float4*)(yo + 4) = make_float4(acc[4], acc[5], acc[6], acc[7]);
  float s1 = 0.f, s2 = 0.f;
  #pragma unroll
  for (int j = 0; j < 8; ++j) { s1 += acc[j]; s2 += acc[j] * acc[j]; }
  #pragma unroll
  for (int off = 32; off > 0; off >>= 1) { s1 += __shfl_down(s1, off); s2 += __shfl_down(s2, off); }
  if (g == 0) { atomicAdd(&gsum[bc], s1); atomicAdd(&gsq[bc], s2); }
}

// -------- 3b. instance-norm finalize (+ optional residual) + relu, in place
__global__ __launch_bounds__(256) void k_inorm(float* __restrict__ y,
                                               const float* __restrict__ gsum,
                                               const float* __restrict__ gsq,
                                               const float* __restrict__ addsrc) {
  int bc = blockIdx.x;
  int t = threadIdx.x;
  float mean = gsum[bc] * (1.f / NN);
  float var = fmaxf(gsq[bc] * (1.f / NN) - mean * mean, 0.f);
  float inv = rsqrtf(var + 1e-5f);
  float* yp = y + (size_t)bc * NN;
  const float* ap = addsrc ? addsrc + (size_t)bc * NN : nullptr;
  #pragma unroll
  for (int ch = 0; ch < 4; ++ch) {
    int p = ch * 1024 + t * 4;
    float4 v = *(const float4*)(yp + p);
    v.x = (v.x - mean) * inv; v.y = (v.y - mean) * inv;
    v.z = (v.z - mean) * inv; v.w = (v.w - mean) * inv;
    if (ap) {
      float4 a = *(const float4*)(ap + p);
      v.x += a.x; v.y += a.y; v.z += a.z; v.w += a.w;
    }
    v.x = fmaxf(v.x, 0.f); v.y = fmaxf(v.y, 0.f);
    v.z = fmaxf(v.z, 0.f); v.w = fmaxf(v.w, 0.f);
    *(float4*)(yp + p) = v;
  }
}

// -------- 4a. per-pixel channel L2-normalize + transpose -> bf16 pixel-major
__global__ __launch_bounds__(256) void k_normT(const float* __restrict__ kx,
                                               unsigned short* __restrict__ khat) {
  int b = blockIdx.x >> 6, p0 = (blockIdx.x & 63) * 64;
  __shared__ float lk[64][65];
  __shared__ float inv[64];
  int t = threadIdx.x;
  const float* kb = kx + (size_t)b * CC * NN + p0;
  for (int idx = t; idx < 4096; idx += 256) {
    int c = idx >> 6, j = idx & 63;
    lk[j][c] = kb[c * NN + j];
  }
  __syncthreads();
  if (t < 64) {
    float s = 0.f;
    for (int c = 0; c < 64; ++c) { float v = lk[t][c]; s += v * v; }
    inv[t] = 1.f / (sqrtf(s) + 1e-8f);
  }
  __syncthreads();
  unsigned short* kh = khat + ((size_t)b * NN + p0) * 64;
  for (int idx = t; idx < 2048; idx += 256) {
    int j = idx >> 5, c2 = (idx & 31) * 2;
    ushort2 w2;
    w2.x = f2bu(lk[j][c2] * inv[j]);
    w2.y = f2bu(lk[j][c2 + 1] * inv[j]);
    *(ushort2*)&kh[j * 64 + c2] = w2;
  }
}

// -------- 4b. transpose x -> bf16 pixel-major (xt) -------------------------
__global__ __launch_bounds__(256) void k_xT(const float* __restrict__ x,
                                            unsigned short* __restrict__ xt) {
  int b = blockIdx.x >> 6, p0 = (blockIdx.x & 63) * 64;
  __shared__ float lx[64][65];
  int t = threadIdx.x;
  const float* xb = x + (size_t)b * CC * NN + p0;
  for (int idx = t; idx < 4096; idx += 256) {
    int c = idx >> 6, j = idx & 63;
    lx[j][c] = xb[c * NN + j];
  }
  __syncthreads();
  unsigned short* xo = xt + ((size_t)b * NN + p0) * 64;
  for (int idx = t; idx < 2048; idx += 256) {
    int j = idx >> 5, c2 = (idx & 31) * 2;
    ushort2 w2;
    w2.x = f2bu(lx[j][c2]);
    w2.y = f2bu(lx[j][c2 + 1]);
    *(ushort2*)&xo[j * 64 + c2] = w2;
  }
}

// -------- 5. attention pass 1: MFMA flash-style, block owns 64 queries -----
__global__ __launch_bounds__(256) void k_att1(const unsigned short* __restrict__ khat,
                                              const unsigned short* __restrict__ xt,
                                              const int* __restrict__ qidx, const int* __restrict__ kidx,
                                              const int* __restrict__ nqv, const int* __restrict__ nkv,
                                              float* __restrict__ afc, float* __restrict__ den) {
  int b = blockIdx.y;
  int nqb = nqv[b], nkb = nkv[b];
  int q0 = blockIdx.x * 64;
  if (q0 >= nqb) return;
  __shared__ unsigned short lq [64 * LS];   // Q   [q][c]
  __shared__ unsigned short lk [64 * LS];   // K   [k][c]
  __shared__ unsigned short lvT[64 * LS];   // V^T [c][k]
  __shared__ unsigned short le [64 * LS];   // E   [q][k]
  int t = threadIdx.x;
  int wave = t >> 6, lane = t & 63;
  int quad = lane >> 4, col = lane & 15;
  int qw = wave * 16;
  const int* qix = qidx + b * NN;
  const int* kix = kidx + b * NN;
  const unsigned short* khb = khat + (size_t)b * NN * 64;
  const unsigned short* xtb = xt + (size_t)b * NN * 64;
  for (int idx = t; idx < 512; idx += 256) {
    int q = idx >> 3, c8 = (idx & 7) * 8;
    uint4 v = make_uint4(0u, 0u, 0u, 0u);
    if (q0 + q < nqb) v = *(const uint4*)(khb + (size_t)qix[q0 + q] * 64 + c8);
    *(uint4*)&lq[q * LS + c8] = v;
  }
  f32x4 pv[4] = {{0.f,0.f,0.f,0.f},{0.f,0.f,0.f,0.f},{0.f,0.f,0.f,0.f},{0.f,0.f,0.f,0.f}};
  float dsum[4] = {0.f, 0.f, 0.f, 0.f};
  for (int j0 = 0; j0 < nkb; j0 += 64) {
    __syncthreads();
    for (int idx = t; idx < 512; idx += 256) {
      int k = idx >> 3, c8 = (idx & 7) * 8;
      uint4 v = make_uint4(0u, 0u, 0u, 0u);
      uint4 vv = make_uint4(0u, 0u, 0u, 0u);
      if (j0 + k < nkb) {
        int kp = kix[j0 + k];
        v  = *(const uint4*)(khb + (size_t)kp * 64 + c8);
        vv = *(const uint4*)(xtb + (size_t)kp * 64 + c8);
      }
      *(uint4*)&lk[k * LS + c8] = v;
      unsigned short* vs = (unsigned short*)&vv;
      #pragma unroll
      for (int jj = 0; jj < 8; ++jj) lvT[(c8 + jj) * LS + k] = vs[jj];
    }
    __syncthreads();
    #pragma unroll
    for (int kt = 0; kt < 4; ++kt) {
      f32x4 s = {0.f, 0.f, 0.f, 0.f};
      #pragma unroll
      for (int h = 0; h < 2; ++h) {
        short8 a  = *(const short8*)&lq[(qw + col) * LS + h * 32 + quad * 8];
        short8 bk = *(const short8*)&lk[(kt * 16 + col) * LS + h * 32 + quad * 8];
        s = __builtin_amdgcn_mfma_f32_16x16x32_bf16(a, bk, s, 0, 0, 0);
      }
      bool kval = (j0 + kt * 16 + col) < nkb;
      #pragma unroll
      for (int r = 0; r < 4; ++r) {
        float e = kval ? __expf(20.f * s[r]) : 0.f;
        dsum[r] += e;
        le[(qw + quad * 4 + r) * LS + kt * 16 + col] = f2bu(e);
      }
    }
    __syncthreads();
    #pragma unroll
    for (int ct = 0; ct < 4; ++ct) {
      #pragma unroll
      for (int h = 0; h < 2; ++h) {
        short8 a  = *(const short8*)&le[(qw + col) * LS + h * 32 + quad * 8];
        short8 bv = *(const short8*)&lvT[(ct * 16 + col) * LS + h * 32 + quad * 8];
        pv[ct] = __builtin_amdgcn_mfma_f32_16x16x32_bf16(a, bv, pv[ct], 0, 0, 0);
      }
    }
  }
  #pragma unroll
  for (int r = 0; r < 4; ++r) {
    float v = dsum[r];
    v += __shfl_xor(v, 1); v += __shfl_xor(v, 2);
    v += __shfl_xor(v, 4); v += __shfl_xor(v, 8);
    dsum[r] = v;
  }
  #pragma unroll
  for (int r = 0; r < 4; ++r) {
    int qq = q0 + qw + quad * 4 + r;
    if (qq < nqb) {
      float dn = dsum[r];
      float invd = (dn > 0.f) ? 1.f / dn : 0.f;
      if (col == 0) den[b * NN + qq] = dn;
      float* dst = afc + ((size_t)b * NN + qq) * 64;
      #pragma unroll
      for (int ct = 0; ct < 4; ++ct) dst[ct * 16 + col] = pv[ct][r] * invd;
    }
  }
}

// -------- 6. attention pass 2: MFMA per-key visatt sums --------------------
__global__ __launch_bounds__(256) void k_att2(const unsigned short* __restrict__ khat,
                                              const int* __restrict__ qidx, const int* __restrict__ kidx,
                                              const int* __restrict__ nqv, const int* __restrict__ nkv,
                                              const float* __restrict__ den, float* __restrict__ vis) {
  int b = blockIdx.y;
  int nqb = nqv[b], nkb = nkv[b];
  int k0 = blockIdx.x * 64;
  if (k0 >= nkb) return;
  __shared__ unsigned short lk[64 * LS];
  __shared__ unsigned short lq[64 * LS];
  __shared__ float w[64];
  int t = threadIdx.x;
  int wave = t >> 6, lane = t & 63;
  int quad = lane >> 4, col = lane & 15;
  int kw = wave * 16;
  const int* qix = qidx + b * NN;
  const int* kix = kidx + b * NN;
  const unsigned short* khb = khat + (size_t)b * NN * 64;
  for (int idx = t; idx < 512; idx += 256) {
    int k = idx >> 3, c8 = (idx & 7) * 8;
    uint4 v = make_uint4(0u, 0u, 0u, 0u);
    if (k0 + k < nkb) v = *(const uint4*)(khb + (size_t)kix[k0 + k] * 64 + c8);
    *(uint4*)&lk[k * LS + c8] = v;
  }
  float vacc[4] = {0.f, 0.f, 0.f, 0.f};
  for (int i0 = 0; i0 < nqb; i0 += 64) {
    __syncthreads();
    for (int idx = t; idx < 512; idx += 256) {
      int q = idx >> 3, c8 = (idx & 7) * 8;
      uint4 v = make_uint4(0u, 0u, 0u, 0u);
      if (i0 + q < nqb) v = *(const uint4*)(khb + (size_t)qix[i0 + q] * 64 + c8);
      *(uint4*)&lq[q * LS + c8] = v;
    }
    if (t < 64) {
      int qq = i0 + t;
      float d = (qq < nqb) ? den[b * NN + qq] : 0.f;
      w[t] = (d > 0.f) ? 1.f / d : 0.f;
    }
    __syncthreads();
    #pragma unroll
    for (int qt = 0; qt < 4; ++qt) {
      f32x4 s = {0.f, 0.f, 0.f, 0.f};
      #pragma unroll
      for (int h = 0; h < 2; ++h) {
        short8 a  = *(const short8*)&lk[(kw + col) * LS + h * 32 + quad * 8];
        short8 bq = *(const short8*)&lq[(qt * 16 + col) * LS + h * 32 + quad * 8];
        s = __builtin_amdgcn_mfma_f32_16x16x32_bf16(a, bq, s, 0, 0, 0);
      }
      float wq = w[qt * 16 + col];
      #pragma unroll
      for (int r = 0; r < 4; ++r) vacc[r] += __expf(20.f * s[r]) * wq;
    }
  }
  #pragma unroll
  for (int r = 0; r < 4; ++r) {
    float v = vacc[r];
    v += __shfl_xor(v, 1); v += __shfl_xor(v, 2);
    v += __shfl_xor(v, 4); v += __shfl_xor(v, 8);
    int kk = k0 + kw + quad * 4 + r;
    if (col == 0 && kk < nkb) vis[b * NN + kix[kk]] = v;
  }
}

// -------- 7a. default out = x (fp32 bit copy, 4 MB) ------------------------
__global__ __launch_bounds__(256) void k_copy(const uint4* __restrict__ src, uint4* __restrict__ dst, int n) {
  int i = blockIdx.x * 256 + threadIdx.x;
  if (i < n) dst[i] = src[i];
}

// -------- 7b. fusion epilogue over fg pixels (LDS ~43.5KB) -----------------
__global__ __launch_bounds__(256) void k_fusion(const unsigned short* __restrict__ xt,
                                                const float* __restrict__ afc,
                                                const int* __restrict__ qidx, const int* __restrict__ nqv,
                                                const float* __restrict__ w1, const float* __restrict__ w2,
                                                const float* __restrict__ b2, const float* __restrict__ wf,
                                                float* __restrict__ outp) {
  int b = blockIdx.y;
  int nqb = nqv[b];
  int q0 = blockIdx.x * 16;
  if (q0 >= nqb) return;
  __shared__ bf16 w1s[128 * 64];
  __shared__ bf16 w2s[64 * 64];
  __shared__ bf16 wfs[128 * 64];
  __shared__ float b2s[64];
  __shared__ float px[4][64];
  __shared__ float pa[4][64];
  __shared__ float pf[4][64];
  int t = threadIdx.x;
  for (int idx = t; idx < 8192; idx += 256) {
    int j = idx >> 6, c = idx & 63;
    w1s[j * 64 + c] = __float2bfloat16(w1[c * 128 + j]);
    wfs[j * 64 + c] = __float2bfloat16(wf[c * 128 + j]);
  }
  for (int idx = t; idx < 4096; idx += 256) {
    int j = idx >> 6, c = idx & 63;
    w2s[j * 64 + c] = __float2bfloat16(w2[c * 64 + j]);
  }
  if (t < 64) b2s[t] = b2[t];
  int c = t & 63, pp = t >> 6;
  const int* qix = qidx + b * NN;
  const unsigned short* xtb = xt + (size_t)b * NN * 64;
  for (int it = 0; it < 4; ++it) {
    int qq = q0 + it * 4 + pp;
    bool valid = qq < nqb;
    int qp = valid ? qix[qq] : 0;
    __syncthreads();
    px[pp][c] = valid ? us2f(xtb[(size_t)qp * 64 + c]) : 0.f;
    pa[pp][c] = valid ? afc[((size_t)b * NN + qq) * 64 + c] : 0.f;
    __syncthreads();
    float f1 = 0.f;
    for (int j = 0; j < 64; ++j) f1 += b2f(w1s[j * 64 + c]) * px[pp][j];
    for (int j = 0; j < 64; ++j) f1 += b2f(w1s[(64 + j) * 64 + c]) * pa[pp][j];
    pf[pp][c] = f1;
    __syncthreads();
    float z = b2s[c];
    for (int j = 0; j < 64; ++j) z += b2f(w2s[j * 64 + c]) * pf[pp][j];
    float sg = 1.f / (1.f + __expf(-z));
    pa[pp][c] = pa[pp][c] * (1.f - sg);
    __syncthreads();
    float fu = 0.f;
    for (int j = 0; j < 64; ++j) fu += b2f(wfs[j * 64 + c]) * px[pp][j];
    for (int j = 0; j < 64; ++j) fu += b2f(wfs[(64 + j) * 64 + c]) * pa[pp][j];
    if (valid) outp[((size_t)b * CC + c) * NN + qp] = fu;
  }
}

// -------- 8a. global max of visatt -----------------------------------------
__global__ __launch_bounds__(256) void k_vmax(const float* __restrict__ vis, unsigned int* __restrict__ vmaxb) {
  int i = blockIdx.x * 256 + threadIdx.x;
  float v = vis[i];
  #pragma unroll
  for (int off = 32; off > 0; off >>= 1) v = fmaxf(v, __shfl_down(v, off));
  if ((threadIdx.x & 63) == 0) atomicMax(vmaxb, __float_as_uint(v));
}

// -------- 8b. x8 nearest upsample + normalize ------------------------------
__global__ __launch_bounds__(256) void k_upsample(const float* __restrict__ vis,
                                                  const unsigned int* __restrict__ vmaxb,
                                                  float* __restrict__ out2) {
  int i = blockIdx.x * 256 + threadIdx.x;
  int b = i >> 18;
  int rem = i & 262143;
  int y = rem >> 9, x = rem & 511;
  float vm = __uint_as_float(vmaxb[0]);
  if (!(vm > 0.f)) vm = 1.f;
  out2[i] = vis[b * NN + (y >> 3) * 64 + (x >> 3)] / vm;
}

extern "C" void kernel_launch(void* const* d_in, const int* in_sizes, int n_in,
                              void* d_out, int out_size, void* d_ws, size_t ws_size,
                              hipStream_t stream) {
  const float* x    = (const float*)d_in[0];
  const float* mask = (const float*)d_in[1];
  const float* w1   = (const float*)d_in[2];
  const float* w2c  = (const float*)d_in[3];
  const float* fsw1 = (const float*)d_in[4];
  const float* fsw2 = (const float*)d_in[5];
  const float* fsb2 = (const float*)d_in[6];
  const float* fswf = (const float*)d_in[7];
  float* out = (float*)d_out;
  char* wsb = (char*)d_ws;

  float* afc = (float*)(wsb + WB_AFC);
  float* den = (float*)(wsb + WB_DEN);
  float* vis = (float*)(wsb + WB_VIS);
  int* qidx  = (int*)(wsb + WB_QIX);
  int* kidx  = (int*)(wsb + WB_KIX);
  unsigned char* mfl = (unsigned char*)(wsb + WB_MFL);
  int* nq = (int*)(wsb + WB_CNT);
  int* nk = nq + 4;
  unsigned int* vmaxb = (unsigned int*)(nq + 8);
  float* gstat = (float*)(wsb + WB_STAT);
  float* gsum1 = gstat;
  float* gsq1  = gstat + 256;
  float* gsum2 = gstat + 512;
  float* gsq2  = gstat + 768;

  // scratch staged inside d_out (regions dead before their final writes):
  // floats [0 .. 1M):  conv1 raw (y1) -> khat (bf16, 2 MB) -> final out
  // floats [1M .. 2M): conv2 raw (kx) -> xt (bf16, 2 MB) -> attmask
  float* y1   = out;
  float* kx   = out + 1048576;
  unsigned short* khat = (unsigned short*)out;
  unsigned short* xt   = (unsigned short*)(out + 1048576);

  k_maxpool<<<64, 256, 0, stream>>>(mask, mfl, vis, gstat, vmaxb);
  k_compact<<<4, 64, 0, stream>>>(mfl, qidx, kidx, nq, nk);
  // conv1: raw output (un-normalized), stats into gsum1/gsq1
  k_conv_raw<false><<<dim3(128, BB), 256, 0, stream>>>(x, w1, nullptr, nullptr, y1, gsum1, gsq1);
  // conv2: normalizes+relus y1 during staging using layer-1 stats
  k_conv_raw<true><<<dim3(128, BB), 256, 0, stream>>>(y1, w2c, gsum1, gsq1, kx, gsum2, gsq2);
  // finalize kx: inorm + residual(x) + relu
  k_inorm<<<256, 256, 0, stream>>>(kx, gsum2, gsq2, x);
  k_normT<<<256, 256, 0, stream>>>(kx, khat);            // writes khat over dead y1 region
  k_xT<<<256, 256, 0, stream>>>(x, xt);                  // overwrites dead kx region
  k_att1<<<dim3(64, BB), 256, 0, stream>>>(khat, xt, qidx, kidx, nq, nk, afc, den);
  k_att2<<<dim3(64, BB), 256, 0, stream>>>(khat, qidx, kidx, nq, nk, den, vis);
  k_copy<<<1024, 256, 0, stream>>>((const uint4*)x, (uint4*)out, 262144);
  k_fusion<<<dim3(256, BB), 256, 0, stream>>>(xt, afc, qidx, nq, fsw1, fsw2, fsb2, fswf, out);
  k_vmax<<<64, 256, 0, stream>>>(vis, vmaxb);
  k_upsample<<<4096, 256, 0, stream>>>(vis, vmaxb, out + 1048576);
}

// Round 9
// 327.663 us; speedup vs baseline: 5.5067x; 1.5273x over previous
//
#include <hip/hip_runtime.h>
#include <hip/hip_bf16.h>

typedef __hip_bfloat16 bf16;
typedef __attribute__((ext_vector_type(8))) short short8;
typedef __attribute__((ext_vector_type(4))) float f32x4;

#define BB 4
#define CC 64
#define NN 4096           // 64*64
#define MH 512
#define MW 512
#define LS 72             // LDS row stride in bf16 elements (144 B, 16B-mult, 2-way alias)

// ---- workspace layout (BYTE offsets; total ~4.62 MiB) ----
#define WB_AFC  ((size_t)0)         // f32[4*4096*64] att_fore NORMALIZED, pixel-major (fg rows only)
                                    // first 2 MB double as y1t (bf16 conv1 raw) before att1
#define WB_DEN  ((size_t)4194304)   // f32[4*4096] softmax denominators (fg rows only)
#define WB_VIS  ((size_t)4259840)   // f32[4*4096] visatt
#define WB_QIX  ((size_t)4325376)   // int[4*4096]
#define WB_KIX  ((size_t)4390912)   // int[4*4096]
#define WB_MFL  ((size_t)4456448)   // uchar[4*4096]
#define WB_CNT  ((size_t)4472832)   // int nq[4]; int nk[4]; uint vmaxbits (12 ints)
#define WB_STAT ((size_t)4472896)   // f32 gsum1[256]; gsq1[256]; gsum2[256]; gsq2[256]
#define WB_WT1  ((size_t)4476992)   // bf16[9*64*64] wT1 (73728 B)
#define WB_WT2  ((size_t)4550720)   // bf16[9*64*64] wT2 (73728 B)

__device__ __forceinline__ float b2f(bf16 v) { return __bfloat162float(v); }
__device__ __forceinline__ float us2f(unsigned short u) { return __uint_as_float(((unsigned)u) << 16); }
__device__ __forceinline__ unsigned short f2bu(float f) {
  bf16 h = __float2bfloat16(f);
  return *(unsigned short*)&h;
}

// ------- 1. maxpool 8x8 on mask + zero-init vis/stats/vmax -----------------
__global__ __launch_bounds__(256) void k_maxpool(const float* __restrict__ mask,
                                                 unsigned char* __restrict__ mfl,
                                                 float* __restrict__ vis,
                                                 float* __restrict__ gstat,
                                                 unsigned int* __restrict__ vmaxb) {
  int i = blockIdx.x * 256 + threadIdx.x;          // < 4*4096
  int b = i >> 12, p = i & 4095;
  int py = p >> 6, px = p & 63;
  const float* mb = mask + (size_t)b * MH * MW + (py * 8) * MW + px * 8;
  float mx = 0.f;
  #pragma unroll
  for (int dy = 0; dy < 8; ++dy) {
    const float4* r4 = (const float4*)(mb + dy * MW);
    float4 a = r4[0], c = r4[1];
    mx = fmaxf(mx, fmaxf(fmaxf(a.x, a.y), fmaxf(a.z, a.w)));
    mx = fmaxf(mx, fmaxf(fmaxf(c.x, c.y), fmaxf(c.z, c.w)));
  }
  mfl[i] = (mx > 0.f) ? 1 : 0;
  vis[i] = 0.f;
  if (i < 1024) gstat[i] = 0.f;
  if (i == 0) vmaxb[0] = 0u;
}

// ---------------- 2. fg/bg index compaction (1 wave per batch) -------------
__global__ __launch_bounds__(64) void k_compact(const unsigned char* __restrict__ mfl,
                                                int* __restrict__ qidx, int* __restrict__ kidx,
                                                int* __restrict__ nq, int* __restrict__ nk) {
  int b = blockIdx.x, lane = threadIdx.x;
  int qb = 0, kb = 0;
  for (int it = 0; it < 64; ++it) {
    int p = it * 64 + lane;
    bool f = mfl[b * NN + p] != 0;
    unsigned long long bal = __ballot(f);
    int before = __popcll(bal & ((1ULL << lane) - 1ULL));
    if (f)  qidx[b * NN + qb + before] = p;
    if (!f) kidx[b * NN + kb + (lane - before)] = p;
    int cnt = __popcll(bal);
    qb += cnt; kb += 64 - cnt;
  }
  if (lane == 0) { nq[b] = qb; nk[b] = kb; }
}

// -------- 3. transpose x -> bf16 pixel-major (xt) --------------------------
__global__ __launch_bounds__(256) void k_xT(const float* __restrict__ x,
                                            unsigned short* __restrict__ xt) {
  int b = blockIdx.x >> 6, p0 = (blockIdx.x & 63) * 64;
  __shared__ float lx[64][65];
  int t = threadIdx.x;
  const float* xb = x + (size_t)b * CC * NN + p0;
  for (int idx = t; idx < 4096; idx += 256) {
    int c = idx >> 6, j = idx & 63;
    lx[j][c] = xb[c * NN + j];
  }
  __syncthreads();
  unsigned short* xo = xt + ((size_t)b * NN + p0) * 64;
  for (int idx = t; idx < 2048; idx += 256) {
    int j = idx >> 5, c2 = (idx & 31) * 2;
    ushort2 w2;
    w2.x = f2bu(lx[j][c2]);
    w2.y = f2bu(lx[j][c2 + 1]);
    *(ushort2*)&xo[j * 64 + c2] = w2;
  }
}

// -------- 4. weight transform: w[co][ci][tap] fp32 -> wT[tap][co][ci] bf16 -
__global__ __launch_bounds__(256) void k_wprep(const float* __restrict__ w1,
                                               const float* __restrict__ w2,
                                               unsigned short* __restrict__ wT1,
                                               unsigned short* __restrict__ wT2) {
  int i = blockIdx.x * 256 + threadIdx.x;   // < 36864
  if (i >= 36864) return;
  int tap = i >> 12;          // i / 4096
  int rem = i & 4095;
  int co = rem >> 6, ci = rem & 63;
  int src = (co * 64 + ci) * 9 + tap;
  wT1[i] = f2bu(w1[src]);
  wT2[i] = f2bu(w2[src]);
}

// -------- 5. MFMA conv3x3(pad1) as 9 row-gathered GEMMs --------------------
// block = (b, image row r). 256 blocks, 4 waves; wave owns a 16-co strip.
// src: pixel-major bf16 [b][p][ci]; dst: pixel-major bf16 raw conv output.
// NORM_IN: apply layer-1 instance-norm + relu to src during staging.
template <bool NORM_IN>
__global__ __launch_bounds__(256) void k_convm(const unsigned short* __restrict__ src,
                                               const unsigned short* __restrict__ wT,
                                               const float* __restrict__ insum,
                                               const float* __restrict__ insq,
                                               unsigned short* __restrict__ dst,
                                               float* __restrict__ gsum,
                                               float* __restrict__ gsq) {
  int b = blockIdx.y;
  int r = blockIdx.x;              // image row 0..63
  __shared__ unsigned short bx[198 * LS];   // [dy*66 + cx+1][ci], 28.5 KB
  __shared__ float nmean[64], ninv[64];
  int t = threadIdx.x;
  if (NORM_IN) {
    if (t < 64) {
      float m = insum[b * 64 + t] * (1.f / NN);
      float v = fmaxf(insq[b * 64 + t] * (1.f / NN) - m * m, 0.f);
      nmean[t] = m; ninv[t] = rsqrtf(v + 1e-5f);
    }
    __syncthreads();
  }
  const unsigned short* sb = src + (size_t)b * NN * 64;
  for (int idx = t; idx < 198 * 8; idx += 256) {
    int row = idx >> 3, c8 = (idx & 7) * 8;
    int dy = row / 66;
    int cx = row - dy * 66 - 1;
    int rr = r + dy - 1;
    uint4 v = make_uint4(0u, 0u, 0u, 0u);
    if ((unsigned)rr < 64u && (unsigned)cx < 64u) {
      v = *(const uint4*)(sb + ((size_t)(rr * 64 + cx)) * 64 + c8);
      if (NORM_IN) {
        unsigned short* e = (unsigned short*)&v;
        #pragma unroll
        for (int j = 0; j < 8; ++j)
          e[j] = f2bu(fmaxf((us2f(e[j]) - nmean[c8 + j]) * ninv[c8 + j], 0.f));
      }
    }
    *(uint4*)&bx[row * LS + c8] = v;
  }
  __syncthreads();
  int lane = t & 63;
  int quad = lane >> 4, col = lane & 15;
  int qw = (t >> 6) * 16;          // co strip
  f32x4 acc[4] = {{0.f,0.f,0.f,0.f},{0.f,0.f,0.f,0.f},{0.f,0.f,0.f,0.f},{0.f,0.f,0.f,0.f}};
  #pragma unroll
  for (int tap = 0; tap < 9; ++tap) {
    int dy = tap / 3, dx = tap - dy * 3 - 1;
    const unsigned short* wrow = wT + ((size_t)tap * 64 + qw + col) * 64;
    short8 a0 = *(const short8*)(wrow + quad * 8);
    short8 a1 = *(const short8*)(wrow + 32 + quad * 8);
    int rbase = dy * 66 + dx + 1;
    #pragma unroll
    for (int nt = 0; nt < 4; ++nt) {
      int row = rbase + nt * 16 + col;
      short8 b0 = *(const short8*)&bx[row * LS + quad * 8];
      short8 b1 = *(const short8*)&bx[row * LS + 32 + quad * 8];
      acc[nt] = __builtin_amdgcn_mfma_f32_16x16x32_bf16(a0, b0, acc[nt], 0, 0, 0);
      acc[nt] = __builtin_amdgcn_mfma_f32_16x16x32_bf16(a1, b1, acc[nt], 0, 0, 0);
    }
  }
  // per-(b,co) partial stats from fp32 accumulators
  #pragma unroll
  for (int rr = 0; rr < 4; ++rr) {
    float s1 = acc[0][rr] + acc[1][rr] + acc[2][rr] + acc[3][rr];
    float s2 = acc[0][rr]*acc[0][rr] + acc[1][rr]*acc[1][rr]
             + acc[2][rr]*acc[2][rr] + acc[3][rr]*acc[3][rr];
    s1 += __shfl_xor(s1, 1); s2 += __shfl_xor(s2, 1);
    s1 += __shfl_xor(s1, 2); s2 += __shfl_xor(s2, 2);
    s1 += __shfl_xor(s1, 4); s2 += __shfl_xor(s2, 4);
    s1 += __shfl_xor(s1, 8); s2 += __shfl_xor(s2, 8);
    if (col == 0) {
      int co = qw + quad * 4 + rr;
      atomicAdd(&gsum[b * 64 + co], s1);
      atomicAdd(&gsq[b * 64 + co], s2);
    }
  }
  // repack D -> [px][co] bf16 in LDS, then coalesced store
  __syncthreads();
  #pragma unroll
  for (int nt = 0; nt < 4; ++nt)
    #pragma unroll
    for (int rr = 0; rr < 4; ++rr)
      bx[(nt * 16 + col) * LS + qw + quad * 4 + rr] = f2bu(acc[nt][rr]);
  __syncthreads();
  unsigned short* db = dst + ((size_t)b * NN + r * 64) * 64;
  for (int idx = t; idx < 512; idx += 256) {
    int px = idx >> 3, c8 = (idx & 7) * 8;
    *(uint4*)(db + (size_t)px * 64 + c8) = *(const uint4*)&bx[px * LS + c8];
  }
}

// -------- 6. fused inorm2 + residual + relu + per-pixel L2-norm (in place) -
__global__ __launch_bounds__(256) void k_knorm(unsigned short* __restrict__ kxt,
                                               const unsigned short* __restrict__ xt,
                                               const float* __restrict__ gsum,
                                               const float* __restrict__ gsq) {
  int b = blockIdx.x >> 6;
  int p0 = (blockIdx.x & 63) * 64;
  __shared__ float m2[64], i2[64];
  int t = threadIdx.x;
  if (t < 64) {
    float m = gsum[b * 64 + t] * (1.f / NN);
    float v = fmaxf(gsq[b * 64 + t] * (1.f / NN) - m * m, 0.f);
    m2[t] = m; i2[t] = rsqrtf(v + 1e-5f);
  }
  __syncthreads();
  int px = t >> 2, c0 = (t & 3) * 16;
  size_t base = ((size_t)b * NN + p0 + px) * 64 + c0;
  unsigned short kv[16], xv[16];
  *(uint4*)&kv[0] = *(const uint4*)(kxt + base);
  *(uint4*)&kv[8] = *(const uint4*)(kxt + base + 8);
  *(uint4*)&xv[0] = *(const uint4*)(xt + base);
  *(uint4*)&xv[8] = *(const uint4*)(xt + base + 8);
  float v[16]; float ss = 0.f;
  #pragma unroll
  for (int j = 0; j < 16; ++j) {
    float f = fmaxf((us2f(kv[j]) - m2[c0 + j]) * i2[c0 + j] + us2f(xv[j]), 0.f);
    v[j] = f; ss += f * f;
  }
  ss += __shfl_xor(ss, 1);
  ss += __shfl_xor(ss, 2);
  float inv = 1.f / (sqrtf(ss) + 1e-8f);
  #pragma unroll
  for (int j = 0; j < 16; ++j) kv[j] = f2bu(v[j] * inv);
  *(uint4*)(kxt + base) = *(const uint4*)&kv[0];
  *(uint4*)(kxt + base + 8) = *(const uint4*)&kv[8];
}

// -------- 7. attention pass 1: MFMA flash-style, block owns 64 queries -----
__global__ __launch_bounds__(256) void k_att1(const unsigned short* __restrict__ khat,
                                              const unsigned short* __restrict__ xt,
                                              const int* __restrict__ qidx, const int* __restrict__ kidx,
                                              const int* __restrict__ nqv, const int* __restrict__ nkv,
                                              float* __restrict__ afc, float* __restrict__ den) {
  int b = blockIdx.y;
  int nqb = nqv[b], nkb = nkv[b];
  int q0 = blockIdx.x * 64;
  if (q0 >= nqb) return;
  __shared__ unsigned short lq [64 * LS];   // Q   [q][c]
  __shared__ unsigned short lk [64 * LS];   // K   [k][c]
  __shared__ unsigned short lvT[64 * LS];   // V^T [c][k]
  __shared__ unsigned short le [64 * LS];   // E   [q][k]
  int t = threadIdx.x;
  int wave = t >> 6, lane = t & 63;
  int quad = lane >> 4, col = lane & 15;
  int qw = wave * 16;
  const int* qix = qidx + b * NN;
  const int* kix = kidx + b * NN;
  const unsigned short* khb = khat + (size_t)b * NN * 64;
  const unsigned short* xtb = xt + (size_t)b * NN * 64;
  for (int idx = t; idx < 512; idx += 256) {
    int q = idx >> 3, c8 = (idx & 7) * 8;
    uint4 v = make_uint4(0u, 0u, 0u, 0u);
    if (q0 + q < nqb) v = *(const uint4*)(khb + (size_t)qix[q0 + q] * 64 + c8);
    *(uint4*)&lq[q * LS + c8] = v;
  }
  f32x4 pv[4] = {{0.f,0.f,0.f,0.f},{0.f,0.f,0.f,0.f},{0.f,0.f,0.f,0.f},{0.f,0.f,0.f,0.f}};
  float dsum[4] = {0.f, 0.f, 0.f, 0.f};
  for (int j0 = 0; j0 < nkb; j0 += 64) {
    __syncthreads();
    for (int idx = t; idx < 512; idx += 256) {
      int k = idx >> 3, c8 = (idx & 7) * 8;
      uint4 v = make_uint4(0u, 0u, 0u, 0u);
      uint4 vv = make_uint4(0u, 0u, 0u, 0u);
      if (j0 + k < nkb) {
        int kp = kix[j0 + k];
        v  = *(const uint4*)(khb + (size_t)kp * 64 + c8);
        vv = *(const uint4*)(xtb + (size_t)kp * 64 + c8);
      }
      *(uint4*)&lk[k * LS + c8] = v;
      unsigned short* vs = (unsigned short*)&vv;
      #pragma unroll
      for (int jj = 0; jj < 8; ++jj) lvT[(c8 + jj) * LS + k] = vs[jj];
    }
    __syncthreads();
    #pragma unroll
    for (int kt = 0; kt < 4; ++kt) {
      f32x4 s = {0.f, 0.f, 0.f, 0.f};
      #pragma unroll
      for (int h = 0; h < 2; ++h) {
        short8 a  = *(const short8*)&lq[(qw + col) * LS + h * 32 + quad * 8];
        short8 bk = *(const short8*)&lk[(kt * 16 + col) * LS + h * 32 + quad * 8];
        s = __builtin_amdgcn_mfma_f32_16x16x32_bf16(a, bk, s, 0, 0, 0);
      }
      bool kval = (j0 + kt * 16 + col) < nkb;
      #pragma unroll
      for (int r = 0; r < 4; ++r) {
        float e = kval ? __expf(20.f * s[r]) : 0.f;
        dsum[r] += e;
        le[(qw + quad * 4 + r) * LS + kt * 16 + col] = f2bu(e);
      }
    }
    __syncthreads();
    #pragma unroll
    for (int ct = 0; ct < 4; ++ct) {
      #pragma unroll
      for (int h = 0; h < 2; ++h) {
        short8 a  = *(const short8*)&le[(qw + col) * LS + h * 32 + quad * 8];
        short8 bv = *(const short8*)&lvT[(ct * 16 + col) * LS + h * 32 + quad * 8];
        pv[ct] = __builtin_amdgcn_mfma_f32_16x16x32_bf16(a, bv, pv[ct], 0, 0, 0);
      }
    }
  }
  #pragma unroll
  for (int r = 0; r < 4; ++r) {
    float v = dsum[r];
    v += __shfl_xor(v, 1); v += __shfl_xor(v, 2);
    v += __shfl_xor(v, 4); v += __shfl_xor(v, 8);
    dsum[r] = v;
  }
  #pragma unroll
  for (int r = 0; r < 4; ++r) {
    int qq = q0 + qw + quad * 4 + r;
    if (qq < nqb) {
      float dn = dsum[r];
      float invd = (dn > 0.f) ? 1.f / dn : 0.f;
      if (col == 0) den[b * NN + qq] = dn;
      float* dst = afc + ((size_t)b * NN + qq) * 64;
      #pragma unroll
      for (int ct = 0; ct < 4; ++ct) dst[ct * 16 + col] = pv[ct][r] * invd;
    }
  }
}

// -------- 8. attention pass 2: MFMA per-key visatt sums --------------------
__global__ __launch_bounds__(256) void k_att2(const unsigned short* __restrict__ khat,
                                              const int* __restrict__ qidx, const int* __restrict__ kidx,
                                              const int* __restrict__ nqv, const int* __restrict__ nkv,
                                              const float* __restrict__ den, float* __restrict__ vis) {
  int b = blockIdx.y;
  int nqb = nqv[b], nkb = nkv[b];
  int k0 = blockIdx.x * 64;
  if (k0 >= nkb) return;
  __shared__ unsigned short lk[64 * LS];
  __shared__ unsigned short lq[64 * LS];
  __shared__ float w[64];
  int t = threadIdx.x;
  int wave = t >> 6, lane = t & 63;
  int quad = lane >> 4, col = lane & 15;
  int kw = wave * 16;
  const int* qix = qidx + b * NN;
  const int* kix = kidx + b * NN;
  const unsigned short* khb = khat + (size_t)b * NN * 64;
  for (int idx = t; idx < 512; idx += 256) {
    int k = idx >> 3, c8 = (idx & 7) * 8;
    uint4 v = make_uint4(0u, 0u, 0u, 0u);
    if (k0 + k < nkb) v = *(const uint4*)(khb + (size_t)kix[k0 + k] * 64 + c8);
    *(uint4*)&lk[k * LS + c8] = v;
  }
  float vacc[4] = {0.f, 0.f, 0.f, 0.f};
  for (int i0 = 0; i0 < nqb; i0 += 64) {
    __syncthreads();
    for (int idx = t; idx < 512; idx += 256) {
      int q = idx >> 3, c8 = (idx & 7) * 8;
      uint4 v = make_uint4(0u, 0u, 0u, 0u);
      if (i0 + q < nqb) v = *(const uint4*)(khb + (size_t)qix[i0 + q] * 64 + c8);
      *(uint4*)&lq[q * LS + c8] = v;
    }
    if (t < 64) {
      int qq = i0 + t;
      float d = (qq < nqb) ? den[b * NN + qq] : 0.f;
      w[t] = (d > 0.f) ? 1.f / d : 0.f;
    }
    __syncthreads();
    #pragma unroll
    for (int qt = 0; qt < 4; ++qt) {
      f32x4 s = {0.f, 0.f, 0.f, 0.f};
      #pragma unroll
      for (int h = 0; h < 2; ++h) {
        short8 a  = *(const short8*)&lk[(kw + col) * LS + h * 32 + quad * 8];
        short8 bq = *(const short8*)&lq[(qt * 16 + col) * LS + h * 32 + quad * 8];
        s = __builtin_amdgcn_mfma_f32_16x16x32_bf16(a, bq, s, 0, 0, 0);
      }
      float wq = w[qt * 16 + col];
      #pragma unroll
      for (int r = 0; r < 4; ++r) vacc[r] += __expf(20.f * s[r]) * wq;
    }
  }
  #pragma unroll
  for (int r = 0; r < 4; ++r) {
    float v = vacc[r];
    v += __shfl_xor(v, 1); v += __shfl_xor(v, 2);
    v += __shfl_xor(v, 4); v += __shfl_xor(v, 8);
    int kk = k0 + kw + quad * 4 + r;
    if (col == 0 && kk < nkb) vis[b * NN + kix[kk]] = v;
  }
}

// -------- 9a. default out = x (fp32 bit copy, 4 MB) ------------------------
__global__ __launch_bounds__(256) void k_copy(const uint4* __restrict__ src, uint4* __restrict__ dst, int n) {
  int i = blockIdx.x * 256 + threadIdx.x;
  if (i < n) dst[i] = src[i];
}

// -------- 9b. fusion epilogue over fg pixels (LDS ~43.5KB) -----------------
__global__ __launch_bounds__(256) void k_fusion(const unsigned short* __restrict__ xt,
                                                const float* __restrict__ afc,
                                                const int* __restrict__ qidx, const int* __restrict__ nqv,
                                                const float* __restrict__ w1, const float* __restrict__ w2,
                                                const float* __restrict__ b2, const float* __restrict__ wf,
                                                float* __restrict__ outp) {
  int b = blockIdx.y;
  int nqb = nqv[b];
  int q0 = blockIdx.x * 16;
  if (q0 >= nqb) return;
  __shared__ bf16 w1s[128 * 64];
  __shared__ bf16 w2s[64 * 64];
  __shared__ bf16 wfs[128 * 64];
  __shared__ float b2s[64];
  __shared__ float px[4][64];
  __shared__ float pa[4][64];
  __shared__ float pf[4][64];
  int t = threadIdx.x;
  for (int idx = t; idx < 8192; idx += 256) {
    int j = idx >> 6, c = idx & 63;
    w1s[j * 64 + c] = __float2bfloat16(w1[c * 128 + j]);
    wfs[j * 64 + c] = __float2bfloat16(wf[c * 128 + j]);
  }
  for (int idx = t; idx < 4096; idx += 256) {
    int j = idx >> 6, c = idx & 63;
    w2s[j * 64 + c] = __float2bfloat16(w2[c * 64 + j]);
  }
  if (t < 64) b2s[t] = b2[t];
  int c = t & 63, pp = t >> 6;
  const int* qix = qidx + b * NN;
  const unsigned short* xtb = xt + (size_t)b * NN * 64;
  for (int it = 0; it < 4; ++it) {
    int qq = q0 + it * 4 + pp;
    bool valid = qq < nqb;
    int qp = valid ? qix[qq] : 0;
    __syncthreads();
    px[pp][c] = valid ? us2f(xtb[(size_t)qp * 64 + c]) : 0.f;
    pa[pp][c] = valid ? afc[((size_t)b * NN + qq) * 64 + c] : 0.f;
    __syncthreads();
    float f1 = 0.f;
    for (int j = 0; j < 64; ++j) f1 += b2f(w1s[j * 64 + c]) * px[pp][j];
    for (int j = 0; j < 64; ++j) f1 += b2f(w1s[(64 + j) * 64 + c]) * pa[pp][j];
    pf[pp][c] = f1;
    __syncthreads();
    float z = b2s[c];
    for (int j = 0; j < 64; ++j) z += b2f(w2s[j * 64 + c]) * pf[pp][j];
    float sg = 1.f / (1.f + __expf(-z));
    pa[pp][c] = pa[pp][c] * (1.f - sg);
    __syncthreads();
    float fu = 0.f;
    for (int j = 0; j < 64; ++j) fu += b2f(wfs[j * 64 + c]) * px[pp][j];
    for (int j = 0; j < 64; ++j) fu += b2f(wfs[(64 + j) * 64 + c]) * pa[pp][j];
    if (valid) outp[((size_t)b * CC + c) * NN + qp] = fu;
  }
}

// -------- 10a. global max of visatt ----------------------------------------
__global__ __launch_bounds__(256) void k_vmax(const float* __restrict__ vis, unsigned int* __restrict__ vmaxb) {
  int i = blockIdx.x * 256 + threadIdx.x;
  float v = vis[i];
  #pragma unroll
  for (int off = 32; off > 0; off >>= 1) v = fmaxf(v, __shfl_down(v, off));
  if ((threadIdx.x & 63) == 0) atomicMax(vmaxb, __float_as_uint(v));
}

// -------- 10b. x8 nearest upsample + normalize -----------------------------
__global__ __launch_bounds__(256) void k_upsample(const float* __restrict__ vis,
                                                  const unsigned int* __restrict__ vmaxb,
                                                  float* __restrict__ out2) {
  int i = blockIdx.x * 256 + threadIdx.x;
  int b = i >> 18;
  int rem = i & 262143;
  int y = rem >> 9, x = rem & 511;
  float vm = __uint_as_float(vmaxb[0]);
  if (!(vm > 0.f)) vm = 1.f;
  out2[i] = vis[b * NN + (y >> 3) * 64 + (x >> 3)] / vm;
}

extern "C" void kernel_launch(void* const* d_in, const int* in_sizes, int n_in,
                              void* d_out, int out_size, void* d_ws, size_t ws_size,
                              hipStream_t stream) {
  const float* x    = (const float*)d_in[0];
  const float* mask = (const float*)d_in[1];
  const float* w1   = (const float*)d_in[2];
  const float* w2c  = (const float*)d_in[3];
  const float* fsw1 = (const float*)d_in[4];
  const float* fsw2 = (const float*)d_in[5];
  const float* fsb2 = (const float*)d_in[6];
  const float* fswf = (const float*)d_in[7];
  float* out = (float*)d_out;
  char* wsb = (char*)d_ws;

  float* afc = (float*)(wsb + WB_AFC);
  float* den = (float*)(wsb + WB_DEN);
  float* vis = (float*)(wsb + WB_VIS);
  int* qidx  = (int*)(wsb + WB_QIX);
  int* kidx  = (int*)(wsb + WB_KIX);
  unsigned char* mfl = (unsigned char*)(wsb + WB_MFL);
  int* nq = (int*)(wsb + WB_CNT);
  int* nk = nq + 4;
  unsigned int* vmaxb = (unsigned int*)(nq + 8);
  float* gstat = (float*)(wsb + WB_STAT);
  float* gsum1 = gstat;
  float* gsq1  = gstat + 256;
  float* gsum2 = gstat + 512;
  float* gsq2  = gstat + 768;
  unsigned short* wT1 = (unsigned short*)(wsb + WB_WT1);
  unsigned short* wT2 = (unsigned short*)(wsb + WB_WT2);
  unsigned short* y1t = (unsigned short*)(wsb + WB_AFC);   // 2 MB, dead before att1 writes afc

  // scratch staged inside d_out (regions dead before their final writes):
  // floats [0 .. 0.5M):  kxt raw bf16 -> khat bf16 (in place) -> final out (k_copy)
  // floats [1M .. 1.5M): xt bf16 -> attmask (k_upsample, after fusion reads xt)
  unsigned short* kxt = (unsigned short*)out;
  unsigned short* khat = kxt;
  unsigned short* xt = (unsigned short*)(out + 1048576);

  k_maxpool<<<64, 256, 0, stream>>>(mask, mfl, vis, gstat, vmaxb);
  k_compact<<<4, 64, 0, stream>>>(mfl, qidx, kidx, nq, nk);
  k_xT<<<256, 256, 0, stream>>>(x, xt);
  k_wprep<<<144, 256, 0, stream>>>(w1, w2c, wT1, wT2);
  // conv1: B = xt, raw bf16 out y1t + fp32 stats
  k_convm<false><<<dim3(64, BB), 256, 0, stream>>>(xt, wT1, nullptr, nullptr, y1t, gsum1, gsq1);
  // conv2: B = inorm1(y1t) fused in staging, raw bf16 out kxt + stats
  k_convm<true><<<dim3(64, BB), 256, 0, stream>>>(y1t, wT2, gsum1, gsq1, kxt, gsum2, gsq2);
  // inorm2 + residual(xt) + relu + per-pixel L2 normalize, in place -> khat
  k_knorm<<<256, 256, 0, stream>>>(kxt, xt, gsum2, gsq2);
  k_att1<<<dim3(64, BB), 256, 0, stream>>>(khat, xt, qidx, kidx, nq, nk, afc, den);
  k_att2<<<dim3(64, BB), 256, 0, stream>>>(khat, qidx, kidx, nq, nk, den, vis);
  k_copy<<<1024, 256, 0, stream>>>((const uint4*)x, (uint4*)out, 262144);
  k_fusion<<<dim3(256, BB), 256, 0, stream>>>(xt, afc, qidx, nq, fsw1, fsw2, fsb2, fswf, out);
  k_vmax<<<64, 256, 0, stream>>>(vis, vmaxb);
  k_upsample<<<4096, 256, 0, stream>>>(vis, vmaxb, out + 1048576);
}

// Round 10
// 246.308 us; speedup vs baseline: 7.3255x; 1.3303x over previous
//
#include <hip/hip_runtime.h>
#include <hip/hip_bf16.h>

typedef __hip_bfloat16 bf16;
typedef __attribute__((ext_vector_type(8))) short short8;
typedef __attribute__((ext_vector_type(4))) float f32x4;

#define BB 4
#define CC 64
#define NN 4096           // 64*64
#define MH 512
#define MW 512
#define LS 72             // LDS row stride in bf16 elements

// ---- workspace layout (BYTE offsets; total ~4.62 MiB) ----
#define WB_AFC  ((size_t)0)         // f32[4*4096*64] att_fore UNNORMALIZED sums (atomic)
                                    // first 2 MB double as y1t (bf16 conv1 raw) before k_knorm
#define WB_DEN  ((size_t)4194304)   // f32[4*4096] softmax denominators (atomic)
#define WB_VIS  ((size_t)4259840)   // f32[4*4096] visatt (atomic)
#define WB_QIX  ((size_t)4325376)   // int[4*4096]
#define WB_KIX  ((size_t)4390912)   // int[4*4096]
#define WB_MFL  ((size_t)4456448)   // uchar[4*4096]
#define WB_CNT  ((size_t)4472832)   // int nq[4]; int nk[4]; uint vmaxbits (12 ints)
#define WB_STAT ((size_t)4472896)   // f32 gsum1[256]; gsq1[256]; gsum2[256]; gsq2[256]
#define WB_WT1  ((size_t)4476992)   // bf16[9*64*64] wT1
#define WB_WT2  ((size_t)4550720)   // bf16[9*64*64] wT2

__device__ __forceinline__ float b2f(bf16 v) { return __bfloat162float(v); }
__device__ __forceinline__ float us2f(unsigned short u) { return __uint_as_float(((unsigned)u) << 16); }
__device__ __forceinline__ unsigned short f2bu(float f) {
  bf16 h = __float2bfloat16(f);
  return *(unsigned short*)&h;
}

// ------- 1. maxpool 8x8 on mask (4 lanes/window) + zero vis/stats/vmax -----
__global__ __launch_bounds__(256) void k_maxpool(const float* __restrict__ mask,
                                                 unsigned char* __restrict__ mfl,
                                                 float* __restrict__ vis,
                                                 float* __restrict__ gstat,
                                                 unsigned int* __restrict__ vmaxb) {
  int g = blockIdx.x * 256 + threadIdx.x;          // < 4*4096*4
  int o = g >> 2, sub = g & 3;
  int b = o >> 12, p = o & 4095;
  int py = p >> 6, px = p & 63;
  const float* mb = mask + (size_t)b * MH * MW + (py * 8 + sub * 2) * MW + px * 8;
  float mx = 0.f;
  #pragma unroll
  for (int dy = 0; dy < 2; ++dy) {
    const float4* r4 = (const float4*)(mb + dy * MW);
    float4 a = r4[0], c = r4[1];
    mx = fmaxf(mx, fmaxf(fmaxf(a.x, a.y), fmaxf(a.z, a.w)));
    mx = fmaxf(mx, fmaxf(fmaxf(c.x, c.y), fmaxf(c.z, c.w)));
  }
  mx = fmaxf(mx, __shfl_xor(mx, 1));
  mx = fmaxf(mx, __shfl_xor(mx, 2));
  if (sub == 0) {
    mfl[o] = (mx > 0.f) ? 1 : 0;
    vis[o] = 0.f;
  }
  if (g < 1024) gstat[g] = 0.f;
  if (g == 0) vmaxb[0] = 0u;
}

// ---------------- 2. fg/bg index compaction (1 wave per batch) -------------
__global__ __launch_bounds__(64) void k_compact(const unsigned char* __restrict__ mfl,
                                                int* __restrict__ qidx, int* __restrict__ kidx,
                                                int* __restrict__ nq, int* __restrict__ nk) {
  int b = blockIdx.x, lane = threadIdx.x;
  int qb = 0, kb = 0;
  for (int it = 0; it < 64; ++it) {
    int p = it * 64 + lane;
    bool f = mfl[b * NN + p] != 0;
    unsigned long long bal = __ballot(f);
    int before = __popcll(bal & ((1ULL << lane) - 1ULL));
    if (f)  qidx[b * NN + qb + before] = p;
    if (!f) kidx[b * NN + kb + (lane - before)] = p;
    int cnt = __popcll(bal);
    qb += cnt; kb += 64 - cnt;
  }
  if (lane == 0) { nq[b] = qb; nk[b] = kb; }
}

// -------- 3. transpose x -> bf16 pixel-major (xt) --------------------------
__global__ __launch_bounds__(256) void k_xT(const float* __restrict__ x,
                                            unsigned short* __restrict__ xt) {
  int b = blockIdx.x >> 6, p0 = (blockIdx.x & 63) * 64;
  __shared__ float lx[64][65];
  int t = threadIdx.x;
  const float* xb = x + (size_t)b * CC * NN + p0;
  for (int idx = t; idx < 4096; idx += 256) {
    int c = idx >> 6, j = idx & 63;
    lx[j][c] = xb[c * NN + j];
  }
  __syncthreads();
  unsigned short* xo = xt + ((size_t)b * NN + p0) * 64;
  for (int idx = t; idx < 2048; idx += 256) {
    int j = idx >> 5, c2 = (idx & 31) * 2;
    ushort2 w2;
    w2.x = f2bu(lx[j][c2]);
    w2.y = f2bu(lx[j][c2 + 1]);
    *(ushort2*)&xo[j * 64 + c2] = w2;
  }
}

// -------- 4. weight transform: w[co][ci][tap] fp32 -> wT[tap][co][ci] bf16 -
__global__ __launch_bounds__(256) void k_wprep(const float* __restrict__ w1,
                                               const float* __restrict__ w2,
                                               unsigned short* __restrict__ wT1,
                                               unsigned short* __restrict__ wT2) {
  int i = blockIdx.x * 256 + threadIdx.x;   // < 36864
  if (i >= 36864) return;
  int tap = i >> 12;
  int rem = i & 4095;
  int co = rem >> 6, ci = rem & 63;
  int src = (co * 64 + ci) * 9 + tap;
  wT1[i] = f2bu(w1[src]);
  wT2[i] = f2bu(w2[src]);
}

// -------- 5. MFMA conv3x3(pad1) as 9 row-gathered GEMMs --------------------
template <bool NORM_IN>
__global__ __launch_bounds__(256) void k_convm(const unsigned short* __restrict__ src,
                                               const unsigned short* __restrict__ wT,
                                               const float* __restrict__ insum,
                                               const float* __restrict__ insq,
                                               unsigned short* __restrict__ dst,
                                               float* __restrict__ gsum,
                                               float* __restrict__ gsq) {
  int b = blockIdx.y;
  int r = blockIdx.x;              // image row 0..63
  __shared__ unsigned short bx[198 * LS];   // 28.5 KB
  __shared__ float nmean[64], ninv[64];
  int t = threadIdx.x;
  if (NORM_IN) {
    if (t < 64) {
      float m = insum[b * 64 + t] * (1.f / NN);
      float v = fmaxf(insq[b * 64 + t] * (1.f / NN) - m * m, 0.f);
      nmean[t] = m; ninv[t] = rsqrtf(v + 1e-5f);
    }
    __syncthreads();
  }
  const unsigned short* sb = src + (size_t)b * NN * 64;
  for (int idx = t; idx < 198 * 8; idx += 256) {
    int row = idx >> 3, c8 = (idx & 7) * 8;
    int dy = row / 66;
    int cx = row - dy * 66 - 1;
    int rr = r + dy - 1;
    uint4 v = make_uint4(0u, 0u, 0u, 0u);
    if ((unsigned)rr < 64u && (unsigned)cx < 64u) {
      v = *(const uint4*)(sb + ((size_t)(rr * 64 + cx)) * 64 + c8);
      if (NORM_IN) {
        unsigned short* e = (unsigned short*)&v;
        #pragma unroll
        for (int j = 0; j < 8; ++j)
          e[j] = f2bu(fmaxf((us2f(e[j]) - nmean[c8 + j]) * ninv[c8 + j], 0.f));
      }
    }
    *(uint4*)&bx[row * LS + c8] = v;
  }
  __syncthreads();
  int lane = t & 63;
  int quad = lane >> 4, col = lane & 15;
  int qw = (t >> 6) * 16;          // co strip
  f32x4 acc[4] = {{0.f,0.f,0.f,0.f},{0.f,0.f,0.f,0.f},{0.f,0.f,0.f,0.f},{0.f,0.f,0.f,0.f}};
  #pragma unroll
  for (int tap = 0; tap < 9; ++tap) {
    int dy = tap / 3, dx = tap - dy * 3 - 1;
    const unsigned short* wrow = wT + ((size_t)tap * 64 + qw + col) * 64;
    short8 a0 = *(const short8*)(wrow + quad * 8);
    short8 a1 = *(const short8*)(wrow + 32 + quad * 8);
    int rbase = dy * 66 + dx + 1;
    #pragma unroll
    for (int nt = 0; nt < 4; ++nt) {
      int row = rbase + nt * 16 + col;
      short8 b0 = *(const short8*)&bx[row * LS + quad * 8];
      short8 b1 = *(const short8*)&bx[row * LS + 32 + quad * 8];
      acc[nt] = __builtin_amdgcn_mfma_f32_16x16x32_bf16(a0, b0, acc[nt], 0, 0, 0);
      acc[nt] = __builtin_amdgcn_mfma_f32_16x16x32_bf16(a1, b1, acc[nt], 0, 0, 0);
    }
  }
  #pragma unroll
  for (int rr = 0; rr < 4; ++rr) {
    float s1 = acc[0][rr] + acc[1][rr] + acc[2][rr] + acc[3][rr];
    float s2 = acc[0][rr]*acc[0][rr] + acc[1][rr]*acc[1][rr]
             + acc[2][rr]*acc[2][rr] + acc[3][rr]*acc[3][rr];
    s1 += __shfl_xor(s1, 1); s2 += __shfl_xor(s2, 1);
    s1 += __shfl_xor(s1, 2); s2 += __shfl_xor(s2, 2);
    s1 += __shfl_xor(s1, 4); s2 += __shfl_xor(s2, 4);
    s1 += __shfl_xor(s1, 8); s2 += __shfl_xor(s2, 8);
    if (col == 0) {
      int co = qw + quad * 4 + rr;
      atomicAdd(&gsum[b * 64 + co], s1);
      atomicAdd(&gsq[b * 64 + co], s2);
    }
  }
  __syncthreads();
  #pragma unroll
  for (int nt = 0; nt < 4; ++nt)
    #pragma unroll
    for (int rr = 0; rr < 4; ++rr)
      bx[(nt * 16 + col) * LS + qw + quad * 4 + rr] = f2bu(acc[nt][rr]);
  __syncthreads();
  unsigned short* db = dst + ((size_t)b * NN + r * 64) * 64;
  for (int idx = t; idx < 512; idx += 256) {
    int px = idx >> 3, c8 = (idx & 7) * 8;
    *(uint4*)(db + (size_t)px * 64 + c8) = *(const uint4*)&bx[px * LS + c8];
  }
}

// -------- 6. fused inorm2 + residual + relu + L2-norm; zero afc/den --------
__global__ __launch_bounds__(256) void k_knorm(unsigned short* __restrict__ kxt,
                                               const unsigned short* __restrict__ xt,
                                               const float* __restrict__ gsum,
                                               const float* __restrict__ gsq,
                                               float* __restrict__ afc,
                                               float* __restrict__ den) {
  int b = blockIdx.x >> 6;
  int p0 = (blockIdx.x & 63) * 64;
  __shared__ float m2[64], i2[64];
  int t = threadIdx.x;
  if (t < 64) {
    float m = gsum[b * 64 + t] * (1.f / NN);
    float v = fmaxf(gsq[b * 64 + t] * (1.f / NN) - m * m, 0.f);
    m2[t] = m; i2[t] = rsqrtf(v + 1e-5f);
  }
  // zero the atomic accumulators (afc 1M floats, den 16K floats)
  size_t gid = (size_t)blockIdx.x * 256 + t;
  float4 z4 = make_float4(0.f, 0.f, 0.f, 0.f);
  float4* az = (float4*)afc;
  #pragma unroll
  for (int j = 0; j < 4; ++j) az[gid + (size_t)j * 65536] = z4;
  if (gid < 16384) den[gid] = 0.f;
  __syncthreads();
  int px = t >> 2, c0 = (t & 3) * 16;
  size_t base = ((size_t)b * NN + p0 + px) * 64 + c0;
  unsigned short kv[16], xv[16];
  *(uint4*)&kv[0] = *(const uint4*)(kxt + base);
  *(uint4*)&kv[8] = *(const uint4*)(kxt + base + 8);
  *(uint4*)&xv[0] = *(const uint4*)(xt + base);
  *(uint4*)&xv[8] = *(const uint4*)(xt + base + 8);
  float v[16]; float ss = 0.f;
  #pragma unroll
  for (int j = 0; j < 16; ++j) {
    float f = fmaxf((us2f(kv[j]) - m2[c0 + j]) * i2[c0 + j] + us2f(xv[j]), 0.f);
    v[j] = f; ss += f * f;
  }
  ss += __shfl_xor(ss, 1);
  ss += __shfl_xor(ss, 2);
  float inv = 1.f / (sqrtf(ss) + 1e-8f);
  #pragma unroll
  for (int j = 0; j < 16; ++j) kv[j] = f2bu(v[j] * inv);
  *(uint4*)(kxt + base) = *(const uint4*)&kv[0];
  *(uint4*)(kxt + base + 8) = *(const uint4*)&kv[8];
}

// -------- 7. attention pass 1: MFMA, K-split x4, atomic combine ------------
__global__ __launch_bounds__(256) void k_att1(const unsigned short* __restrict__ khat,
                                              const unsigned short* __restrict__ xt,
                                              const int* __restrict__ qidx, const int* __restrict__ kidx,
                                              const int* __restrict__ nqv, const int* __restrict__ nkv,
                                              float* __restrict__ afc, float* __restrict__ den) {
  int b = blockIdx.y;
  int nqb = nqv[b], nkb = nkv[b];
  int q0 = (blockIdx.x >> 2) * 64;
  int part = blockIdx.x & 3;
  if (q0 >= nqb) return;
  int kbeg = (part * nkb) >> 2;
  int kend = ((part + 1) * nkb) >> 2;
  __shared__ unsigned short lq [64 * LS];   // Q   [q][c]
  __shared__ unsigned short lk [64 * LS];   // K   [k][c]
  __shared__ unsigned short lvT[64 * LS];   // V^T [c][k]
  __shared__ unsigned short le [64 * LS];   // E   [q][k]
  int t = threadIdx.x;
  int wave = t >> 6, lane = t & 63;
  int quad = lane >> 4, col = lane & 15;
  int qw = wave * 16;
  const int* qix = qidx + b * NN;
  const int* kix = kidx + b * NN;
  const unsigned short* khb = khat + (size_t)b * NN * 64;
  const unsigned short* xtb = xt + (size_t)b * NN * 64;
  for (int idx = t; idx < 512; idx += 256) {
    int q = idx >> 3, c8 = (idx & 7) * 8;
    uint4 v = make_uint4(0u, 0u, 0u, 0u);
    if (q0 + q < nqb) v = *(const uint4*)(khb + (size_t)qix[q0 + q] * 64 + c8);
    *(uint4*)&lq[q * LS + c8] = v;
  }
  f32x4 pv[4] = {{0.f,0.f,0.f,0.f},{0.f,0.f,0.f,0.f},{0.f,0.f,0.f,0.f},{0.f,0.f,0.f,0.f}};
  float dsum[4] = {0.f, 0.f, 0.f, 0.f};
  for (int j0 = kbeg; j0 < kend; j0 += 64) {
    __syncthreads();
    for (int idx = t; idx < 512; idx += 256) {
      int k = idx >> 3, c8 = (idx & 7) * 8;
      uint4 v = make_uint4(0u, 0u, 0u, 0u);
      uint4 vv = make_uint4(0u, 0u, 0u, 0u);
      if (j0 + k < kend) {
        int kp = kix[j0 + k];
        v  = *(const uint4*)(khb + (size_t)kp * 64 + c8);
        vv = *(const uint4*)(xtb + (size_t)kp * 64 + c8);
      }
      *(uint4*)&lk[k * LS + c8] = v;
      unsigned short* vs = (unsigned short*)&vv;
      #pragma unroll
      for (int jj = 0; jj < 8; ++jj) lvT[(c8 + jj) * LS + k] = vs[jj];
    }
    __syncthreads();
    #pragma unroll
    for (int kt = 0; kt < 4; ++kt) {
      f32x4 s = {0.f, 0.f, 0.f, 0.f};
      #pragma unroll
      for (int h = 0; h < 2; ++h) {
        short8 a  = *(const short8*)&lq[(qw + col) * LS + h * 32 + quad * 8];
        short8 bk = *(const short8*)&lk[(kt * 16 + col) * LS + h * 32 + quad * 8];
        s = __builtin_amdgcn_mfma_f32_16x16x32_bf16(a, bk, s, 0, 0, 0);
      }
      bool kval = (j0 + kt * 16 + col) < kend;
      #pragma unroll
      for (int r = 0; r < 4; ++r) {
        float e = kval ? __expf(20.f * s[r]) : 0.f;
        dsum[r] += e;
        le[(qw + quad * 4 + r) * LS + kt * 16 + col] = f2bu(e);
      }
    }
    __syncthreads();
    #pragma unroll
    for (int ct = 0; ct < 4; ++ct) {
      #pragma unroll
      for (int h = 0; h < 2; ++h) {
        short8 a  = *(const short8*)&le[(qw + col) * LS + h * 32 + quad * 8];
        short8 bv = *(const short8*)&lvT[(ct * 16 + col) * LS + h * 32 + quad * 8];
        pv[ct] = __builtin_amdgcn_mfma_f32_16x16x32_bf16(a, bv, pv[ct], 0, 0, 0);
      }
    }
  }
  #pragma unroll
  for (int r = 0; r < 4; ++r) {
    float v = dsum[r];
    v += __shfl_xor(v, 1); v += __shfl_xor(v, 2);
    v += __shfl_xor(v, 4); v += __shfl_xor(v, 8);
    dsum[r] = v;
  }
  #pragma unroll
  for (int r = 0; r < 4; ++r) {
    int qq = q0 + qw + quad * 4 + r;
    if (qq < nqb) {
      if (col == 0) atomicAdd(&den[b * NN + qq], dsum[r]);
      float* dst = afc + ((size_t)b * NN + qq) * 64;
      #pragma unroll
      for (int ct = 0; ct < 4; ++ct) atomicAdd(&dst[ct * 16 + col], pv[ct][r]);
    }
  }
}

// -------- 8. attention pass 2: MFMA, Q-split x4, atomic vis ----------------
__global__ __launch_bounds__(256) void k_att2(const unsigned short* __restrict__ khat,
                                              const int* __restrict__ qidx, const int* __restrict__ kidx,
                                              const int* __restrict__ nqv, const int* __restrict__ nkv,
                                              const float* __restrict__ den, float* __restrict__ vis) {
  int b = blockIdx.y;
  int nqb = nqv[b], nkb = nkv[b];
  int k0 = (blockIdx.x >> 2) * 64;
  int part = blockIdx.x & 3;
  if (k0 >= nkb) return;
  int qbeg = (part * nqb) >> 2;
  int qend = ((part + 1) * nqb) >> 2;
  __shared__ unsigned short lk[64 * LS];
  __shared__ unsigned short lq[64 * LS];
  __shared__ float w[64];
  int t = threadIdx.x;
  int wave = t >> 6, lane = t & 63;
  int quad = lane >> 4, col = lane & 15;
  int kw = wave * 16;
  const int* qix = qidx + b * NN;
  const int* kix = kidx + b * NN;
  const unsigned short* khb = khat + (size_t)b * NN * 64;
  for (int idx = t; idx < 512; idx += 256) {
    int k = idx >> 3, c8 = (idx & 7) * 8;
    uint4 v = make_uint4(0u, 0u, 0u, 0u);
    if (k0 + k < nkb) v = *(const uint4*)(khb + (size_t)kix[k0 + k] * 64 + c8);
    *(uint4*)&lk[k * LS + c8] = v;
  }
  float vacc[4] = {0.f, 0.f, 0.f, 0.f};
  for (int i0 = qbeg; i0 < qend; i0 += 64) {
    __syncthreads();
    for (int idx = t; idx < 512; idx += 256) {
      int q = idx >> 3, c8 = (idx & 7) * 8;
      uint4 v = make_uint4(0u, 0u, 0u, 0u);
      if (i0 + q < qend) v = *(const uint4*)(khb + (size_t)qix[i0 + q] * 64 + c8);
      *(uint4*)&lq[q * LS + c8] = v;
    }
    if (t < 64) {
      int qq = i0 + t;
      float d = (qq < qend) ? den[b * NN + qq] : 0.f;
      w[t] = (d > 0.f) ? 1.f / d : 0.f;
    }
    __syncthreads();
    #pragma unroll
    for (int qt = 0; qt < 4; ++qt) {
      f32x4 s = {0.f, 0.f, 0.f, 0.f};
      #pragma unroll
      for (int h = 0; h < 2; ++h) {
        short8 a  = *(const short8*)&lk[(kw + col) * LS + h * 32 + quad * 8];
        short8 bq = *(const short8*)&lq[(qt * 16 + col) * LS + h * 32 + quad * 8];
        s = __builtin_amdgcn_mfma_f32_16x16x32_bf16(a, bq, s, 0, 0, 0);
      }
      float wq = w[qt * 16 + col];
      #pragma unroll
      for (int r = 0; r < 4; ++r) vacc[r] += __expf(20.f * s[r]) * wq;
    }
  }
  #pragma unroll
  for (int r = 0; r < 4; ++r) {
    float v = vacc[r];
    v += __shfl_xor(v, 1); v += __shfl_xor(v, 2);
    v += __shfl_xor(v, 4); v += __shfl_xor(v, 8);
    int kk = k0 + kw + quad * 4 + r;
    if (col == 0 && kk < nkb) atomicAdd(&vis[b * NN + kix[kk]], v);
  }
}

// -------- 9a. default out = x (fp32 bit copy, 4 MB) ------------------------
__global__ __launch_bounds__(256) void k_copy(const uint4* __restrict__ src, uint4* __restrict__ dst, int n) {
  int i = blockIdx.x * 256 + threadIdx.x;
  if (i < n) dst[i] = src[i];
}

// -------- 9b. fusion epilogue over fg pixels -------------------------------
__global__ __launch_bounds__(256) void k_fusion(const unsigned short* __restrict__ xt,
                                                const float* __restrict__ afc,
                                                const float* __restrict__ den,
                                                const int* __restrict__ qidx, const int* __restrict__ nqv,
                                                const float* __restrict__ w1, const float* __restrict__ w2,
                                                const float* __restrict__ b2, const float* __restrict__ wf,
                                                float* __restrict__ outp) {
  int b = blockIdx.y;
  int nqb = nqv[b];
  int q0 = blockIdx.x * 16;
  if (q0 >= nqb) return;
  __shared__ bf16 w1s[128 * 64];
  __shared__ bf16 w2s[64 * 64];
  __shared__ bf16 wfs[128 * 64];
  __shared__ float b2s[64];
  __shared__ float px[4][64];
  __shared__ float pa[4][64];
  __shared__ float pf[4][64];
  int t = threadIdx.x;
  for (int idx = t; idx < 8192; idx += 256) {
    int j = idx >> 6, c = idx & 63;
    w1s[j * 64 + c] = __float2bfloat16(w1[c * 128 + j]);
    wfs[j * 64 + c] = __float2bfloat16(wf[c * 128 + j]);
  }
  for (int idx = t; idx < 4096; idx += 256) {
    int j = idx >> 6, c = idx & 63;
    w2s[j * 64 + c] = __float2bfloat16(w2[c * 64 + j]);
  }
  if (t < 64) b2s[t] = b2[t];
  int c = t & 63, pp = t >> 6;
  const int* qix = qidx + b * NN;
  const unsigned short* xtb = xt + (size_t)b * NN * 64;
  for (int it = 0; it < 4; ++it) {
    int qq = q0 + it * 4 + pp;
    bool valid = qq < nqb;
    int qp = valid ? qix[qq] : 0;
    float dq = valid ? den[b * NN + qq] : 1.f;
    float invd = (dq > 0.f) ? 1.f / dq : 0.f;
    __syncthreads();
    px[pp][c] = valid ? us2f(xtb[(size_t)qp * 64 + c]) : 0.f;
    pa[pp][c] = valid ? afc[((size_t)b * NN + qq) * 64 + c] * invd : 0.f;
    __syncthreads();
    float f1 = 0.f;
    for (int j = 0; j < 64; ++j) f1 += b2f(w1s[j * 64 + c]) * px[pp][j];
    for (int j = 0; j < 64; ++j) f1 += b2f(w1s[(64 + j) * 64 + c]) * pa[pp][j];
    pf[pp][c] = f1;
    __syncthreads();
    float z = b2s[c];
    for (int j = 0; j < 64; ++j) z += b2f(w2s[j * 64 + c]) * pf[pp][j];
    float sg = 1.f / (1.f + __expf(-z));
    pa[pp][c] = pa[pp][c] * (1.f - sg);
    __syncthreads();
    float fu = 0.f;
    for (int j = 0; j < 64; ++j) fu += b2f(wfs[j * 64 + c]) * px[pp][j];
    for (int j = 0; j < 64; ++j) fu += b2f(wfs[(64 + j) * 64 + c]) * pa[pp][j];
    if (valid) outp[((size_t)b * CC + c) * NN + qp] = fu;
  }
}

// -------- 10a. global max of visatt ----------------------------------------
__global__ __launch_bounds__(256) void k_vmax(const float* __restrict__ vis, unsigned int* __restrict__ vmaxb) {
  int i = blockIdx.x * 256 + threadIdx.x;
  float v = vis[i];
  #pragma unroll
  for (int off = 32; off > 0; off >>= 1) v = fmaxf(v, __shfl_down(v, off));
  if ((threadIdx.x & 63) == 0) atomicMax(vmaxb, __float_as_uint(v));
}

// -------- 10b. x8 nearest upsample + normalize -----------------------------
__global__ __launch_bounds__(256) void k_upsample(const float* __restrict__ vis,
                                                  const unsigned int* __restrict__ vmaxb,
                                                  float* __restrict__ out2) {
  int i = blockIdx.x * 256 + threadIdx.x;
  int b = i >> 18;
  int rem = i & 262143;
  int y = rem >> 9, x = rem & 511;
  float vm = __uint_as_float(vmaxb[0]);
  if (!(vm > 0.f)) vm = 1.f;
  out2[i] = vis[b * NN + (y >> 3) * 64 + (x >> 3)] / vm;
}

extern "C" void kernel_launch(void* const* d_in, const int* in_sizes, int n_in,
                              void* d_out, int out_size, void* d_ws, size_t ws_size,
                              hipStream_t stream) {
  const float* x    = (const float*)d_in[0];
  const float* mask = (const float*)d_in[1];
  const float* w1   = (const float*)d_in[2];
  const float* w2c  = (const float*)d_in[3];
  const float* fsw1 = (const float*)d_in[4];
  const float* fsw2 = (const float*)d_in[5];
  const float* fsb2 = (const float*)d_in[6];
  const float* fswf = (const float*)d_in[7];
  float* out = (float*)d_out;
  char* wsb = (char*)d_ws;

  float* afc = (float*)(wsb + WB_AFC);
  float* den = (float*)(wsb + WB_DEN);
  float* vis = (float*)(wsb + WB_VIS);
  int* qidx  = (int*)(wsb + WB_QIX);
  int* kidx  = (int*)(wsb + WB_KIX);
  unsigned char* mfl = (unsigned char*)(wsb + WB_MFL);
  int* nq = (int*)(wsb + WB_CNT);
  int* nk = nq + 4;
  unsigned int* vmaxb = (unsigned int*)(nq + 8);
  float* gstat = (float*)(wsb + WB_STAT);
  float* gsum1 = gstat;
  float* gsq1  = gstat + 256;
  float* gsum2 = gstat + 512;
  float* gsq2  = gstat + 768;
  unsigned short* wT1 = (unsigned short*)(wsb + WB_WT1);
  unsigned short* wT2 = (unsigned short*)(wsb + WB_WT2);
  unsigned short* y1t = (unsigned short*)(wsb + WB_AFC);   // 2 MB, dead before k_knorm zeroes afc

  // scratch staged inside d_out:
  unsigned short* kxt = (unsigned short*)out;
  unsigned short* khat = kxt;
  unsigned short* xt = (unsigned short*)(out + 1048576);

  k_maxpool<<<256, 256, 0, stream>>>(mask, mfl, vis, gstat, vmaxb);
  k_compact<<<4, 64, 0, stream>>>(mfl, qidx, kidx, nq, nk);
  k_xT<<<256, 256, 0, stream>>>(x, xt);
  k_wprep<<<144, 256, 0, stream>>>(w1, w2c, wT1, wT2);
  k_convm<false><<<dim3(64, BB), 256, 0, stream>>>(xt, wT1, nullptr, nullptr, y1t, gsum1, gsq1);
  k_convm<true><<<dim3(64, BB), 256, 0, stream>>>(y1t, wT2, gsum1, gsq1, kxt, gsum2, gsq2);
  k_knorm<<<256, 256, 0, stream>>>(kxt, xt, gsum2, gsq2, afc, den);
  k_att1<<<dim3(256, BB), 256, 0, stream>>>(khat, xt, qidx, kidx, nq, nk, afc, den);
  k_att2<<<dim3(256, BB), 256, 0, stream>>>(khat, qidx, kidx, nq, nk, den, vis);
  k_copy<<<1024, 256, 0, stream>>>((const uint4*)x, (uint4*)out, 262144);
  k_fusion<<<dim3(256, BB), 256, 0, stream>>>(xt, afc, den, qidx, nq, fsw1, fsw2, fsb2, fswf, out);
  k_vmax<<<64, 256, 0, stream>>>(vis, vmaxb);
  k_upsample<<<4096, 256, 0, stream>>>(vis, vmaxb, out + 1048576);
}

// Round 11
// 196.890 us; speedup vs baseline: 9.1642x; 1.2510x over previous
//
#include <hip/hip_runtime.h>
#include <hip/hip_bf16.h>

typedef __hip_bfloat16 bf16;
typedef __attribute__((ext_vector_type(8))) short short8;
typedef __attribute__((ext_vector_type(4))) float f32x4;

#define BB 4
#define CC 64
#define NN 4096           // 64*64
#define MH 512
#define MW 512
#define LS 72             // LDS row stride in bf16 elements

// ---- workspace layout (BYTE offsets; total ~4.67 MiB) ----
#define WB_AFC  ((size_t)0)         // f32[4*4096*64] att_fore UNNORMALIZED sums (atomic)
                                    // first 2 MB double as y1t (bf16 conv1 raw) before k_knorm
#define WB_DEN  ((size_t)4194304)   // f32[4*4096] softmax denominators (atomic)
#define WB_VIS  ((size_t)4259840)   // f32[4*4096] visatt (atomic)
#define WB_QIX  ((size_t)4325376)   // int[4*4096]
#define WB_KIX  ((size_t)4390912)   // int[4*4096]
#define WB_MFL  ((size_t)4456448)   // uchar[4*4096]
#define WB_CNT  ((size_t)4472832)   // int nq[4]; int nk[4]; uint vmaxbits (12 ints)
#define WB_STAT ((size_t)4472896)   // f32 gsum1[256]; gsq1[256]; gsum2[256]; gsq2[256]
#define WB_WT1  ((size_t)4476992)   // bf16[9*64*64] wT1
#define WB_WT2  ((size_t)4550720)   // bf16[9*64*64] wT2
#define WB_WFB  ((size_t)4624448)   // bf16 w1b[8192]; w2b[4096]; wfb[8192] (40960 B)

__device__ __forceinline__ float b2f(bf16 v) { return __bfloat162float(v); }
__device__ __forceinline__ float us2f(unsigned short u) { return __uint_as_float(((unsigned)u) << 16); }
__device__ __forceinline__ unsigned short f2bu(float f) {
  bf16 h = __float2bfloat16(f);
  return *(unsigned short*)&h;
}

// ------- 1. maxpool 8x8 on mask (4 lanes/window) + zero vis/stats/vmax -----
__global__ __launch_bounds__(256) void k_maxpool(const float* __restrict__ mask,
                                                 unsigned char* __restrict__ mfl,
                                                 float* __restrict__ vis,
                                                 float* __restrict__ gstat,
                                                 unsigned int* __restrict__ vmaxb) {
  int g = blockIdx.x * 256 + threadIdx.x;          // < 4*4096*4
  int o = g >> 2, sub = g & 3;
  int b = o >> 12, p = o & 4095;
  int py = p >> 6, px = p & 63;
  const float* mb = mask + (size_t)b * MH * MW + (py * 8 + sub * 2) * MW + px * 8;
  float mx = 0.f;
  #pragma unroll
  for (int dy = 0; dy < 2; ++dy) {
    const float4* r4 = (const float4*)(mb + dy * MW);
    float4 a = r4[0], c = r4[1];
    mx = fmaxf(mx, fmaxf(fmaxf(a.x, a.y), fmaxf(a.z, a.w)));
    mx = fmaxf(mx, fmaxf(fmaxf(c.x, c.y), fmaxf(c.z, c.w)));
  }
  mx = fmaxf(mx, __shfl_xor(mx, 1));
  mx = fmaxf(mx, __shfl_xor(mx, 2));
  if (sub == 0) {
    mfl[o] = (mx > 0.f) ? 1 : 0;
    vis[o] = 0.f;
  }
  if (g < 1024) gstat[g] = 0.f;
  if (g == 0) vmaxb[0] = 0u;
}

// ---------------- 2. fg/bg index compaction (1 wave per batch) -------------
__global__ __launch_bounds__(64) void k_compact(const unsigned char* __restrict__ mfl,
                                                int* __restrict__ qidx, int* __restrict__ kidx,
                                                int* __restrict__ nq, int* __restrict__ nk) {
  int b = blockIdx.x, lane = threadIdx.x;
  int qb = 0, kb = 0;
  for (int it = 0; it < 64; ++it) {
    int p = it * 64 + lane;
    bool f = mfl[b * NN + p] != 0;
    unsigned long long bal = __ballot(f);
    int before = __popcll(bal & ((1ULL << lane) - 1ULL));
    if (f)  qidx[b * NN + qb + before] = p;
    if (!f) kidx[b * NN + kb + (lane - before)] = p;
    int cnt = __popcll(bal);
    qb += cnt; kb += 64 - cnt;
  }
  if (lane == 0) { nq[b] = qb; nk[b] = kb; }
}

// -------- 3. transpose x -> bf16 pixel-major (xt) --------------------------
__global__ __launch_bounds__(256) void k_xT(const float* __restrict__ x,
                                            unsigned short* __restrict__ xt) {
  int b = blockIdx.x >> 6, p0 = (blockIdx.x & 63) * 64;
  __shared__ float lx[64][65];
  int t = threadIdx.x;
  const float* xb = x + (size_t)b * CC * NN + p0;
  for (int idx = t; idx < 4096; idx += 256) {
    int c = idx >> 6, j = idx & 63;
    lx[j][c] = xb[c * NN + j];
  }
  __syncthreads();
  unsigned short* xo = xt + ((size_t)b * NN + p0) * 64;
  for (int idx = t; idx < 2048; idx += 256) {
    int j = idx >> 5, c2 = (idx & 31) * 2;
    ushort2 w2;
    w2.x = f2bu(lx[j][c2]);
    w2.y = f2bu(lx[j][c2 + 1]);
    *(ushort2*)&xo[j * 64 + c2] = w2;
  }
}

// -------- 4. weight prep: conv wT + fusion weights -> bf16 -----------------
__global__ __launch_bounds__(256) void k_wprep(const float* __restrict__ w1,
                                               const float* __restrict__ w2,
                                               const float* __restrict__ fw1,
                                               const float* __restrict__ fw2,
                                               const float* __restrict__ fwf,
                                               unsigned short* __restrict__ wT1,
                                               unsigned short* __restrict__ wT2,
                                               unsigned short* __restrict__ wfb) {
  int i = blockIdx.x * 256 + threadIdx.x;   // < 57344
  if (i < 36864) {
    int tap = i >> 12;
    int rem = i & 4095;
    int co = rem >> 6, ci = rem & 63;
    int src = (co * 64 + ci) * 9 + tap;
    wT1[i] = f2bu(w1[src]);
    wT2[i] = f2bu(w2[src]);
  } else if (i < 57344) {
    int j = i - 36864;
    if (j < 8192)       wfb[j] = f2bu(fw1[j]);                 // w1b
    else if (j < 12288) wfb[j] = f2bu(fw2[j - 8192]);          // w2b
    else                wfb[j] = f2bu(fwf[j - 12288]);         // wfb
  }
}

// -------- 5. MFMA conv3x3(pad1) as 9 row-gathered GEMMs --------------------
template <bool NORM_IN>
__global__ __launch_bounds__(256) void k_convm(const unsigned short* __restrict__ src,
                                               const unsigned short* __restrict__ wT,
                                               const float* __restrict__ insum,
                                               const float* __restrict__ insq,
                                               unsigned short* __restrict__ dst,
                                               float* __restrict__ gsum,
                                               float* __restrict__ gsq) {
  int b = blockIdx.y;
  int r = blockIdx.x;              // image row 0..63
  __shared__ unsigned short bx[198 * LS];   // 28.5 KB
  __shared__ float nmean[64], ninv[64];
  int t = threadIdx.x;
  if (NORM_IN) {
    if (t < 64) {
      float m = insum[b * 64 + t] * (1.f / NN);
      float v = fmaxf(insq[b * 64 + t] * (1.f / NN) - m * m, 0.f);
      nmean[t] = m; ninv[t] = rsqrtf(v + 1e-5f);
    }
    __syncthreads();
  }
  const unsigned short* sb = src + (size_t)b * NN * 64;
  for (int idx = t; idx < 198 * 8; idx += 256) {
    int row = idx >> 3, c8 = (idx & 7) * 8;
    int dy = row / 66;
    int cx = row - dy * 66 - 1;
    int rr = r + dy - 1;
    uint4 v = make_uint4(0u, 0u, 0u, 0u);
    if ((unsigned)rr < 64u && (unsigned)cx < 64u) {
      v = *(const uint4*)(sb + ((size_t)(rr * 64 + cx)) * 64 + c8);
      if (NORM_IN) {
        unsigned short* e = (unsigned short*)&v;
        #pragma unroll
        for (int j = 0; j < 8; ++j)
          e[j] = f2bu(fmaxf((us2f(e[j]) - nmean[c8 + j]) * ninv[c8 + j], 0.f));
      }
    }
    *(uint4*)&bx[row * LS + c8] = v;
  }
  __syncthreads();
  int lane = t & 63;
  int quad = lane >> 4, col = lane & 15;
  int qw = (t >> 6) * 16;          // co strip
  f32x4 acc[4] = {{0.f,0.f,0.f,0.f},{0.f,0.f,0.f,0.f},{0.f,0.f,0.f,0.f},{0.f,0.f,0.f,0.f}};
  #pragma unroll
  for (int tap = 0; tap < 9; ++tap) {
    int dy = tap / 3, dx = tap - dy * 3 - 1;
    const unsigned short* wrow = wT + ((size_t)tap * 64 + qw + col) * 64;
    short8 a0 = *(const short8*)(wrow + quad * 8);
    short8 a1 = *(const short8*)(wrow + 32 + quad * 8);
    int rbase = dy * 66 + dx + 1;
    #pragma unroll
    for (int nt = 0; nt < 4; ++nt) {
      int row = rbase + nt * 16 + col;
      short8 b0 = *(const short8*)&bx[row * LS + quad * 8];
      short8 b1 = *(const short8*)&bx[row * LS + 32 + quad * 8];
      acc[nt] = __builtin_amdgcn_mfma_f32_16x16x32_bf16(a0, b0, acc[nt], 0, 0, 0);
      acc[nt] = __builtin_amdgcn_mfma_f32_16x16x32_bf16(a1, b1, acc[nt], 0, 0, 0);
    }
  }
  #pragma unroll
  for (int rr = 0; rr < 4; ++rr) {
    float s1 = acc[0][rr] + acc[1][rr] + acc[2][rr] + acc[3][rr];
    float s2 = acc[0][rr]*acc[0][rr] + acc[1][rr]*acc[1][rr]
             + acc[2][rr]*acc[2][rr] + acc[3][rr]*acc[3][rr];
    s1 += __shfl_xor(s1, 1); s2 += __shfl_xor(s2, 1);
    s1 += __shfl_xor(s1, 2); s2 += __shfl_xor(s2, 2);
    s1 += __shfl_xor(s1, 4); s2 += __shfl_xor(s2, 4);
    s1 += __shfl_xor(s1, 8); s2 += __shfl_xor(s2, 8);
    if (col == 0) {
      int co = qw + quad * 4 + rr;
      atomicAdd(&gsum[b * 64 + co], s1);
      atomicAdd(&gsq[b * 64 + co], s2);
    }
  }
  __syncthreads();
  #pragma unroll
  for (int nt = 0; nt < 4; ++nt)
    #pragma unroll
    for (int rr = 0; rr < 4; ++rr)
      bx[(nt * 16 + col) * LS + qw + quad * 4 + rr] = f2bu(acc[nt][rr]);
  __syncthreads();
  unsigned short* db = dst + ((size_t)b * NN + r * 64) * 64;
  for (int idx = t; idx < 512; idx += 256) {
    int px = idx >> 3, c8 = (idx & 7) * 8;
    *(uint4*)(db + (size_t)px * 64 + c8) = *(const uint4*)&bx[px * LS + c8];
  }
}

// -------- 6. fused inorm2 + residual + relu + L2-norm; zero afc/den --------
__global__ __launch_bounds__(256) void k_knorm(unsigned short* __restrict__ kxt,
                                               const unsigned short* __restrict__ xt,
                                               const float* __restrict__ gsum,
                                               const float* __restrict__ gsq,
                                               float* __restrict__ afc,
                                               float* __restrict__ den) {
  int b = blockIdx.x >> 6;
  int p0 = (blockIdx.x & 63) * 64;
  __shared__ float m2[64], i2[64];
  int t = threadIdx.x;
  if (t < 64) {
    float m = gsum[b * 64 + t] * (1.f / NN);
    float v = fmaxf(gsq[b * 64 + t] * (1.f / NN) - m * m, 0.f);
    m2[t] = m; i2[t] = rsqrtf(v + 1e-5f);
  }
  size_t gid = (size_t)blockIdx.x * 256 + t;
  float4 z4 = make_float4(0.f, 0.f, 0.f, 0.f);
  float4* az = (float4*)afc;
  #pragma unroll
  for (int j = 0; j < 4; ++j) az[gid + (size_t)j * 65536] = z4;
  if (gid < 16384) den[gid] = 0.f;
  __syncthreads();
  int px = t >> 2, c0 = (t & 3) * 16;
  size_t base = ((size_t)b * NN + p0 + px) * 64 + c0;
  unsigned short kv[16], xv[16];
  *(uint4*)&kv[0] = *(const uint4*)(kxt + base);
  *(uint4*)&kv[8] = *(const uint4*)(kxt + base + 8);
  *(uint4*)&xv[0] = *(const uint4*)(xt + base);
  *(uint4*)&xv[8] = *(const uint4*)(xt + base + 8);
  float v[16]; float ss = 0.f;
  #pragma unroll
  for (int j = 0; j < 16; ++j) {
    float f = fmaxf((us2f(kv[j]) - m2[c0 + j]) * i2[c0 + j] + us2f(xv[j]), 0.f);
    v[j] = f; ss += f * f;
  }
  ss += __shfl_xor(ss, 1);
  ss += __shfl_xor(ss, 2);
  float inv = 1.f / (sqrtf(ss) + 1e-8f);
  #pragma unroll
  for (int j = 0; j < 16; ++j) kv[j] = f2bu(v[j] * inv);
  *(uint4*)(kxt + base) = *(const uint4*)&kv[0];
  *(uint4*)(kxt + base + 8) = *(const uint4*)&kv[8];
}

// -------- 7. attention pass 1: MFMA, K-split x4, atomic combine ------------
__global__ __launch_bounds__(256) void k_att1(const unsigned short* __restrict__ khat,
                                              const unsigned short* __restrict__ xt,
                                              const int* __restrict__ qidx, const int* __restrict__ kidx,
                                              const int* __restrict__ nqv, const int* __restrict__ nkv,
                                              float* __restrict__ afc, float* __restrict__ den) {
  int b = blockIdx.y;
  int nqb = nqv[b], nkb = nkv[b];
  int q0 = (blockIdx.x >> 2) * 64;
  int part = blockIdx.x & 3;
  if (q0 >= nqb) return;
  int kbeg = (part * nkb) >> 2;
  int kend = ((part + 1) * nkb) >> 2;
  __shared__ unsigned short lq [64 * LS];
  __shared__ unsigned short lk [64 * LS];
  __shared__ unsigned short lvT[64 * LS];
  __shared__ unsigned short le [64 * LS];
  int t = threadIdx.x;
  int wave = t >> 6, lane = t & 63;
  int quad = lane >> 4, col = lane & 15;
  int qw = wave * 16;
  const int* qix = qidx + b * NN;
  const int* kix = kidx + b * NN;
  const unsigned short* khb = khat + (size_t)b * NN * 64;
  const unsigned short* xtb = xt + (size_t)b * NN * 64;
  for (int idx = t; idx < 512; idx += 256) {
    int q = idx >> 3, c8 = (idx & 7) * 8;
    uint4 v = make_uint4(0u, 0u, 0u, 0u);
    if (q0 + q < nqb) v = *(const uint4*)(khb + (size_t)qix[q0 + q] * 64 + c8);
    *(uint4*)&lq[q * LS + c8] = v;
  }
  f32x4 pv[4] = {{0.f,0.f,0.f,0.f},{0.f,0.f,0.f,0.f},{0.f,0.f,0.f,0.f},{0.f,0.f,0.f,0.f}};
  float dsum[4] = {0.f, 0.f, 0.f, 0.f};
  for (int j0 = kbeg; j0 < kend; j0 += 64) {
    __syncthreads();
    for (int idx = t; idx < 512; idx += 256) {
      int k = idx >> 3, c8 = (idx & 7) * 8;
      uint4 v = make_uint4(0u, 0u, 0u, 0u);
      uint4 vv = make_uint4(0u, 0u, 0u, 0u);
      if (j0 + k < kend) {
        int kp = kix[j0 + k];
        v  = *(const uint4*)(khb + (size_t)kp * 64 + c8);
        vv = *(const uint4*)(xtb + (size_t)kp * 64 + c8);
      }
      *(uint4*)&lk[k * LS + c8] = v;
      unsigned short* vs = (unsigned short*)&vv;
      #pragma unroll
      for (int jj = 0; jj < 8; ++jj) lvT[(c8 + jj) * LS + k] = vs[jj];
    }
    __syncthreads();
    #pragma unroll
    for (int kt = 0; kt < 4; ++kt) {
      f32x4 s = {0.f, 0.f, 0.f, 0.f};
      #pragma unroll
      for (int h = 0; h < 2; ++h) {
        short8 a  = *(const short8*)&lq[(qw + col) * LS + h * 32 + quad * 8];
        short8 bk = *(const short8*)&lk[(kt * 16 + col) * LS + h * 32 + quad * 8];
        s = __builtin_amdgcn_mfma_f32_16x16x32_bf16(a, bk, s, 0, 0, 0);
      }
      bool kval = (j0 + kt * 16 + col) < kend;
      #pragma unroll
      for (int r = 0; r < 4; ++r) {
        float e = kval ? __expf(20.f * s[r]) : 0.f;
        dsum[r] += e;
        le[(qw + quad * 4 + r) * LS + kt * 16 + col] = f2bu(e);
      }
    }
    __syncthreads();
    #pragma unroll
    for (int ct = 0; ct < 4; ++ct) {
      #pragma unroll
      for (int h = 0; h < 2; ++h) {
        short8 a  = *(const short8*)&le[(qw + col) * LS + h * 32 + quad * 8];
        short8 bv = *(const short8*)&lvT[(ct * 16 + col) * LS + h * 32 + quad * 8];
        pv[ct] = __builtin_amdgcn_mfma_f32_16x16x32_bf16(a, bv, pv[ct], 0, 0, 0);
      }
    }
  }
  #pragma unroll
  for (int r = 0; r < 4; ++r) {
    float v = dsum[r];
    v += __shfl_xor(v, 1); v += __shfl_xor(v, 2);
    v += __shfl_xor(v, 4); v += __shfl_xor(v, 8);
    dsum[r] = v;
  }
  #pragma unroll
  for (int r = 0; r < 4; ++r) {
    int qq = q0 + qw + quad * 4 + r;
    if (qq < nqb) {
      if (col == 0) atomicAdd(&den[b * NN + qq], dsum[r]);
      float* dst = afc + ((size_t)b * NN + qq) * 64;
      #pragma unroll
      for (int ct = 0; ct < 4; ++ct) atomicAdd(&dst[ct * 16 + col], pv[ct][r]);
    }
  }
}

// -------- 8. attention pass 2: MFMA, Q-split x4, atomic vis ----------------
__global__ __launch_bounds__(256) void k_att2(const unsigned short* __restrict__ khat,
                                              const int* __restrict__ qidx, const int* __restrict__ kidx,
                                              const int* __restrict__ nqv, const int* __restrict__ nkv,
                                              const float* __restrict__ den, float* __restrict__ vis) {
  int b = blockIdx.y;
  int nqb = nqv[b], nkb = nkv[b];
  int k0 = (blockIdx.x >> 2) * 64;
  int part = blockIdx.x & 3;
  if (k0 >= nkb) return;
  int qbeg = (part * nqb) >> 2;
  int qend = ((part + 1) * nqb) >> 2;
  __shared__ unsigned short lk[64 * LS];
  __shared__ unsigned short lq[64 * LS];
  __shared__ float w[64];
  int t = threadIdx.x;
  int wave = t >> 6, lane = t & 63;
  int quad = lane >> 4, col = lane & 15;
  int kw = wave * 16;
  const int* qix = qidx + b * NN;
  const int* kix = kidx + b * NN;
  const unsigned short* khb = khat + (size_t)b * NN * 64;
  for (int idx = t; idx < 512; idx += 256) {
    int k = idx >> 3, c8 = (idx & 7) * 8;
    uint4 v = make_uint4(0u, 0u, 0u, 0u);
    if (k0 + k < nkb) v = *(const uint4*)(khb + (size_t)kix[k0 + k] * 64 + c8);
    *(uint4*)&lk[k * LS + c8] = v;
  }
  float vacc[4] = {0.f, 0.f, 0.f, 0.f};
  for (int i0 = qbeg; i0 < qend; i0 += 64) {
    __syncthreads();
    for (int idx = t; idx < 512; idx += 256) {
      int q = idx >> 3, c8 = (idx & 7) * 8;
      uint4 v = make_uint4(0u, 0u, 0u, 0u);
      if (i0 + q < qend) v = *(const uint4*)(khb + (size_t)qix[i0 + q] * 64 + c8);
      *(uint4*)&lq[q * LS + c8] = v;
    }
    if (t < 64) {
      int qq = i0 + t;
      float d = (qq < qend) ? den[b * NN + qq] : 0.f;
      w[t] = (d > 0.f) ? 1.f / d : 0.f;
    }
    __syncthreads();
    #pragma unroll
    for (int qt = 0; qt < 4; ++qt) {
      f32x4 s = {0.f, 0.f, 0.f, 0.f};
      #pragma unroll
      for (int h = 0; h < 2; ++h) {
        short8 a  = *(const short8*)&lk[(kw + col) * LS + h * 32 + quad * 8];
        short8 bq = *(const short8*)&lq[(qt * 16 + col) * LS + h * 32 + quad * 8];
        s = __builtin_amdgcn_mfma_f32_16x16x32_bf16(a, bq, s, 0, 0, 0);
      }
      float wq = w[qt * 16 + col];
      #pragma unroll
      for (int r = 0; r < 4; ++r) vacc[r] += __expf(20.f * s[r]) * wq;
    }
  }
  #pragma unroll
  for (int r = 0; r < 4; ++r) {
    float v = vacc[r];
    v += __shfl_xor(v, 1); v += __shfl_xor(v, 2);
    v += __shfl_xor(v, 4); v += __shfl_xor(v, 8);
    int kk = k0 + kw + quad * 4 + r;
    if (col == 0 && kk < nkb) atomicAdd(&vis[b * NN + kix[kk]], v);
  }
}

// -------- 9a. default out = x (fp32 bit copy, 4 MB) ------------------------
__global__ __launch_bounds__(256) void k_copy(const uint4* __restrict__ src, uint4* __restrict__ dst, int n) {
  int i = blockIdx.x * 256 + threadIdx.x;
  if (i < n) dst[i] = src[i];
}

// -------- 9b. fusion epilogue: MFMA over 64-q blocks -----------------------
// wfb layout: w1b[8192] | w2b[4096] | wfb[8192] (all bf16, flat [co][k])
#define FS 136            // pxa row stride (bf16)
__global__ __launch_bounds__(256) void k_fusionm(const unsigned short* __restrict__ xt,
                                                 const float* __restrict__ afc,
                                                 const float* __restrict__ den,
                                                 const int* __restrict__ qidx, const int* __restrict__ nqv,
                                                 const unsigned short* __restrict__ wall,
                                                 const float* __restrict__ b2,
                                                 float* __restrict__ outp) {
  int b = blockIdx.y;
  int nqb = nqv[b];
  int q0 = blockIdx.x * 64;
  if (q0 >= nqb) return;
  __shared__ unsigned short pxa[64 * FS];   // [q][128] px|pa, 17.4 KB
  __shared__ unsigned short f1s[64 * LS];   // [q][co], 9.2 KB
  __shared__ int qpl[64];
  int t = threadIdx.x;
  int lane = t & 63;
  int quad = lane >> 4, col = lane & 15;
  int cb = (t >> 6) * 16;                   // wave's co strip
  const int* qix = qidx + b * NN;
  const unsigned short* xtb = xt + (size_t)b * NN * 64;
  // per-lane weight fragments (registers, from L2)
  const unsigned short* w1b = wall;
  const unsigned short* w2b = wall + 8192;
  const unsigned short* wfb = wall + 12288;
  short8 a1[4], a2[2], af[4];
  #pragma unroll
  for (int kt = 0; kt < 4; ++kt) {
    a1[kt] = *(const short8*)&w1b[(cb + col) * 128 + kt * 32 + quad * 8];
    af[kt] = *(const short8*)&wfb[(cb + col) * 128 + kt * 32 + quad * 8];
  }
  #pragma unroll
  for (int kt = 0; kt < 2; ++kt)
    a2[kt] = *(const short8*)&w2b[(cb + col) * 64 + kt * 32 + quad * 8];
  float b2v[4];
  #pragma unroll
  for (int r = 0; r < 4; ++r) b2v[r] = b2[cb + quad * 4 + r];
  if (t < 64) qpl[t] = (q0 + t < nqb) ? qix[q0 + t] : -1;
  // stage pxa: px from xt row, pa = afc * inv(den)
  for (int idx = t; idx < 512; idx += 256) {
    int q = idx >> 3, c8 = (idx & 7) * 8;
    int qq = q0 + q;
    uint4 pv = make_uint4(0u, 0u, 0u, 0u);
    unsigned short pa8[8] = {0, 0, 0, 0, 0, 0, 0, 0};
    if (qq < nqb) {
      int qp = qix[qq];
      pv = *(const uint4*)(xtb + (size_t)qp * 64 + c8);
      float d = den[b * NN + qq];
      float invd = (d > 0.f) ? 1.f / d : 0.f;
      const float* ap = afc + ((size_t)b * NN + qq) * 64 + c8;
      #pragma unroll
      for (int j = 0; j < 8; ++j) pa8[j] = f2bu(ap[j] * invd);
    }
    *(uint4*)&pxa[q * FS + c8] = pv;
    *(uint4*)&pxa[q * FS + 64 + c8] = *(const uint4*)&pa8[0];
  }
  __syncthreads();
  // stage 1: f1[co][q] = W1 . pxa   (K=128)
  #pragma unroll
  for (int qt = 0; qt < 4; ++qt) {
    f32x4 acc = {0.f, 0.f, 0.f, 0.f};
    #pragma unroll
    for (int kt = 0; kt < 4; ++kt) {
      short8 bfrag = *(const short8*)&pxa[(qt * 16 + col) * FS + kt * 32 + quad * 8];
      acc = __builtin_amdgcn_mfma_f32_16x16x32_bf16(a1[kt], bfrag, acc, 0, 0, 0);
    }
    #pragma unroll
    for (int r = 0; r < 4; ++r)
      f1s[(qt * 16 + col) * LS + cb + quad * 4 + r] = f2bu(acc[r]);
  }
  __syncthreads();
  // stage 2: z[co][q] = W2 . f1 + b2; sigmoid; pa *= (1-s)
  #pragma unroll
  for (int qt = 0; qt < 4; ++qt) {
    f32x4 acc = {0.f, 0.f, 0.f, 0.f};
    #pragma unroll
    for (int kt = 0; kt < 2; ++kt) {
      short8 bfrag = *(const short8*)&f1s[(qt * 16 + col) * LS + kt * 32 + quad * 8];
      acc = __builtin_amdgcn_mfma_f32_16x16x32_bf16(a2[kt], bfrag, acc, 0, 0, 0);
    }
    #pragma unroll
    for (int r = 0; r < 4; ++r) {
      float sg = 1.f / (1.f + __expf(-(acc[r] + b2v[r])));
      int addr = (qt * 16 + col) * FS + 64 + cb + quad * 4 + r;
      pxa[addr] = f2bu(us2f(pxa[addr]) * (1.f - sg));
    }
  }
  __syncthreads();
  // stage 3: fu[co][q] = Wf . pxa'  (K=128); direct scatter to out
  #pragma unroll
  for (int qt = 0; qt < 4; ++qt) {
    f32x4 acc = {0.f, 0.f, 0.f, 0.f};
    #pragma unroll
    for (int kt = 0; kt < 4; ++kt) {
      short8 bfrag = *(const short8*)&pxa[(qt * 16 + col) * FS + kt * 32 + quad * 8];
      acc = __builtin_amdgcn_mfma_f32_16x16x32_bf16(af[kt], bfrag, acc, 0, 0, 0);
    }
    int qp = qpl[qt * 16 + col];
    if (qp >= 0) {
      #pragma unroll
      for (int r = 0; r < 4; ++r)
        outp[((size_t)b * CC + cb + quad * 4 + r) * NN + qp] = acc[r];
    }
  }
}

// -------- 10a. global max of visatt ----------------------------------------
__global__ __launch_bounds__(256) void k_vmax(const float* __restrict__ vis, unsigned int* __restrict__ vmaxb) {
  int i = blockIdx.x * 256 + threadIdx.x;
  float v = vis[i];
  #pragma unroll
  for (int off = 32; off > 0; off >>= 1) v = fmaxf(v, __shfl_down(v, off));
  if ((threadIdx.x & 63) == 0) atomicMax(vmaxb, __float_as_uint(v));
}

// -------- 10b. x8 nearest upsample + normalize -----------------------------
__global__ __launch_bounds__(256) void k_upsample(const float* __restrict__ vis,
                                                  const unsigned int* __restrict__ vmaxb,
                                                  float* __restrict__ out2) {
  int i = blockIdx.x * 256 + threadIdx.x;
  int b = i >> 18;
  int rem = i & 262143;
  int y = rem >> 9, x = rem & 511;
  float vm = __uint_as_float(vmaxb[0]);
  if (!(vm > 0.f)) vm = 1.f;
  out2[i] = vis[b * NN + (y >> 3) * 64 + (x >> 3)] / vm;
}

extern "C" void kernel_launch(void* const* d_in, const int* in_sizes, int n_in,
                              void* d_out, int out_size, void* d_ws, size_t ws_size,
                              hipStream_t stream) {
  const float* x    = (const float*)d_in[0];
  const float* mask = (const float*)d_in[1];
  const float* w1   = (const float*)d_in[2];
  const float* w2c  = (const float*)d_in[3];
  const float* fsw1 = (const float*)d_in[4];
  const float* fsw2 = (const float*)d_in[5];
  const float* fsb2 = (const float*)d_in[6];
  const float* fswf = (const float*)d_in[7];
  float* out = (float*)d_out;
  char* wsb = (char*)d_ws;

  float* afc = (float*)(wsb + WB_AFC);
  float* den = (float*)(wsb + WB_DEN);
  float* vis = (float*)(wsb + WB_VIS);
  int* qidx  = (int*)(wsb + WB_QIX);
  int* kidx  = (int*)(wsb + WB_KIX);
  unsigned char* mfl = (unsigned char*)(wsb + WB_MFL);
  int* nq = (int*)(wsb + WB_CNT);
  int* nk = nq + 4;
  unsigned int* vmaxb = (unsigned int*)(nq + 8);
  float* gstat = (float*)(wsb + WB_STAT);
  float* gsum1 = gstat;
  float* gsq1  = gstat + 256;
  float* gsum2 = gstat + 512;
  float* gsq2  = gstat + 768;
  unsigned short* wT1 = (unsigned short*)(wsb + WB_WT1);
  unsigned short* wT2 = (unsigned short*)(wsb + WB_WT2);
  unsigned short* wall = (unsigned short*)(wsb + WB_WFB);
  unsigned short* y1t = (unsigned short*)(wsb + WB_AFC);   // 2 MB, dead before k_knorm zeroes afc

  // scratch staged inside d_out:
  unsigned short* kxt = (unsigned short*)out;
  unsigned short* khat = kxt;
  unsigned short* xt = (unsigned short*)(out + 1048576);

  k_maxpool<<<256, 256, 0, stream>>>(mask, mfl, vis, gstat, vmaxb);
  k_compact<<<4, 64, 0, stream>>>(mfl, qidx, kidx, nq, nk);
  k_xT<<<256, 256, 0, stream>>>(x, xt);
  k_wprep<<<224, 256, 0, stream>>>(w1, w2c, fsw1, fsw2, fswf, wT1, wT2, wall);
  k_convm<false><<<dim3(64, BB), 256, 0, stream>>>(xt, wT1, nullptr, nullptr, y1t, gsum1, gsq1);
  k_convm<true><<<dim3(64, BB), 256, 0, stream>>>(y1t, wT2, gsum1, gsq1, kxt, gsum2, gsq2);
  k_knorm<<<256, 256, 0, stream>>>(kxt, xt, gsum2, gsq2, afc, den);
  k_att1<<<dim3(256, BB), 256, 0, stream>>>(khat, xt, qidx, kidx, nq, nk, afc, den);
  k_att2<<<dim3(256, BB), 256, 0, stream>>>(khat, qidx, kidx, nq, nk, den, vis);
  k_copy<<<1024, 256, 0, stream>>>((const uint4*)x, (uint4*)out, 262144);
  k_fusionm<<<dim3(64, BB), 256, 0, stream>>>(xt, afc, den, qidx, nq, wall, fsb2, out);
  k_vmax<<<64, 256, 0, stream>>>(vis, vmaxb);
  k_upsample<<<4096, 256, 0, stream>>>(vis, vmaxb, out + 1048576);
}